// Round 2
// 250.367 us; speedup vs baseline: 1.1301x; 1.1301x over previous
//
#include <hip/hip_runtime.h>

#define BATCH 8
#define CH    48
#define NPTS  4096
#define NBN   (BATCH*NPTS)
#define KNN   9
#define NCAND 12             // per-lane filter depth

typedef unsigned short u16;
typedef unsigned int   u32;
typedef unsigned long long u64;
typedef __bf16 bf16x8 __attribute__((ext_vector_type(8)));
typedef float  f32x4  __attribute__((ext_vector_type(4)));

__device__ __forceinline__ float bf2f(u16 v) { return __uint_as_float(((u32)v) << 16); }
__device__ __forceinline__ u16 f2bf(float f) {
  u32 u = __float_as_uint(f);
  u = (u + 0x7fffu + ((u >> 16) & 1u)) >> 16;
  return (u16)u;
}

// ======================= FAST PATH (ws >= ~83 MB) =======================
// k_prep: normalize per reference; write xraw/xn fp32 node-major, csq;
// build hi/lo-split bf16 operands. A layout MFMA-coalesced:
// [tile16][variant(4)][lane(64)][8 bf16]; B [node][128]. Zero deg.
__global__ __launch_bounds__(256)
void k_prep(const float* __restrict__ x, float* __restrict__ xraw,
            float* __restrict__ xn, float* __restrict__ csq,
            u16* __restrict__ Abuf, u16* __restrict__ Bbuf,
            int* __restrict__ deg) {
  int node = blockIdx.x * 256 + threadIdx.x;
  deg[node] = 0;
  int b = node >> 12, n = node & (NPTS - 1);
  const float* xb = x + (size_t)b * CH * NPTS;
  float f[CH];
#pragma unroll
  for (int c = 0; c < CH; ++c) f[c] = xb[(size_t)c * NPTS + n];
  float a0 = 0, a1 = 0, a2 = 0, a3 = 0;
#pragma unroll
  for (int k = 0; k < CH; k += 4) {
    a0 += f[k] * f[k]; a1 += f[k+1] * f[k+1];
    a2 += f[k+2] * f[k+2]; a3 += f[k+3] * f[k+3];
  }
  float nrm = fmaxf(sqrtf((a0 + a1) + (a2 + a3)), 1e-12f);
  float xv[CH];
#pragma unroll
  for (int c = 0; c < CH; ++c) xv[c] = f[c] / nrm;     // true division (ref)
  a0 = a1 = a2 = a3 = 0;
#pragma unroll
  for (int k = 0; k < CH; k += 4) {
    a0 += xv[k] * xv[k]; a1 += xv[k+1] * xv[k+1];
    a2 += xv[k+2] * xv[k+2]; a3 += xv[k+3] * xv[k+3];
  }
  float csqv = (a0 + a1) + (a2 + a3);
  csq[node] = csqv;
  float4* ro = (float4*)(xraw + (size_t)node * CH);
  float4* no = (float4*)(xn   + (size_t)node * CH);
#pragma unroll
  for (int i = 0; i < CH / 4; ++i) {
    ro[i] = make_float4(f[4*i], f[4*i+1], f[4*i+2], f[4*i+3]);
    no[i] = make_float4(xv[4*i], xv[4*i+1], xv[4*i+2], xv[4*i+3]);
  }
  u16 ah[64], al[64];
#pragma unroll
  for (int k = 0; k < CH; ++k) {
    float av = -2.0f * xv[k];
    u16 h = f2bf(av); ah[k] = h; al[k] = f2bf(av - bf2f(h));
  }
  { u16 h = f2bf(csqv); ah[48] = h; al[48] = f2bf(csqv - bf2f(h)); }
#pragma unroll
  for (int k = 49; k < 64; ++k) { ah[k] = 0; al[k] = 0; }
  u16* Bh = Bbuf + (size_t)node * 128;
#pragma unroll
  for (int k = 0; k < CH; ++k) {
    float bv = xv[k];
    u16 h = f2bf(bv); Bh[k] = h; Bh[64 + k] = f2bf(bv - bf2f(h));
  }
  Bh[48] = 0x3F80; Bh[64 + 48] = 0;            // 1.0 bf16 exact
#pragma unroll
  for (int k = 49; k < 64; ++k) { Bh[k] = 0; Bh[64 + k] = 0; }
  u16* Ag = Abuf + (size_t)(node >> 4) * 2048 + (size_t)(node & 15) * 8;
#pragma unroll
  for (int v = 0; v < 4; ++v) {
    const u16* src = (v < 2) ? ah : al;
    int koff = (v & 1) * 32;
#pragma unroll
    for (int q = 0; q < 4; ++q) {
      uint4 pk;
      const u16* s = src + koff + q * 8;
      pk.x = (u32)s[0] | ((u32)s[1] << 16);
      pk.y = (u32)s[2] | ((u32)s[3] << 16);
      pk.z = (u32)s[4] | ((u32)s[5] << 16);
      pk.w = (u32)s[6] | ((u32)s[7] << 16);
      *(uint4*)(Ag + v * 512 + q * 128) = pk;
    }
  }
}

// k_knn_m: wave = 16-row panel; blockIdx.y = column quarter (64 tiles of 16).
// 6 MFMAs/tile (hh,hl,lh). Top-12 filter via single-instruction v_med3_u32
// insertion: inserting x into sorted s0<=...<=s11 (drop max) is
//   s_i' = med3(s_{i-1}, s_i, x)  (i=11..1, old values),  s0' = min(s0, x).
// 12 VALU ops/candidate instead of 24 (min+max STEP chain), same result.
// KEY RANGE: MFMA computes csq_col - 2<x_col,x_row>  (row's own sqn omitted,
// rank-invariant) which lies in [-1-eps, 3+eps]. acc bias +2.5 maps keys to
// [~1.5, ~5.5] -- strictly positive floats, so the raw bit pattern is
// order-preserving with no sign-flip map. (+0.5 was WRONG: negative keys.)
// Epilogue emits u64 = (packed_key << 12) | global_col (total order, no ties).
#define MED3(d, a, b, c) \
  asm("v_med3_u32 %0, %1, %2, %3" : "=v"(d) : "v"(a), "v"(b), "v"(c))
#define INSERT12(x) do { \
  MED3(s11, s10, s11, x); MED3(s10, s9, s10, x); MED3(s9, s8, s9, x);  \
  MED3(s8,  s7,  s8,  x); MED3(s7,  s6, s7,  x); MED3(s6, s5, s6, x);  \
  MED3(s5,  s4,  s5,  x); MED3(s4,  s3, s4,  x); MED3(s3, s2, s3, x);  \
  MED3(s2,  s1,  s2,  x); MED3(s1,  s0, s1,  x); s0 = min(s0, x);      \
} while (0)

__global__ __launch_bounds__(256, 8)
void k_knn_m(const u16* __restrict__ Abuf, const u16* __restrict__ Bbuf,
             u64* __restrict__ candu) {
  int tid = threadIdx.x;
  int lane = tid & 63;
  int quad = lane >> 4, m16 = lane & 15;
  int panel = blockIdx.x * 4 + (tid >> 6);
  int row = panel * 16 + m16;
  int b4096 = row & ~(NPTS - 1);
  int quarter = blockIdx.y;
  int ct0 = quarter * 64;

  const __bf16* Bb = (const __bf16*)Bbuf + (size_t)row * 128;
  bf16x8 bh0 = *(const bf16x8*)(Bb + quad * 8);
  bf16x8 bh1 = *(const bf16x8*)(Bb + 32 + quad * 8);
  bf16x8 bl0 = *(const bf16x8*)(Bb + 64 + quad * 8);
  bf16x8 bl1 = *(const bf16x8*)(Bb + 96 + quad * 8);

  const __bf16* Ag = (const __bf16*)Abuf + (size_t)(b4096 >> 4) * 2048
                     + (size_t)lane * 8;

  u32 s0=~0u,s1=~0u,s2=~0u,s3=~0u,s4=~0u,s5=~0u,
      s6=~0u,s7=~0u,s8=~0u,s9=~0u,s10=~0u,s11=~0u;

  for (int t = 0; t < 64; ++t) {
    int ct = ct0 + t;
    const __bf16* ap = Ag + (size_t)ct * 2048;
    bf16x8 a0 = *(const bf16x8*)(ap);
    bf16x8 a1 = *(const bf16x8*)(ap + 512);
    bf16x8 a2 = *(const bf16x8*)(ap + 1024);
    bf16x8 a3 = *(const bf16x8*)(ap + 1536);
    f32x4 acc = {2.5f, 2.5f, 2.5f, 2.5f};   // +2.5 bias: keys strictly positive
    acc = __builtin_amdgcn_mfma_f32_16x16x32_bf16(a0, bh0, acc, 0, 0, 0);
    acc = __builtin_amdgcn_mfma_f32_16x16x32_bf16(a1, bh1, acc, 0, 0, 0);
    acc = __builtin_amdgcn_mfma_f32_16x16x32_bf16(a0, bl0, acc, 0, 0, 0);
    acc = __builtin_amdgcn_mfma_f32_16x16x32_bf16(a1, bl1, acc, 0, 0, 0);
    acc = __builtin_amdgcn_mfma_f32_16x16x32_bf16(a2, bh0, acc, 0, 0, 0);
    acc = __builtin_amdgcn_mfma_f32_16x16x32_bf16(a3, bh1, acc, 0, 0, 0);
#pragma unroll
    for (int r = 0; r < 4; ++r) {
      u32 u = __float_as_uint(acc[r]);               // positive -> monotone
      u32 x = (u & 0xFFFFFC00u) | (u32)((ct << 2) | r);
      INSERT12(x);
    }
  }

  u64* o = candu + (((size_t)row * 4 + quarter) * 4 + quad) * NCAND;
#define EMIT(j, sv) { u32 col = ((sv & 0x3FFu) >> 2) * 16 + quad * 4 + (sv & 3u); \
                      o[j] = ((u64)sv << 12) | (u64)col; }
  EMIT(0, s0)  EMIT(1, s1)  EMIT(2, s2)  EMIT(3, s3)
  EMIT(4, s4)  EMIT(5, s5)  EMIT(6, s6)  EMIT(7, s7)
  EMIT(8, s8)  EMIT(9, s9)  EMIT(10, s10) EMIT(11, s11)
#undef EMIT
}

// k_reduce: per row, top-12 of the 192 u64 candidates (coalesced reads, no
// feature gathers). 64 rows/block x 4 threads/row; branchless u64 STEP
// network in named registers; 2-stage (48 each -> 48 merged by thread 0).
#define STEP64(si) { u64 _lo = (x < si) ? x : si; u64 _hi = (x < si) ? si : x; \
                     si = _lo; x = _hi; }
__global__ __launch_bounds__(256, 4)
void k_reduce(const u64* __restrict__ candu, u32* __restrict__ cand12) {
  __shared__ u64 ls[64 * 4 * NCAND];   // 24,576 B
  int tid = threadIdx.x;
  int lr = tid >> 2, q = tid & 3;
  int row = blockIdx.x * 64 + lr;
  const u64* src = candu + (size_t)row * 192 + q * 48;
  u64 t0=~0ull,t1=~0ull,t2=~0ull,t3=~0ull,t4=~0ull,t5=~0ull,
      t6=~0ull,t7=~0ull,t8=~0ull,t9=~0ull,t10=~0ull,t11=~0ull;
  for (int s = 0; s < 48; ++s) {
    u64 x = src[s];
    STEP64(t0) STEP64(t1) STEP64(t2) STEP64(t3) STEP64(t4) STEP64(t5)
    STEP64(t6) STEP64(t7) STEP64(t8) STEP64(t9) STEP64(t10) STEP64(t11)
  }
  u64* lw = ls + (size_t)(lr * 4 + q) * NCAND;
  lw[0]=t0; lw[1]=t1; lw[2]=t2; lw[3]=t3; lw[4]=t4; lw[5]=t5;
  lw[6]=t6; lw[7]=t7; lw[8]=t8; lw[9]=t9; lw[10]=t10; lw[11]=t11;
  __syncthreads();
  if (q == 0) {
    u64 g0=~0ull,g1=~0ull,g2=~0ull,g3=~0ull,g4=~0ull,g5=~0ull,
        g6=~0ull,g7=~0ull,g8=~0ull,g9=~0ull,g10=~0ull,g11=~0ull;
    const u64* lsrc = ls + (size_t)lr * 48;
    for (int s = 0; s < 48; ++s) {
      u64 x = lsrc[s];
      STEP64(g0) STEP64(g1) STEP64(g2) STEP64(g3) STEP64(g4) STEP64(g5)
      STEP64(g6) STEP64(g7) STEP64(g8) STEP64(g9) STEP64(g10) STEP64(g11)
    }
    u32* o = cand12 + (size_t)row * NCAND;
    o[0]=(u32)(g0&0xFFFu); o[1]=(u32)(g1&0xFFFu); o[2]=(u32)(g2&0xFFFu);
    o[3]=(u32)(g3&0xFFFu); o[4]=(u32)(g4&0xFFFu); o[5]=(u32)(g5&0xFFFu);
    o[6]=(u32)(g6&0xFFFu); o[7]=(u32)(g7&0xFFFu); o[8]=(u32)(g8&0xFFFu);
    o[9]=(u32)(g9&0xFFFu); o[10]=(u32)(g10&0xFFFu); o[11]=(u32)(g11&0xFFFu);
  }
}

// k_rescore: 16 rows/block x 16 threads/row; threads 0..11 each gather ONE
// candidate row and compute the exact fp32 dist (proven formula); thread 0
// merges 12 with the exact (dist, idx) comparator -> top-9. Fused nn write
// + degree histogram (tail edge drop). Only 12 gathers/row.
#define RR 16
__global__ __launch_bounds__(256, 4)
void k_rescore(const float* __restrict__ xn, const float* __restrict__ csq,
               const u32* __restrict__ cand12,
               u16* __restrict__ nn, int* __restrict__ deg) {
  __shared__ float dS[RR * NCAND];
  __shared__ int   iS[RR * NCAND];
  int tid = threadIdx.x;
  int lr = tid >> 4, q = tid & 15;
  int bi = blockIdx.x;
  int row = (bi & 7) * NPTS + (bi >> 3) * RR + lr;   // XCD swizzle (perf-only)
  int b4096 = row & ~(NPTS - 1);
  const float* xnb = xn + (size_t)b4096 * CH;
  if (q < NCAND) {
    float rf[CH];
    const float4* p = (const float4*)(xn + (size_t)row * CH);
#pragma unroll
    for (int i = 0; i < CH / 4; ++i) {
      float4 v = p[i];
      rf[4*i] = v.x; rf[4*i+1] = v.y; rf[4*i+2] = v.z; rf[4*i+3] = v.w;
    }
    float sqn = csq[row];
    int c = (int)(cand12[(size_t)row * NCAND + q] & (NPTS - 1));
    const float4* cp = (const float4*)(xnb + (size_t)c * CH);
    float a0 = 0, a1 = 0, a2 = 0, a3 = 0;
#pragma unroll
    for (int i = 0; i < CH / 4; ++i) {
      float4 v = cp[i];
      a0 += rf[4*i]   * v.x; a1 += rf[4*i+1] * v.y;
      a2 += rf[4*i+2] * v.z; a3 += rf[4*i+3] * v.w;
    }
    float dist = (sqn + csq[b4096 + c]) - 2.0f * ((a0 + a1) + (a2 + a3));
    dS[lr * NCAND + q] = dist;
    iS[lr * NCAND + q] = c;
  }
  __syncthreads();
  if (q == 0) {
    float gd[KNN]; int gi[KNN];
#pragma unroll
    for (int j = 0; j < KNN; ++j) { gd[j] = 3.4e38f; gi[j] = 0x7fffffff; }
    for (int s = 0; s < NCAND; ++s) {
      float dc = dS[lr * NCAND + s]; int ic = iS[lr * NCAND + s];
      if (dc < gd[KNN - 1] || (dc == gd[KNN - 1] && ic < gi[KNN - 1])) {
        gd[KNN - 1] = dc; gi[KNN - 1] = ic;
#pragma unroll
        for (int k2 = KNN - 1; k2 > 0; --k2) {
          bool sw = (gd[k2] < gd[k2 - 1]) ||
                    (gd[k2] == gd[k2 - 1] && gi[k2] < gi[k2 - 1]);
          if (sw) {
            float td = gd[k2]; gd[k2] = gd[k2 - 1]; gd[k2 - 1] = td;
            int ti = gi[k2]; gi[k2] = gi[k2 - 1]; gi[k2 - 1] = ti;
          }
        }
      }
    }
    u16* o = nn + (size_t)row * KNN;
    int jmax = (row == NBN - 1) ? (KNN - 1) : KNN;   // linspace tail drop
#pragma unroll
    for (int j = 0; j < KNN; ++j) o[j] = (u16)(gi[j] & (NPTS - 1));
    for (int j = 0; j < jmax; ++j)
      atomicAdd(&deg[b4096 + (gi[j] & (NPTS - 1))], 1);
  }
}

// k_out: 64 nodes/block x 4 threads/node (12 out-channels each), XCD swizzle.
#define ONB 64
#define LPAD 52
__global__ __launch_bounds__(256)
void k_out_f(const float* __restrict__ xraw, const u16* __restrict__ nn,
             const int* __restrict__ deg,
             const float* __restrict__ W0, const float* __restrict__ W1,
             const float* __restrict__ bias, float* __restrict__ out) {
  __shared__ float w0[CH * CH], w1[CH * CH], bs[CH];
  __shared__ __align__(16) float fS[ONB * LPAD];
  __shared__ __align__(16) float txS[ONB * LPAD];
  __shared__ float dinvS[ONB];
  int tid = threadIdx.x;
  int bi = blockIdx.x;
  int n0 = (bi & 7) * NPTS + (bi >> 3) * ONB;   // XCD swizzle (perf-only)
  int b12 = n0 & ~(NPTS - 1);
  for (int i = tid; i < CH * CH; i += 256) { w0[i] = W0[i]; w1[i] = W1[i]; }
  if (tid < CH) bs[tid] = bias[tid];
  for (int i = tid; i < ONB * 12; i += 256) {
    int ln = i / 12, f4 = i % 12;
    *(float4*)(fS + ln * LPAD + f4 * 4) =
        *(const float4*)(xraw + (size_t)(n0 + ln) * CH + f4 * 4);
  }
  if (tid < ONB) {
    int dg = deg[n0 + tid];
    dinvS[tid] = (dg > 0) ? (1.0f / sqrtf((float)dg)) : 0.0f;
  }
  __syncthreads();

  int ln = tid >> 2, p = tid & 3;
  int node = n0 + ln;
  float dn = dinvS[ln];
  const u16* nrow = nn + (size_t)node * KNN;
  bool full = (node != NBN - 1);
  float tx[12];
#pragma unroll
  for (int i = 0; i < 12; ++i) tx[i] = 0.f;
#pragma unroll
  for (int j = 0; j < KNN; ++j) {
    if (j < KNN - 1 || full) {
      int s = nrow[j] & (NPTS - 1);
      int dgs = deg[b12 + s];
      float ds = (dgs > 0) ? (1.0f / sqrtf((float)dgs)) : 0.0f;
      float w = -(ds * dn);
      const float4* pr = (const float4*)(xraw + (size_t)(b12 + s) * CH + p * 12);
#pragma unroll
      for (int q3 = 0; q3 < 3; ++q3) {
        float4 v = pr[q3];
        tx[q3*4]   += w * v.x; tx[q3*4+1] += w * v.y;
        tx[q3*4+2] += w * v.z; tx[q3*4+3] += w * v.w;
      }
    }
  }
#pragma unroll
  for (int q3 = 0; q3 < 3; ++q3)
    *(float4*)(txS + ln * LPAD + p * 12 + q3 * 4) =
        make_float4(tx[q3*4], tx[q3*4+1], tx[q3*4+2], tx[q3*4+3]);
  __syncthreads();

  float acc[12];
#pragma unroll
  for (int i = 0; i < 12; ++i) acc[i] = bs[p * 12 + i];
  const float* fr = fS + ln * LPAD;
  const float* tr = txS + ln * LPAD;
#pragma unroll
  for (int c = 0; c < CH; ++c) {
    float fc = fr[c];
    const float* wr = w0 + c * CH + p * 12;
#pragma unroll
    for (int i = 0; i < 12; ++i) acc[i] += fc * wr[i];
  }
#pragma unroll
  for (int c = 0; c < CH; ++c) {
    float tc = tr[c];
    const float* wr = w1 + c * CH + p * 12;
#pragma unroll
    for (int i = 0; i < 12; ++i) acc[i] += tc * wr[i];
  }
  float* op = out + (size_t)node * CH + p * 12;
#pragma unroll
  for (int q3 = 0; q3 < 3; ++q3)
    *(float4*)(op + q3 * 4) =
        make_float4(acc[q3*4], acc[q3*4+1], acc[q3*4+2], acc[q3*4+3]);
}

// ======================= FALLBACK (round-4, proven) =======================
__global__ __launch_bounds__(256)
void k_zero(int* __restrict__ deg) { deg[blockIdx.x * 256 + threadIdx.x] = 0; }

__global__ __launch_bounds__(256)
void k_hist(const u16* __restrict__ nn, int* __restrict__ deg) {
  int node = blockIdx.x * 256 + threadIdx.x;
  int b12 = node & ~(NPTS - 1);
  int jmax = (node == NBN - 1) ? (KNN - 1) : KNN;
  for (int j = 0; j < jmax; ++j)
    atomicAdd(&deg[b12 + (nn[(size_t)node * KNN + j] & (NPTS - 1))], 1);
}

__global__ __launch_bounds__(256)
void k_dinv(const int* __restrict__ deg, float* __restrict__ dinv) {
  int i = blockIdx.x * 256 + threadIdx.x;
  int dg = deg[i];
  dinv[i] = (dg > 0) ? (1.0f / sqrtf((float)dg)) : 0.0f;
}

#define NQ    4
#define QCOLS (NPTS/NQ)
#define TCOLS 32
#define NTILES (QCOLS/TCOLS)
#define RPB   64

__global__ __launch_bounds__(256)
void k_knn_nb(const float* __restrict__ x, u16* __restrict__ nn) {
  __shared__ __align__(16) float tile[NQ * TCOLS * CH];
  __shared__ float nrmS[NQ * TCOLS];
  __shared__ float csq[NQ * TCOLS];
  int tid = threadIdx.x;
  int r0 = blockIdx.x * RPB;
  int b  = r0 >> 12;
  int q  = tid >> 6;
  int lr = tid & 63;
  int n  = (r0 + lr) & (NPTS - 1);
  const float* xb = x + (size_t)b * CH * NPTS;
  float rf[CH];
#pragma unroll
  for (int c = 0; c < CH; ++c) rf[c] = xb[(size_t)c * NPTS + n];
  float sqn;
  {
    float a0 = 0, a1 = 0, a2 = 0, a3 = 0;
#pragma unroll
    for (int k = 0; k < CH; k += 4) {
      a0 += rf[k] * rf[k]; a1 += rf[k+1] * rf[k+1];
      a2 += rf[k+2] * rf[k+2]; a3 += rf[k+3] * rf[k+3];
    }
    float nrm = fmaxf(sqrtf((a0 + a1) + (a2 + a3)), 1e-12f);
#pragma unroll
    for (int c = 0; c < CH; ++c) rf[c] = rf[c] / nrm;
    a0 = a1 = a2 = a3 = 0;
#pragma unroll
    for (int k = 0; k < CH; k += 4) {
      a0 += rf[k] * rf[k]; a1 += rf[k+1] * rf[k+1];
      a2 += rf[k+2] * rf[k+2]; a3 += rf[k+3] * rf[k+3];
    }
    sqn = (a0 + a1) + (a2 + a3);
  }
  float d[KNN]; int id[KNN];
#pragma unroll
  for (int j = 0; j < KNN; ++j) { d[j] = 3.4e38f; id[j] = 0x7fffffff; }
  for (int t = 0; t < NTILES; ++t) {
    __syncthreads();
#pragma unroll
    for (int qq = 0; qq < NQ; ++qq) {
      int colbase = qq * QCOLS + t * TCOLS;
      float* dst = tile + qq * TCOLS * CH;
#pragma unroll
      for (int it = 0; it < 6; ++it) {
        int i = it * 256 + tid;
        int c = i >> 5, p = i & 31;
        dst[p * CH + c] = xb[(size_t)c * NPTS + colbase + p];
      }
    }
    __syncthreads();
    if (tid < NQ * TCOLS) {
      const float* cp = tile + tid * CH;
      float a0 = 0, a1 = 0, a2 = 0, a3 = 0;
#pragma unroll
      for (int k = 0; k < CH; k += 4) {
        float4 v = *(const float4*)(cp + k);
        a0 += v.x * v.x; a1 += v.y * v.y; a2 += v.z * v.z; a3 += v.w * v.w;
      }
      nrmS[tid] = fmaxf(sqrtf((a0 + a1) + (a2 + a3)), 1e-12f);
    }
    __syncthreads();
    for (int i = tid; i < NQ * TCOLS * CH; i += 256)
      tile[i] = tile[i] / nrmS[i / CH];
    __syncthreads();
    if (tid < NQ * TCOLS) {
      const float* cp = tile + tid * CH;
      float a0 = 0, a1 = 0, a2 = 0, a3 = 0;
#pragma unroll
      for (int k = 0; k < CH; k += 4) {
        float4 v = *(const float4*)(cp + k);
        a0 += v.x * v.x; a1 += v.y * v.y; a2 += v.z * v.z; a3 += v.w * v.w;
      }
      csq[tid] = (a0 + a1) + (a2 + a3);
    }
    __syncthreads();
    int cbase = q * QCOLS + t * TCOLS;
    const float* tq = tile + q * TCOLS * CH;
    for (int cc = 0; cc < TCOLS; ++cc) {
      const float* cp = tq + cc * CH;
      float a0 = 0, a1 = 0, a2 = 0, a3 = 0;
#pragma unroll
      for (int k = 0; k < CH; k += 4) {
        float4 v = *(const float4*)(cp + k);
        a0 += rf[k] * v.x; a1 += rf[k+1] * v.y;
        a2 += rf[k+2] * v.z; a3 += rf[k+3] * v.w;
      }
      float dist = (sqn + csq[q * TCOLS + cc]) - 2.0f * ((a0 + a1) + (a2 + a3));
      if (dist < d[KNN - 1]) {
        d[KNN - 1] = dist; id[KNN - 1] = cbase + cc;
#pragma unroll
        for (int k2 = KNN - 1; k2 > 0; --k2) {
          if (d[k2] < d[k2 - 1]) {
            float td = d[k2]; d[k2] = d[k2 - 1]; d[k2 - 1] = td;
            int ti = id[k2]; id[k2] = id[k2 - 1]; id[k2 - 1] = ti;
          }
        }
      }
    }
  }
  __syncthreads();
  float* md = tile;
  int*   mi = (int*)(tile + 256 * KNN);
#pragma unroll
  for (int j = 0; j < KNN; ++j) { md[tid * KNN + j] = d[j]; mi[tid * KNN + j] = id[j]; }
  __syncthreads();
  if (tid < RPB) {
    float fd[KNN]; int fi[KNN];
#pragma unroll
    for (int j = 0; j < KNN; ++j) { fd[j] = 3.4e38f; fi[j] = 0x7fffffff; }
    for (int qq = 0; qq < NQ; ++qq) {
      int s = qq * RPB + tid;
      for (int j = 0; j < KNN; ++j) {
        float dc = md[s * KNN + j]; int ic = mi[s * KNN + j];
        if (dc < fd[KNN - 1]) {
          fd[KNN - 1] = dc; fi[KNN - 1] = ic;
#pragma unroll
          for (int k2 = KNN - 1; k2 > 0; --k2) {
            if (fd[k2] < fd[k2 - 1]) {
              float td = fd[k2]; fd[k2] = fd[k2 - 1]; fd[k2 - 1] = td;
              int ti = fi[k2]; fi[k2] = fi[k2 - 1]; fi[k2 - 1] = ti;
            }
          }
        }
      }
    }
    u16* o = nn + (size_t)(r0 + tid) * KNN;
#pragma unroll
    for (int j = 0; j < KNN; ++j) o[j] = (u16)(fi[j] & (NPTS - 1));
  }
}

__global__ __launch_bounds__(256)
void k_out_nb(const float* __restrict__ x, const u16* __restrict__ nn,
              const float* __restrict__ dinv,
              const float* __restrict__ W0, const float* __restrict__ W1,
              const float* __restrict__ bias, float* __restrict__ out) {
  __shared__ float w0[CH * CH], w1[CH * CH], bs[CH];
  for (int i = threadIdx.x; i < CH * CH; i += 256) { w0[i] = W0[i]; w1[i] = W1[i]; }
  if (threadIdx.x < CH) bs[threadIdx.x] = bias[threadIdx.x];
  __syncthreads();
  int node = blockIdx.x * 256 + threadIdx.x;
  int b = node >> 12, n = node & (NPTS - 1);
  const float* xb = x + (size_t)b * CH * NPTS;
  float f[CH], acc[CH], tx[CH];
#pragma unroll
  for (int c = 0; c < CH; ++c) f[c] = xb[(size_t)c * NPTS + n];
#pragma unroll
  for (int o = 0; o < CH; ++o) acc[o] = bs[o];
#pragma unroll
  for (int c = 0; c < CH; ++c) {
    float fc = f[c];
    const float* wr = w0 + c * CH;
#pragma unroll
    for (int o = 0; o < CH; ++o) acc[o] += fc * wr[o];
  }
#pragma unroll
  for (int c = 0; c < CH; ++c) tx[c] = 0.f;
  float dn = dinv[node];
  int jmax = (node == NBN - 1) ? (KNN - 1) : KNN;
  for (int j = 0; j < jmax; ++j) {
    int s = nn[(size_t)node * KNN + j] & (NPTS - 1);
    float w = -(dinv[(b << 12) + s] * dn);
#pragma unroll
    for (int c = 0; c < CH; ++c) tx[c] += w * xb[(size_t)c * NPTS + s];
  }
#pragma unroll
  for (int c = 0; c < CH; ++c) {
    float tc = tx[c];
    const float* wr = w1 + c * CH;
#pragma unroll
    for (int o = 0; o < CH; ++o) acc[o] += tc * wr[o];
  }
  float4* op = (float4*)(out + (size_t)node * CH);
#pragma unroll
  for (int i = 0; i < CH / 4; ++i)
    op[i] = make_float4(acc[4*i], acc[4*i+1], acc[4*i+2], acc[4*i+3]);
}

extern "C" void kernel_launch(void* const* d_in, const int* in_sizes, int n_in,
                              void* d_out, int out_size, void* d_ws, size_t ws_size,
                              hipStream_t stream) {
  const float* x    = (const float*)d_in[0];
  const float* W0   = (const float*)d_in[1];
  const float* W1   = (const float*)d_in[2];
  const float* bias = (const float*)d_in[3];
  float* out = (float*)d_out;
  char* w = (char*)d_ws;

  const size_t SZ_XN   = (size_t)NBN * CH * 4;            //  6,291,456
  const size_t SZ_XRAW = (size_t)NBN * CH * 4;            //  6,291,456
  const size_t SZ_CSQ  = (size_t)NBN * 4;                 //    131,072
  const size_t SZ_NN   = (size_t)NBN * KNN * 2;           //    589,824
  const size_t SZ_DEG  = (size_t)NBN * 4;                 //    131,072
  const size_t SZ_AB   = (size_t)NBN * 128 * 2;           //  8,388,608
  const size_t SZ_CU   = (size_t)NBN * 16 * NCAND * 8;    // 50,331,648
  const size_t SZ_C12  = (size_t)NBN * NCAND * 4;         //  1,572,864
  const size_t needF = SZ_XN + SZ_XRAW + SZ_CSQ + SZ_NN + SZ_DEG
                     + 2 * SZ_AB + SZ_CU + SZ_C12;        // ~82.1 MB

  if (ws_size >= needF) {          // FAST path: MFMA filter + reduce + rescore
    size_t off = 0;
    float* xn   = (float*)(w + off); off += SZ_XN;
    float* xraw = (float*)(w + off); off += SZ_XRAW;
    float* csq  = (float*)(w + off); off += SZ_CSQ;
    u16*   nn   = (u16*)  (w + off); off += SZ_NN;
    int*   deg  = (int*)  (w + off); off += SZ_DEG;
    u16*   Abuf = (u16*)  (w + off); off += SZ_AB;
    u16*   Bbuf = (u16*)  (w + off); off += SZ_AB;
    u64*   candu= (u64*)  (w + off); off += SZ_CU;
    u32*   cand12=(u32*)  (w + off);
    k_prep    <<<NBN / 256, 256, 0, stream>>>(x, xraw, xn, csq, Abuf, Bbuf, deg);
    k_knn_m   <<<dim3(NBN / 64, 4), 256, 0, stream>>>(Abuf, Bbuf, candu);
    k_reduce  <<<NBN / 64, 256, 0, stream>>>(candu, cand12);
    k_rescore <<<NBN / RR, 256, 0, stream>>>(xn, csq, cand12, nn, deg);
    k_out_f   <<<NBN / ONB, 256, 0, stream>>>(xraw, nn, deg, W0, W1, bias, out);
  } else {                         // FALLBACK: proven round-4 path (852 KB)
    u16*   nn   = (u16*)w;
    int*   deg  = (int*)(w + SZ_NN);
    float* dinv = (float*)(w + SZ_NN + SZ_DEG);
    k_knn_nb <<<NBN / RPB, 256, 0, stream>>>(x, nn);
    k_zero   <<<NBN / 256, 256, 0, stream>>>(deg);
    k_hist   <<<NBN / 256, 256, 0, stream>>>(nn, deg);
    k_dinv   <<<NBN / 256, 256, 0, stream>>>(deg, dinv);
    k_out_nb <<<NBN / 256, 256, 0, stream>>>(x, nn, dinv, W0, W1, bias, out);
  }
}

// Round 3
// 240.104 us; speedup vs baseline: 1.1784x; 1.0427x over previous
//
#include <hip/hip_runtime.h>

#define BATCH 8
#define CH    48
#define NPTS  4096
#define NBN   (BATCH*NPTS)
#define KNN   9
#define NCAND 12             // per-lane filter depth

typedef unsigned short u16;
typedef unsigned int   u32;
typedef unsigned long long u64;
typedef __bf16 bf16x8 __attribute__((ext_vector_type(8)));
typedef float  f32x4  __attribute__((ext_vector_type(4)));

__device__ __forceinline__ float bf2f(u16 v) { return __uint_as_float(((u32)v) << 16); }
__device__ __forceinline__ u16 f2bf(float f) {
  u32 u = __float_as_uint(f);
  u = (u + 0x7fffu + ((u >> 16) & 1u)) >> 16;
  return (u16)u;
}

// ======================= FAST PATH (ws >= ~83 MB) =======================
// k_prep: normalize per reference; write xraw/xn fp32 node-major, csq;
// build hi/lo-split bf16 operands. A layout MFMA-coalesced:
// [tile16][variant(4)][lane(64)][8 bf16]; B [node][128]. Zero deg.
__global__ __launch_bounds__(256)
void k_prep(const float* __restrict__ x, float* __restrict__ xraw,
            float* __restrict__ xn, float* __restrict__ csq,
            u16* __restrict__ Abuf, u16* __restrict__ Bbuf,
            int* __restrict__ deg) {
  int node = blockIdx.x * 256 + threadIdx.x;
  deg[node] = 0;
  int b = node >> 12, n = node & (NPTS - 1);
  const float* xb = x + (size_t)b * CH * NPTS;
  float f[CH];
#pragma unroll
  for (int c = 0; c < CH; ++c) f[c] = xb[(size_t)c * NPTS + n];
  float a0 = 0, a1 = 0, a2 = 0, a3 = 0;
#pragma unroll
  for (int k = 0; k < CH; k += 4) {
    a0 += f[k] * f[k]; a1 += f[k+1] * f[k+1];
    a2 += f[k+2] * f[k+2]; a3 += f[k+3] * f[k+3];
  }
  float nrm = fmaxf(sqrtf((a0 + a1) + (a2 + a3)), 1e-12f);
  float xv[CH];
#pragma unroll
  for (int c = 0; c < CH; ++c) xv[c] = f[c] / nrm;     // true division (ref)
  a0 = a1 = a2 = a3 = 0;
#pragma unroll
  for (int k = 0; k < CH; k += 4) {
    a0 += xv[k] * xv[k]; a1 += xv[k+1] * xv[k+1];
    a2 += xv[k+2] * xv[k+2]; a3 += xv[k+3] * xv[k+3];
  }
  float csqv = (a0 + a1) + (a2 + a3);
  csq[node] = csqv;
  float4* ro = (float4*)(xraw + (size_t)node * CH);
  float4* no = (float4*)(xn   + (size_t)node * CH);
#pragma unroll
  for (int i = 0; i < CH / 4; ++i) {
    ro[i] = make_float4(f[4*i], f[4*i+1], f[4*i+2], f[4*i+3]);
    no[i] = make_float4(xv[4*i], xv[4*i+1], xv[4*i+2], xv[4*i+3]);
  }
  u16 ah[64], al[64];
#pragma unroll
  for (int k = 0; k < CH; ++k) {
    float av = -2.0f * xv[k];
    u16 h = f2bf(av); ah[k] = h; al[k] = f2bf(av - bf2f(h));
  }
  { u16 h = f2bf(csqv); ah[48] = h; al[48] = f2bf(csqv - bf2f(h)); }
#pragma unroll
  for (int k = 49; k < 64; ++k) { ah[k] = 0; al[k] = 0; }
  u16* Bh = Bbuf + (size_t)node * 128;
#pragma unroll
  for (int k = 0; k < CH; ++k) {
    float bv = xv[k];
    u16 h = f2bf(bv); Bh[k] = h; Bh[64 + k] = f2bf(bv - bf2f(h));
  }
  Bh[48] = 0x3F80; Bh[64 + 48] = 0;            // 1.0 bf16 exact
#pragma unroll
  for (int k = 49; k < 64; ++k) { Bh[k] = 0; Bh[64 + k] = 0; }
  u16* Ag = Abuf + (size_t)(node >> 4) * 2048 + (size_t)(node & 15) * 8;
#pragma unroll
  for (int v = 0; v < 4; ++v) {
    const u16* src = (v < 2) ? ah : al;
    int koff = (v & 1) * 32;
#pragma unroll
    for (int q = 0; q < 4; ++q) {
      uint4 pk;
      const u16* s = src + koff + q * 8;
      pk.x = (u32)s[0] | ((u32)s[1] << 16);
      pk.y = (u32)s[2] | ((u32)s[3] << 16);
      pk.z = (u32)s[4] | ((u32)s[5] << 16);
      pk.w = (u32)s[6] | ((u32)s[7] << 16);
      *(uint4*)(Ag + v * 512 + q * 128) = pk;
    }
  }
}

// k_knn_m: wave = 16-row panel; blockIdx.y = column quarter (64 tiles of 16).
// 6 MFMAs/tile (hh,hl,lh). Top-12 filter via single-instruction v_med3_u32
// insertion: inserting x into sorted s0<=...<=s11 (drop max) is
//   s_i' = med3(s_{i-1}, s_i, x)  (i=11..1, old values),  s0' = min(s0, x).
// KEY RANGE: MFMA computes csq_col - 2<x_col,x_row> in [-1-eps, 3+eps];
// acc bias +2.5 maps keys to [~1.5, ~5.5] -- strictly positive, raw-bits
// order-preserving. Epilogue emits u64 = (key << 12) | global_col.
// PIPELINE: explicit 1-deep prefetch of next tile's A fragments in named
// registers; __launch_bounds__(256,6) lifts the 32-VGPR ceiling that was
// serializing loads into the dependency chain (VGPR 32 -> ~70).
#define MED3(d, a, b, c) \
  asm("v_med3_u32 %0, %1, %2, %3" : "=v"(d) : "v"(a), "v"(b), "v"(c))
#define INSERT12(x) do { \
  MED3(s11, s10, s11, x); MED3(s10, s9, s10, x); MED3(s9, s8, s9, x);  \
  MED3(s8,  s7,  s8,  x); MED3(s7,  s6, s7,  x); MED3(s6, s5, s6, x);  \
  MED3(s5,  s4,  s5,  x); MED3(s4,  s3, s4,  x); MED3(s3, s2, s3, x);  \
  MED3(s2,  s1,  s2,  x); MED3(s1,  s0, s1,  x); s0 = min(s0, x);      \
} while (0)

__global__ __launch_bounds__(256, 6)
void k_knn_m(const u16* __restrict__ Abuf, const u16* __restrict__ Bbuf,
             u64* __restrict__ candu) {
  int tid = threadIdx.x;
  int lane = tid & 63;
  int quad = lane >> 4, m16 = lane & 15;
  int panel = blockIdx.x * 4 + (tid >> 6);
  int row = panel * 16 + m16;
  int b4096 = row & ~(NPTS - 1);
  int quarter = blockIdx.y;
  int ct0 = quarter * 64;

  const __bf16* Bb = (const __bf16*)Bbuf + (size_t)row * 128;
  bf16x8 bh0 = *(const bf16x8*)(Bb + quad * 8);
  bf16x8 bh1 = *(const bf16x8*)(Bb + 32 + quad * 8);
  bf16x8 bl0 = *(const bf16x8*)(Bb + 64 + quad * 8);
  bf16x8 bl1 = *(const bf16x8*)(Bb + 96 + quad * 8);

  const __bf16* Ag = (const __bf16*)Abuf + (size_t)(b4096 >> 4) * 2048
                     + (size_t)lane * 8 + (size_t)ct0 * 2048;

  u32 s0=~0u,s1=~0u,s2=~0u,s3=~0u,s4=~0u,s5=~0u,
      s6=~0u,s7=~0u,s8=~0u,s9=~0u,s10=~0u,s11=~0u;

  // prologue: load tile 0
  bf16x8 a0 = *(const bf16x8*)(Ag);
  bf16x8 a1 = *(const bf16x8*)(Ag + 512);
  bf16x8 a2 = *(const bf16x8*)(Ag + 1024);
  bf16x8 a3 = *(const bf16x8*)(Ag + 1536);

  for (int t = 0; t < 64; ++t) {
    // prefetch tile t+1 (clamped: last iter redundantly reloads tile 63)
    const __bf16* apn = Ag + (size_t)((t < 63) ? (t + 1) : 63) * 2048;
    bf16x8 n0 = *(const bf16x8*)(apn);
    bf16x8 n1 = *(const bf16x8*)(apn + 512);
    bf16x8 n2 = *(const bf16x8*)(apn + 1024);
    bf16x8 n3 = *(const bf16x8*)(apn + 1536);

    f32x4 acc = {2.5f, 2.5f, 2.5f, 2.5f};   // +2.5 bias: keys strictly positive
    acc = __builtin_amdgcn_mfma_f32_16x16x32_bf16(a0, bh0, acc, 0, 0, 0);
    acc = __builtin_amdgcn_mfma_f32_16x16x32_bf16(a1, bh1, acc, 0, 0, 0);
    acc = __builtin_amdgcn_mfma_f32_16x16x32_bf16(a0, bl0, acc, 0, 0, 0);
    acc = __builtin_amdgcn_mfma_f32_16x16x32_bf16(a1, bl1, acc, 0, 0, 0);
    acc = __builtin_amdgcn_mfma_f32_16x16x32_bf16(a2, bh0, acc, 0, 0, 0);
    acc = __builtin_amdgcn_mfma_f32_16x16x32_bf16(a3, bh1, acc, 0, 0, 0);
    int ct = ct0 + t;
#pragma unroll
    for (int r = 0; r < 4; ++r) {
      u32 u = __float_as_uint(acc[r]);               // positive -> monotone
      u32 x = (u & 0xFFFFFC00u) | (u32)((ct << 2) | r);
      INSERT12(x);
    }
    a0 = n0; a1 = n1; a2 = n2; a3 = n3;
  }

  u64* o = candu + (((size_t)row * 4 + quarter) * 4 + quad) * NCAND;
#define EMIT(j, sv) { u32 col = ((sv & 0x3FFu) >> 2) * 16 + quad * 4 + (sv & 3u); \
                      o[j] = ((u64)sv << 12) | (u64)col; }
  EMIT(0, s0)  EMIT(1, s1)  EMIT(2, s2)  EMIT(3, s3)
  EMIT(4, s4)  EMIT(5, s5)  EMIT(6, s6)  EMIT(7, s7)
  EMIT(8, s8)  EMIT(9, s9)  EMIT(10, s10) EMIT(11, s11)
#undef EMIT
}

// k_reduce: per row, top-12 of the 192 u64 candidates (coalesced reads, no
// feature gathers). 64 rows/block x 4 threads/row; branchless u64 STEP
// network in named registers; 2-stage (48 each -> 48 merged by thread 0).
#define STEP64(si) { u64 _lo = (x < si) ? x : si; u64 _hi = (x < si) ? si : x; \
                     si = _lo; x = _hi; }
__global__ __launch_bounds__(256, 4)
void k_reduce(const u64* __restrict__ candu, u32* __restrict__ cand12) {
  __shared__ u64 ls[64 * 4 * NCAND];   // 24,576 B
  int tid = threadIdx.x;
  int lr = tid >> 2, q = tid & 3;
  int row = blockIdx.x * 64 + lr;
  const u64* src = candu + (size_t)row * 192 + q * 48;
  u64 t0=~0ull,t1=~0ull,t2=~0ull,t3=~0ull,t4=~0ull,t5=~0ull,
      t6=~0ull,t7=~0ull,t8=~0ull,t9=~0ull,t10=~0ull,t11=~0ull;
  for (int s = 0; s < 48; ++s) {
    u64 x = src[s];
    STEP64(t0) STEP64(t1) STEP64(t2) STEP64(t3) STEP64(t4) STEP64(t5)
    STEP64(t6) STEP64(t7) STEP64(t8) STEP64(t9) STEP64(t10) STEP64(t11)
  }
  u64* lw = ls + (size_t)(lr * 4 + q) * NCAND;
  lw[0]=t0; lw[1]=t1; lw[2]=t2; lw[3]=t3; lw[4]=t4; lw[5]=t5;
  lw[6]=t6; lw[7]=t7; lw[8]=t8; lw[9]=t9; lw[10]=t10; lw[11]=t11;
  __syncthreads();
  if (q == 0) {
    u64 g0=~0ull,g1=~0ull,g2=~0ull,g3=~0ull,g4=~0ull,g5=~0ull,
        g6=~0ull,g7=~0ull,g8=~0ull,g9=~0ull,g10=~0ull,g11=~0ull;
    const u64* lsrc = ls + (size_t)lr * 48;
    for (int s = 0; s < 48; ++s) {
      u64 x = lsrc[s];
      STEP64(g0) STEP64(g1) STEP64(g2) STEP64(g3) STEP64(g4) STEP64(g5)
      STEP64(g6) STEP64(g7) STEP64(g8) STEP64(g9) STEP64(g10) STEP64(g11)
    }
    u32* o = cand12 + (size_t)row * NCAND;
    o[0]=(u32)(g0&0xFFFu); o[1]=(u32)(g1&0xFFFu); o[2]=(u32)(g2&0xFFFu);
    o[3]=(u32)(g3&0xFFFu); o[4]=(u32)(g4&0xFFFu); o[5]=(u32)(g5&0xFFFu);
    o[6]=(u32)(g6&0xFFFu); o[7]=(u32)(g7&0xFFFu); o[8]=(u32)(g8&0xFFFu);
    o[9]=(u32)(g9&0xFFFu); o[10]=(u32)(g10&0xFFFu); o[11]=(u32)(g11&0xFFFu);
  }
}

// k_rescore: 16 rows/block x 16 threads/row; threads 0..11 each gather ONE
// candidate row and compute the exact fp32 dist (proven formula); thread 0
// merges 12 with the exact (dist, idx) comparator -> top-9. Fused nn write
// + degree histogram (tail edge drop). Only 12 gathers/row.
#define RR 16
__global__ __launch_bounds__(256, 4)
void k_rescore(const float* __restrict__ xn, const float* __restrict__ csq,
               const u32* __restrict__ cand12,
               u16* __restrict__ nn, int* __restrict__ deg) {
  __shared__ float dS[RR * NCAND];
  __shared__ int   iS[RR * NCAND];
  int tid = threadIdx.x;
  int lr = tid >> 4, q = tid & 15;
  int bi = blockIdx.x;
  int row = (bi & 7) * NPTS + (bi >> 3) * RR + lr;   // XCD swizzle (perf-only)
  int b4096 = row & ~(NPTS - 1);
  const float* xnb = xn + (size_t)b4096 * CH;
  if (q < NCAND) {
    float rf[CH];
    const float4* p = (const float4*)(xn + (size_t)row * CH);
#pragma unroll
    for (int i = 0; i < CH / 4; ++i) {
      float4 v = p[i];
      rf[4*i] = v.x; rf[4*i+1] = v.y; rf[4*i+2] = v.z; rf[4*i+3] = v.w;
    }
    float sqn = csq[row];
    int c = (int)(cand12[(size_t)row * NCAND + q] & (NPTS - 1));
    const float4* cp = (const float4*)(xnb + (size_t)c * CH);
    float a0 = 0, a1 = 0, a2 = 0, a3 = 0;
#pragma unroll
    for (int i = 0; i < CH / 4; ++i) {
      float4 v = cp[i];
      a0 += rf[4*i]   * v.x; a1 += rf[4*i+1] * v.y;
      a2 += rf[4*i+2] * v.z; a3 += rf[4*i+3] * v.w;
    }
    float dist = (sqn + csq[b4096 + c]) - 2.0f * ((a0 + a1) + (a2 + a3));
    dS[lr * NCAND + q] = dist;
    iS[lr * NCAND + q] = c;
  }
  __syncthreads();
  if (q == 0) {
    float gd[KNN]; int gi[KNN];
#pragma unroll
    for (int j = 0; j < KNN; ++j) { gd[j] = 3.4e38f; gi[j] = 0x7fffffff; }
    for (int s = 0; s < NCAND; ++s) {
      float dc = dS[lr * NCAND + s]; int ic = iS[lr * NCAND + s];
      if (dc < gd[KNN - 1] || (dc == gd[KNN - 1] && ic < gi[KNN - 1])) {
        gd[KNN - 1] = dc; gi[KNN - 1] = ic;
#pragma unroll
        for (int k2 = KNN - 1; k2 > 0; --k2) {
          bool sw = (gd[k2] < gd[k2 - 1]) ||
                    (gd[k2] == gd[k2 - 1] && gi[k2] < gi[k2 - 1]);
          if (sw) {
            float td = gd[k2]; gd[k2] = gd[k2 - 1]; gd[k2 - 1] = td;
            int ti = gi[k2]; gi[k2] = gi[k2 - 1]; gi[k2 - 1] = ti;
          }
        }
      }
    }
    u16* o = nn + (size_t)row * KNN;
    int jmax = (row == NBN - 1) ? (KNN - 1) : KNN;   // linspace tail drop
#pragma unroll
    for (int j = 0; j < KNN; ++j) o[j] = (u16)(gi[j] & (NPTS - 1));
    for (int j = 0; j < jmax; ++j)
      atomicAdd(&deg[b4096 + (gi[j] & (NPTS - 1))], 1);
  }
}

// k_out: 64 nodes/block x 4 threads/node (12 out-channels each), XCD swizzle.
#define ONB 64
#define LPAD 52
__global__ __launch_bounds__(256)
void k_out_f(const float* __restrict__ xraw, const u16* __restrict__ nn,
             const int* __restrict__ deg,
             const float* __restrict__ W0, const float* __restrict__ W1,
             const float* __restrict__ bias, float* __restrict__ out) {
  __shared__ float w0[CH * CH], w1[CH * CH], bs[CH];
  __shared__ __align__(16) float fS[ONB * LPAD];
  __shared__ __align__(16) float txS[ONB * LPAD];
  __shared__ float dinvS[ONB];
  int tid = threadIdx.x;
  int bi = blockIdx.x;
  int n0 = (bi & 7) * NPTS + (bi >> 3) * ONB;   // XCD swizzle (perf-only)
  int b12 = n0 & ~(NPTS - 1);
  for (int i = tid; i < CH * CH; i += 256) { w0[i] = W0[i]; w1[i] = W1[i]; }
  if (tid < CH) bs[tid] = bias[tid];
  for (int i = tid; i < ONB * 12; i += 256) {
    int ln = i / 12, f4 = i % 12;
    *(float4*)(fS + ln * LPAD + f4 * 4) =
        *(const float4*)(xraw + (size_t)(n0 + ln) * CH + f4 * 4);
  }
  if (tid < ONB) {
    int dg = deg[n0 + tid];
    dinvS[tid] = (dg > 0) ? (1.0f / sqrtf((float)dg)) : 0.0f;
  }
  __syncthreads();

  int ln = tid >> 2, p = tid & 3;
  int node = n0 + ln;
  float dn = dinvS[ln];
  const u16* nrow = nn + (size_t)node * KNN;
  bool full = (node != NBN - 1);
  float tx[12];
#pragma unroll
  for (int i = 0; i < 12; ++i) tx[i] = 0.f;
#pragma unroll
  for (int j = 0; j < KNN; ++j) {
    if (j < KNN - 1 || full) {
      int s = nrow[j] & (NPTS - 1);
      int dgs = deg[b12 + s];
      float ds = (dgs > 0) ? (1.0f / sqrtf((float)dgs)) : 0.0f;
      float w = -(ds * dn);
      const float4* pr = (const float4*)(xraw + (size_t)(b12 + s) * CH + p * 12);
#pragma unroll
      for (int q3 = 0; q3 < 3; ++q3) {
        float4 v = pr[q3];
        tx[q3*4]   += w * v.x; tx[q3*4+1] += w * v.y;
        tx[q3*4+2] += w * v.z; tx[q3*4+3] += w * v.w;
      }
    }
  }
#pragma unroll
  for (int q3 = 0; q3 < 3; ++q3)
    *(float4*)(txS + ln * LPAD + p * 12 + q3 * 4) =
        make_float4(tx[q3*4], tx[q3*4+1], tx[q3*4+2], tx[q3*4+3]);
  __syncthreads();

  float acc[12];
#pragma unroll
  for (int i = 0; i < 12; ++i) acc[i] = bs[p * 12 + i];
  const float* fr = fS + ln * LPAD;
  const float* tr = txS + ln * LPAD;
#pragma unroll
  for (int c = 0; c < CH; ++c) {
    float fc = fr[c];
    const float* wr = w0 + c * CH + p * 12;
#pragma unroll
    for (int i = 0; i < 12; ++i) acc[i] += fc * wr[i];
  }
#pragma unroll
  for (int c = 0; c < CH; ++c) {
    float tc = tr[c];
    const float* wr = w1 + c * CH + p * 12;
#pragma unroll
    for (int i = 0; i < 12; ++i) acc[i] += tc * wr[i];
  }
  float* op = out + (size_t)node * CH + p * 12;
#pragma unroll
  for (int q3 = 0; q3 < 3; ++q3)
    *(float4*)(op + q3 * 4) =
        make_float4(acc[q3*4], acc[q3*4+1], acc[q3*4+2], acc[q3*4+3]);
}

// ======================= FALLBACK (round-4, proven) =======================
__global__ __launch_bounds__(256)
void k_zero(int* __restrict__ deg) { deg[blockIdx.x * 256 + threadIdx.x] = 0; }

__global__ __launch_bounds__(256)
void k_hist(const u16* __restrict__ nn, int* __restrict__ deg) {
  int node = blockIdx.x * 256 + threadIdx.x;
  int b12 = node & ~(NPTS - 1);
  int jmax = (node == NBN - 1) ? (KNN - 1) : KNN;
  for (int j = 0; j < jmax; ++j)
    atomicAdd(&deg[b12 + (nn[(size_t)node * KNN + j] & (NPTS - 1))], 1);
}

__global__ __launch_bounds__(256)
void k_dinv(const int* __restrict__ deg, float* __restrict__ dinv) {
  int i = blockIdx.x * 256 + threadIdx.x;
  int dg = deg[i];
  dinv[i] = (dg > 0) ? (1.0f / sqrtf((float)dg)) : 0.0f;
}

#define NQ    4
#define QCOLS (NPTS/NQ)
#define TCOLS 32
#define NTILES (QCOLS/TCOLS)
#define RPB   64

__global__ __launch_bounds__(256)
void k_knn_nb(const float* __restrict__ x, u16* __restrict__ nn) {
  __shared__ __align__(16) float tile[NQ * TCOLS * CH];
  __shared__ float nrmS[NQ * TCOLS];
  __shared__ float csq[NQ * TCOLS];
  int tid = threadIdx.x;
  int r0 = blockIdx.x * RPB;
  int b  = r0 >> 12;
  int q  = tid >> 6;
  int lr = tid & 63;
  int n  = (r0 + lr) & (NPTS - 1);
  const float* xb = x + (size_t)b * CH * NPTS;
  float rf[CH];
#pragma unroll
  for (int c = 0; c < CH; ++c) rf[c] = xb[(size_t)c * NPTS + n];
  float sqn;
  {
    float a0 = 0, a1 = 0, a2 = 0, a3 = 0;
#pragma unroll
    for (int k = 0; k < CH; k += 4) {
      a0 += rf[k] * rf[k]; a1 += rf[k+1] * rf[k+1];
      a2 += rf[k+2] * rf[k+2]; a3 += rf[k+3] * rf[k+3];
    }
    float nrm = fmaxf(sqrtf((a0 + a1) + (a2 + a3)), 1e-12f);
#pragma unroll
    for (int c = 0; c < CH; ++c) rf[c] = rf[c] / nrm;
    a0 = a1 = a2 = a3 = 0;
#pragma unroll
    for (int k = 0; k < CH; k += 4) {
      a0 += rf[k] * rf[k]; a1 += rf[k+1] * rf[k+1];
      a2 += rf[k+2] * rf[k+2]; a3 += rf[k+3] * rf[k+3];
    }
    sqn = (a0 + a1) + (a2 + a3);
  }
  float d[KNN]; int id[KNN];
#pragma unroll
  for (int j = 0; j < KNN; ++j) { d[j] = 3.4e38f; id[j] = 0x7fffffff; }
  for (int t = 0; t < NTILES; ++t) {
    __syncthreads();
#pragma unroll
    for (int qq = 0; qq < NQ; ++qq) {
      int colbase = qq * QCOLS + t * TCOLS;
      float* dst = tile + qq * TCOLS * CH;
#pragma unroll
      for (int it = 0; it < 6; ++it) {
        int i = it * 256 + tid;
        int c = i >> 5, p = i & 31;
        dst[p * CH + c] = xb[(size_t)c * NPTS + colbase + p];
      }
    }
    __syncthreads();
    if (tid < NQ * TCOLS) {
      const float* cp = tile + tid * CH;
      float a0 = 0, a1 = 0, a2 = 0, a3 = 0;
#pragma unroll
      for (int k = 0; k < CH; k += 4) {
        float4 v = *(const float4*)(cp + k);
        a0 += v.x * v.x; a1 += v.y * v.y; a2 += v.z * v.z; a3 += v.w * v.w;
      }
      nrmS[tid] = fmaxf(sqrtf((a0 + a1) + (a2 + a3)), 1e-12f);
    }
    __syncthreads();
    for (int i = tid; i < NQ * TCOLS * CH; i += 256)
      tile[i] = tile[i] / nrmS[i / CH];
    __syncthreads();
    if (tid < NQ * TCOLS) {
      const float* cp = tile + tid * CH;
      float a0 = 0, a1 = 0, a2 = 0, a3 = 0;
#pragma unroll
      for (int k = 0; k < CH; k += 4) {
        float4 v = *(const float4*)(cp + k);
        a0 += v.x * v.x; a1 += v.y * v.y; a2 += v.z * v.z; a3 += v.w * v.w;
      }
      csq[tid] = (a0 + a1) + (a2 + a3);
    }
    __syncthreads();
    int cbase = q * QCOLS + t * TCOLS;
    const float* tq = tile + q * TCOLS * CH;
    for (int cc = 0; cc < TCOLS; ++cc) {
      const float* cp = tq + cc * CH;
      float a0 = 0, a1 = 0, a2 = 0, a3 = 0;
#pragma unroll
      for (int k = 0; k < CH; k += 4) {
        float4 v = *(const float4*)(cp + k);
        a0 += rf[k] * v.x; a1 += rf[k+1] * v.y;
        a2 += rf[k+2] * v.z; a3 += rf[k+3] * v.w;
      }
      float dist = (sqn + csq[q * TCOLS + cc]) - 2.0f * ((a0 + a1) + (a2 + a3));
      if (dist < d[KNN - 1]) {
        d[KNN - 1] = dist; id[KNN - 1] = cbase + cc;
#pragma unroll
        for (int k2 = KNN - 1; k2 > 0; --k2) {
          if (d[k2] < d[k2 - 1]) {
            float td = d[k2]; d[k2] = d[k2 - 1]; d[k2 - 1] = td;
            int ti = id[k2]; id[k2] = id[k2 - 1]; id[k2 - 1] = ti;
          }
        }
      }
    }
  }
  __syncthreads();
  float* md = tile;
  int*   mi = (int*)(tile + 256 * KNN);
#pragma unroll
  for (int j = 0; j < KNN; ++j) { md[tid * KNN + j] = d[j]; mi[tid * KNN + j] = id[j]; }
  __syncthreads();
  if (tid < RPB) {
    float fd[KNN]; int fi[KNN];
#pragma unroll
    for (int j = 0; j < KNN; ++j) { fd[j] = 3.4e38f; fi[j] = 0x7fffffff; }
    for (int qq = 0; qq < NQ; ++qq) {
      int s = qq * RPB + tid;
      for (int j = 0; j < KNN; ++j) {
        float dc = md[s * KNN + j]; int ic = mi[s * KNN + j];
        if (dc < fd[KNN - 1]) {
          fd[KNN - 1] = dc; fi[KNN - 1] = ic;
#pragma unroll
          for (int k2 = KNN - 1; k2 > 0; --k2) {
            if (fd[k2] < fd[k2 - 1]) {
              float td = fd[k2]; fd[k2] = fd[k2 - 1]; fd[k2 - 1] = td;
              int ti = fi[k2]; fi[k2] = fi[k2 - 1]; fi[k2 - 1] = ti;
            }
          }
        }
      }
    }
    u16* o = nn + (size_t)(r0 + tid) * KNN;
#pragma unroll
    for (int j = 0; j < KNN; ++j) o[j] = (u16)(fi[j] & (NPTS - 1));
  }
}

__global__ __launch_bounds__(256)
void k_out_nb(const float* __restrict__ x, const u16* __restrict__ nn,
              const float* __restrict__ dinv,
              const float* __restrict__ W0, const float* __restrict__ W1,
              const float* __restrict__ bias, float* __restrict__ out) {
  __shared__ float w0[CH * CH], w1[CH * CH], bs[CH];
  for (int i = threadIdx.x; i < CH * CH; i += 256) { w0[i] = W0[i]; w1[i] = W1[i]; }
  if (threadIdx.x < CH) bs[threadIdx.x] = bias[threadIdx.x];
  __syncthreads();
  int node = blockIdx.x * 256 + threadIdx.x;
  int b = node >> 12, n = node & (NPTS - 1);
  const float* xb = x + (size_t)b * CH * NPTS;
  float f[CH], acc[CH], tx[CH];
#pragma unroll
  for (int c = 0; c < CH; ++c) f[c] = xb[(size_t)c * NPTS + n];
#pragma unroll
  for (int o = 0; o < CH; ++o) acc[o] = bs[o];
#pragma unroll
  for (int c = 0; c < CH; ++c) {
    float fc = f[c];
    const float* wr = w0 + c * CH;
#pragma unroll
    for (int o = 0; o < CH; ++o) acc[o] += fc * wr[o];
  }
#pragma unroll
  for (int c = 0; c < CH; ++c) tx[c] = 0.f;
  float dn = dinv[node];
  int jmax = (node == NBN - 1) ? (KNN - 1) : KNN;
  for (int j = 0; j < jmax; ++j) {
    int s = nn[(size_t)node * KNN + j] & (NPTS - 1);
    float w = -(dinv[(b << 12) + s] * dn);
#pragma unroll
    for (int c = 0; c < CH; ++c) tx[c] += w * xb[(size_t)c * NPTS + s];
  }
#pragma unroll
  for (int c = 0; c < CH; ++c) {
    float tc = tx[c];
    const float* wr = w1 + c * CH;
#pragma unroll
    for (int o = 0; o < CH; ++o) acc[o] += tc * wr[o];
  }
  float4* op = (float4*)(out + (size_t)node * CH);
#pragma unroll
  for (int i = 0; i < CH / 4; ++i)
    op[i] = make_float4(acc[4*i], acc[4*i+1], acc[4*i+2], acc[4*i+3]);
}

extern "C" void kernel_launch(void* const* d_in, const int* in_sizes, int n_in,
                              void* d_out, int out_size, void* d_ws, size_t ws_size,
                              hipStream_t stream) {
  const float* x    = (const float*)d_in[0];
  const float* W0   = (const float*)d_in[1];
  const float* W1   = (const float*)d_in[2];
  const float* bias = (const float*)d_in[3];
  float* out = (float*)d_out;
  char* w = (char*)d_ws;

  const size_t SZ_XN   = (size_t)NBN * CH * 4;            //  6,291,456
  const size_t SZ_XRAW = (size_t)NBN * CH * 4;            //  6,291,456
  const size_t SZ_CSQ  = (size_t)NBN * 4;                 //    131,072
  const size_t SZ_NN   = (size_t)NBN * KNN * 2;           //    589,824
  const size_t SZ_DEG  = (size_t)NBN * 4;                 //    131,072
  const size_t SZ_AB   = (size_t)NBN * 128 * 2;           //  8,388,608
  const size_t SZ_CU   = (size_t)NBN * 16 * NCAND * 8;    // 50,331,648
  const size_t SZ_C12  = (size_t)NBN * NCAND * 4;         //  1,572,864
  const size_t needF = SZ_XN + SZ_XRAW + SZ_CSQ + SZ_NN + SZ_DEG
                     + 2 * SZ_AB + SZ_CU + SZ_C12;        // ~82.1 MB

  if (ws_size >= needF) {          // FAST path: MFMA filter + reduce + rescore
    size_t off = 0;
    float* xn   = (float*)(w + off); off += SZ_XN;
    float* xraw = (float*)(w + off); off += SZ_XRAW;
    float* csq  = (float*)(w + off); off += SZ_CSQ;
    u16*   nn   = (u16*)  (w + off); off += SZ_NN;
    int*   deg  = (int*)  (w + off); off += SZ_DEG;
    u16*   Abuf = (u16*)  (w + off); off += SZ_AB;
    u16*   Bbuf = (u16*)  (w + off); off += SZ_AB;
    u64*   candu= (u64*)  (w + off); off += SZ_CU;
    u32*   cand12=(u32*)  (w + off);
    k_prep    <<<NBN / 256, 256, 0, stream>>>(x, xraw, xn, csq, Abuf, Bbuf, deg);
    k_knn_m   <<<dim3(NBN / 64, 4), 256, 0, stream>>>(Abuf, Bbuf, candu);
    k_reduce  <<<NBN / 64, 256, 0, stream>>>(candu, cand12);
    k_rescore <<<NBN / RR, 256, 0, stream>>>(xn, csq, cand12, nn, deg);
    k_out_f   <<<NBN / ONB, 256, 0, stream>>>(xraw, nn, deg, W0, W1, bias, out);
  } else {                         // FALLBACK: proven round-4 path (852 KB)
    u16*   nn   = (u16*)w;
    int*   deg  = (int*)(w + SZ_NN);
    float* dinv = (float*)(w + SZ_NN + SZ_DEG);
    k_knn_nb <<<NBN / RPB, 256, 0, stream>>>(x, nn);
    k_zero   <<<NBN / 256, 256, 0, stream>>>(deg);
    k_hist   <<<NBN / 256, 256, 0, stream>>>(nn, deg);
    k_dinv   <<<NBN / 256, 256, 0, stream>>>(deg, dinv);
    k_out_nb <<<NBN / 256, 256, 0, stream>>>(x, nn, dinv, W0, W1, bias, out);
  }
}

// Round 4
// 225.497 us; speedup vs baseline: 1.2547x; 1.0648x over previous
//
#include <hip/hip_runtime.h>

#define BATCH 8
#define CH    48
#define NPTS  4096
#define NBN   (BATCH*NPTS)
#define KNN   9
#define NCAND 12             // per-lane filter depth

typedef unsigned short u16;
typedef unsigned int   u32;
typedef unsigned long long u64;
typedef __bf16 bf16x8 __attribute__((ext_vector_type(8)));
typedef float  f32x4  __attribute__((ext_vector_type(4)));

__device__ __forceinline__ float bf2f(u16 v) { return __uint_as_float(((u32)v) << 16); }
__device__ __forceinline__ u16 f2bf(float f) {
  u32 u = __float_as_uint(f);
  u = (u + 0x7fffu + ((u >> 16) & 1u)) >> 16;
  return (u16)u;
}

// Shared med3 insert: insert x into sorted p0<=...<=p11 keeping smallest 12.
//   p_i' = med3(p_{i-1}, p_i, x) (i=11..1, old values), p0' = min(p0, x).
#define MED3U(d, a, b, c) \
  asm("v_med3_u32 %0, %1, %2, %3" : "=v"(d) : "v"(a), "v"(b), "v"(c))
#define INS12(p0,p1,p2,p3,p4,p5,p6,p7,p8,p9,p10,p11,x) do { \
  MED3U(p11,p10,p11,x); MED3U(p10,p9,p10,x); MED3U(p9,p8,p9,x);  \
  MED3U(p8, p7, p8, x); MED3U(p7, p6,p7, x); MED3U(p6,p5,p6,x);  \
  MED3U(p5, p4, p5, x); MED3U(p4, p3,p4, x); MED3U(p3,p2,p3,x);  \
  MED3U(p2, p1, p2, x); MED3U(p1, p0,p1, x); p0 = min(p0, x);    \
} while (0)

// ======================= FAST PATH (ws >= ~57 MB) =======================
// k_prep: normalize per reference; write xraw/xn fp32 node-major, csq;
// build hi/lo-split bf16 operands. A layout MFMA-coalesced:
// [tile16][variant(4)][lane(64)][8 bf16]; B [node][128]. Zero deg.
__global__ __launch_bounds__(256)
void k_prep(const float* __restrict__ x, float* __restrict__ xraw,
            float* __restrict__ xn, float* __restrict__ csq,
            u16* __restrict__ Abuf, u16* __restrict__ Bbuf,
            int* __restrict__ deg) {
  int node = blockIdx.x * 256 + threadIdx.x;
  deg[node] = 0;
  int b = node >> 12, n = node & (NPTS - 1);
  const float* xb = x + (size_t)b * CH * NPTS;
  float f[CH];
#pragma unroll
  for (int c = 0; c < CH; ++c) f[c] = xb[(size_t)c * NPTS + n];
  float a0 = 0, a1 = 0, a2 = 0, a3 = 0;
#pragma unroll
  for (int k = 0; k < CH; k += 4) {
    a0 += f[k] * f[k]; a1 += f[k+1] * f[k+1];
    a2 += f[k+2] * f[k+2]; a3 += f[k+3] * f[k+3];
  }
  float nrm = fmaxf(sqrtf((a0 + a1) + (a2 + a3)), 1e-12f);
  float xv[CH];
#pragma unroll
  for (int c = 0; c < CH; ++c) xv[c] = f[c] / nrm;     // true division (ref)
  a0 = a1 = a2 = a3 = 0;
#pragma unroll
  for (int k = 0; k < CH; k += 4) {
    a0 += xv[k] * xv[k]; a1 += xv[k+1] * xv[k+1];
    a2 += xv[k+2] * xv[k+2]; a3 += xv[k+3] * xv[k+3];
  }
  float csqv = (a0 + a1) + (a2 + a3);
  csq[node] = csqv;
  float4* ro = (float4*)(xraw + (size_t)node * CH);
  float4* no = (float4*)(xn   + (size_t)node * CH);
#pragma unroll
  for (int i = 0; i < CH / 4; ++i) {
    ro[i] = make_float4(f[4*i], f[4*i+1], f[4*i+2], f[4*i+3]);
    no[i] = make_float4(xv[4*i], xv[4*i+1], xv[4*i+2], xv[4*i+3]);
  }
  u16 ah[64], al[64];
#pragma unroll
  for (int k = 0; k < CH; ++k) {
    float av = -2.0f * xv[k];
    u16 h = f2bf(av); ah[k] = h; al[k] = f2bf(av - bf2f(h));
  }
  { u16 h = f2bf(csqv); ah[48] = h; al[48] = f2bf(csqv - bf2f(h)); }
#pragma unroll
  for (int k = 49; k < 64; ++k) { ah[k] = 0; al[k] = 0; }
  u16* Bh = Bbuf + (size_t)node * 128;
#pragma unroll
  for (int k = 0; k < CH; ++k) {
    float bv = xv[k];
    u16 h = f2bf(bv); Bh[k] = h; Bh[64 + k] = f2bf(bv - bf2f(h));
  }
  Bh[48] = 0x3F80; Bh[64 + 48] = 0;            // 1.0 bf16 exact
#pragma unroll
  for (int k = 49; k < 64; ++k) { Bh[k] = 0; Bh[64 + k] = 0; }
  u16* Ag = Abuf + (size_t)(node >> 4) * 2048 + (size_t)(node & 15) * 8;
#pragma unroll
  for (int v = 0; v < 4; ++v) {
    const u16* src = (v < 2) ? ah : al;
    int koff = (v & 1) * 32;
#pragma unroll
    for (int q = 0; q < 4; ++q) {
      uint4 pk;
      const u16* s = src + koff + q * 8;
      pk.x = (u32)s[0] | ((u32)s[1] << 16);
      pk.y = (u32)s[2] | ((u32)s[3] << 16);
      pk.z = (u32)s[4] | ((u32)s[5] << 16);
      pk.w = (u32)s[6] | ((u32)s[7] << 16);
      *(uint4*)(Ag + v * 512 + q * 128) = pk;
    }
  }
}

// k_knn_m: wave = 16-row panel; blockIdx.y = column quarter (64 tiles of 16).
// 6 MFMAs/tile (hh,hl,lh). Top-12 filter via v_med3_u32 insert network.
// KEY: MFMA computes csq_col - 2<x_col,x_row> in [-1-eps, 3+eps]; acc bias
// +2.5 maps keys to [~1.5, ~5.5] -- strictly positive, raw-bits monotone.
// Key u32 = (fp_bits & 0xFFFFF000) | global_col(12b): full col embedded, so
// candu is u32 (half the traffic of the old u64) and quantization (~1e-3,
// 11 mantissa bits kept) stays within the NCAND slack + exact-rescore net.
// PIPELINE: ping-pong unroll-by-2 -- even iters compute on a*, prefetch c*;
// odd iters swap. NO register rotation (round-3's a=n copies were ~16
// VALU-counted accvgpr movs/tile; structural removal).
__global__ __launch_bounds__(256, 4)
void k_knn_m(const u16* __restrict__ Abuf, const u16* __restrict__ Bbuf,
             u32* __restrict__ candu) {
  int tid = threadIdx.x;
  int lane = tid & 63;
  int quad = lane >> 4, m16 = lane & 15;
  int panel = blockIdx.x * 4 + (tid >> 6);
  int row = panel * 16 + m16;
  int b4096 = row & ~(NPTS - 1);
  int quarter = blockIdx.y;
  int ct0 = quarter * 64;

  const __bf16* Bb = (const __bf16*)Bbuf + (size_t)row * 128;
  bf16x8 bh0 = *(const bf16x8*)(Bb + quad * 8);
  bf16x8 bh1 = *(const bf16x8*)(Bb + 32 + quad * 8);
  bf16x8 bl0 = *(const bf16x8*)(Bb + 64 + quad * 8);
  bf16x8 bl1 = *(const bf16x8*)(Bb + 96 + quad * 8);

  const __bf16* Ag = (const __bf16*)Abuf + (size_t)(b4096 >> 4) * 2048
                     + (size_t)lane * 8 + (size_t)ct0 * 2048;

  u32 s0=~0u,s1=~0u,s2=~0u,s3=~0u,s4=~0u,s5=~0u,
      s6=~0u,s7=~0u,s8=~0u,s9=~0u,s10=~0u,s11=~0u;

#define TILE_BODY(A0,A1,A2,A3,CT) do {                                      \
    f32x4 acc = {2.5f, 2.5f, 2.5f, 2.5f};                                   \
    acc = __builtin_amdgcn_mfma_f32_16x16x32_bf16(A0, bh0, acc, 0, 0, 0);   \
    acc = __builtin_amdgcn_mfma_f32_16x16x32_bf16(A1, bh1, acc, 0, 0, 0);   \
    acc = __builtin_amdgcn_mfma_f32_16x16x32_bf16(A0, bl0, acc, 0, 0, 0);   \
    acc = __builtin_amdgcn_mfma_f32_16x16x32_bf16(A1, bl1, acc, 0, 0, 0);   \
    acc = __builtin_amdgcn_mfma_f32_16x16x32_bf16(A2, bh0, acc, 0, 0, 0);   \
    acc = __builtin_amdgcn_mfma_f32_16x16x32_bf16(A3, bh1, acc, 0, 0, 0);   \
    u32 colb = ((u32)(CT) << 4) | ((u32)quad << 2);                         \
    _Pragma("unroll")                                                       \
    for (int r = 0; r < 4; ++r) {                                           \
      u32 u = __float_as_uint(acc[r]);                                      \
      u32 xx = (u & 0xFFFFF000u) | (colb | (u32)r);                         \
      INS12(s0,s1,s2,s3,s4,s5,s6,s7,s8,s9,s10,s11, xx);                     \
    }                                                                       \
  } while (0)

  // prologue: tile 0 resident in a*
  bf16x8 a0 = *(const bf16x8*)(Ag);
  bf16x8 a1 = *(const bf16x8*)(Ag + 512);
  bf16x8 a2 = *(const bf16x8*)(Ag + 1024);
  bf16x8 a3 = *(const bf16x8*)(Ag + 1536);

  for (int t = 0; t < 64; t += 2) {
    const __bf16* apc = Ag + (size_t)(t + 1) * 2048;
    bf16x8 c0 = *(const bf16x8*)(apc);
    bf16x8 c1 = *(const bf16x8*)(apc + 512);
    bf16x8 c2 = *(const bf16x8*)(apc + 1024);
    bf16x8 c3 = *(const bf16x8*)(apc + 1536);

    TILE_BODY(a0, a1, a2, a3, ct0 + t);

    const __bf16* apn = Ag + (size_t)((t + 2 < 64) ? (t + 2) : 63) * 2048;
    a0 = *(const bf16x8*)(apn);
    a1 = *(const bf16x8*)(apn + 512);
    a2 = *(const bf16x8*)(apn + 1024);
    a3 = *(const bf16x8*)(apn + 1536);

    TILE_BODY(c0, c1, c2, c3, ct0 + t + 1);
  }
#undef TILE_BODY

  u32* o = candu + (((size_t)row * 4 + quarter) * 4 + quad) * NCAND;
  o[0]=s0; o[1]=s1; o[2]=s2; o[3]=s3; o[4]=s4; o[5]=s5;
  o[6]=s6; o[7]=s7; o[8]=s8; o[9]=s9; o[10]=s10; o[11]=s11;
}

// k_reduce: per row, top-12 of the 192 u32 candidates (coalesced reads, no
// feature gathers). 64 rows/block x 4 threads/row; med3 insert network;
// 2-stage (48 each -> 48 merged by thread 0). Keys embed col in low 12b.
__global__ __launch_bounds__(256, 4)
void k_reduce(const u32* __restrict__ candu, u32* __restrict__ cand12) {
  __shared__ u32 ls[64 * 4 * NCAND];   // 12,288 B
  int tid = threadIdx.x;
  int lr = tid >> 2, q = tid & 3;
  int row = blockIdx.x * 64 + lr;
  const u32* src = candu + (size_t)row * 192 + q * 48;
  u32 t0=~0u,t1=~0u,t2=~0u,t3=~0u,t4=~0u,t5=~0u,
      t6=~0u,t7=~0u,t8=~0u,t9=~0u,t10=~0u,t11=~0u;
  for (int s = 0; s < 48; ++s) {
    u32 x = src[s];
    INS12(t0,t1,t2,t3,t4,t5,t6,t7,t8,t9,t10,t11, x);
  }
  u32* lw = ls + (size_t)(lr * 4 + q) * NCAND;
  lw[0]=t0; lw[1]=t1; lw[2]=t2; lw[3]=t3; lw[4]=t4; lw[5]=t5;
  lw[6]=t6; lw[7]=t7; lw[8]=t8; lw[9]=t9; lw[10]=t10; lw[11]=t11;
  __syncthreads();
  if (q == 0) {
    u32 g0=~0u,g1=~0u,g2=~0u,g3=~0u,g4=~0u,g5=~0u,
        g6=~0u,g7=~0u,g8=~0u,g9=~0u,g10=~0u,g11=~0u;
    const u32* lsrc = ls + (size_t)lr * 48;
    for (int s = 0; s < 48; ++s) {
      u32 x = lsrc[s];
      INS12(g0,g1,g2,g3,g4,g5,g6,g7,g8,g9,g10,g11, x);
    }
    u32* o = cand12 + (size_t)row * NCAND;
    o[0]=(g0&0xFFFu); o[1]=(g1&0xFFFu); o[2]=(g2&0xFFFu);
    o[3]=(g3&0xFFFu); o[4]=(g4&0xFFFu); o[5]=(g5&0xFFFu);
    o[6]=(g6&0xFFFu); o[7]=(g7&0xFFFu); o[8]=(g8&0xFFFu);
    o[9]=(g9&0xFFFu); o[10]=(g10&0xFFFu); o[11]=(g11&0xFFFu);
  }
}

// k_rescore: 16 rows/block x 16 threads/row; threads 0..11 each gather ONE
// candidate row and compute the exact fp32 dist (proven formula); thread 0
// merges 12 with the exact (dist, idx) comparator -> top-9. Fused nn write
// + degree histogram (tail edge drop). Only 12 gathers/row.
#define RR 16
__global__ __launch_bounds__(256, 4)
void k_rescore(const float* __restrict__ xn, const float* __restrict__ csq,
               const u32* __restrict__ cand12,
               u16* __restrict__ nn, int* __restrict__ deg) {
  __shared__ float dS[RR * NCAND];
  __shared__ int   iS[RR * NCAND];
  int tid = threadIdx.x;
  int lr = tid >> 4, q = tid & 15;
  int bi = blockIdx.x;
  int row = (bi & 7) * NPTS + (bi >> 3) * RR + lr;   // XCD swizzle (perf-only)
  int b4096 = row & ~(NPTS - 1);
  const float* xnb = xn + (size_t)b4096 * CH;
  if (q < NCAND) {
    float rf[CH];
    const float4* p = (const float4*)(xn + (size_t)row * CH);
#pragma unroll
    for (int i = 0; i < CH / 4; ++i) {
      float4 v = p[i];
      rf[4*i] = v.x; rf[4*i+1] = v.y; rf[4*i+2] = v.z; rf[4*i+3] = v.w;
    }
    float sqn = csq[row];
    int c = (int)(cand12[(size_t)row * NCAND + q] & (NPTS - 1));
    const float4* cp = (const float4*)(xnb + (size_t)c * CH);
    float a0 = 0, a1 = 0, a2 = 0, a3 = 0;
#pragma unroll
    for (int i = 0; i < CH / 4; ++i) {
      float4 v = cp[i];
      a0 += rf[4*i]   * v.x; a1 += rf[4*i+1] * v.y;
      a2 += rf[4*i+2] * v.z; a3 += rf[4*i+3] * v.w;
    }
    float dist = (sqn + csq[b4096 + c]) - 2.0f * ((a0 + a1) + (a2 + a3));
    dS[lr * NCAND + q] = dist;
    iS[lr * NCAND + q] = c;
  }
  __syncthreads();
  if (q == 0) {
    float gd[KNN]; int gi[KNN];
#pragma unroll
    for (int j = 0; j < KNN; ++j) { gd[j] = 3.4e38f; gi[j] = 0x7fffffff; }
    for (int s = 0; s < NCAND; ++s) {
      float dc = dS[lr * NCAND + s]; int ic = iS[lr * NCAND + s];
      if (dc < gd[KNN - 1] || (dc == gd[KNN - 1] && ic < gi[KNN - 1])) {
        gd[KNN - 1] = dc; gi[KNN - 1] = ic;
#pragma unroll
        for (int k2 = KNN - 1; k2 > 0; --k2) {
          bool sw = (gd[k2] < gd[k2 - 1]) ||
                    (gd[k2] == gd[k2 - 1] && gi[k2] < gi[k2 - 1]);
          if (sw) {
            float td = gd[k2]; gd[k2] = gd[k2 - 1]; gd[k2 - 1] = td;
            int ti = gi[k2]; gi[k2] = gi[k2 - 1]; gi[k2 - 1] = ti;
          }
        }
      }
    }
    u16* o = nn + (size_t)row * KNN;
    int jmax = (row == NBN - 1) ? (KNN - 1) : KNN;   // linspace tail drop
#pragma unroll
    for (int j = 0; j < KNN; ++j) o[j] = (u16)(gi[j] & (NPTS - 1));
    for (int j = 0; j < jmax; ++j)
      atomicAdd(&deg[b4096 + (gi[j] & (NPTS - 1))], 1);
  }
}

// k_out: 64 nodes/block x 4 threads/node (12 out-channels each), XCD swizzle.
#define ONB 64
#define LPAD 52
__global__ __launch_bounds__(256)
void k_out_f(const float* __restrict__ xraw, const u16* __restrict__ nn,
             const int* __restrict__ deg,
             const float* __restrict__ W0, const float* __restrict__ W1,
             const float* __restrict__ bias, float* __restrict__ out) {
  __shared__ float w0[CH * CH], w1[CH * CH], bs[CH];
  __shared__ __align__(16) float fS[ONB * LPAD];
  __shared__ __align__(16) float txS[ONB * LPAD];
  __shared__ float dinvS[ONB];
  int tid = threadIdx.x;
  int bi = blockIdx.x;
  int n0 = (bi & 7) * NPTS + (bi >> 3) * ONB;   // XCD swizzle (perf-only)
  int b12 = n0 & ~(NPTS - 1);
  for (int i = tid; i < CH * CH; i += 256) { w0[i] = W0[i]; w1[i] = W1[i]; }
  if (tid < CH) bs[tid] = bias[tid];
  for (int i = tid; i < ONB * 12; i += 256) {
    int ln = i / 12, f4 = i % 12;
    *(float4*)(fS + ln * LPAD + f4 * 4) =
        *(const float4*)(xraw + (size_t)(n0 + ln) * CH + f4 * 4);
  }
  if (tid < ONB) {
    int dg = deg[n0 + tid];
    dinvS[tid] = (dg > 0) ? (1.0f / sqrtf((float)dg)) : 0.0f;
  }
  __syncthreads();

  int ln = tid >> 2, p = tid & 3;
  int node = n0 + ln;
  float dn = dinvS[ln];
  const u16* nrow = nn + (size_t)node * KNN;
  bool full = (node != NBN - 1);
  float tx[12];
#pragma unroll
  for (int i = 0; i < 12; ++i) tx[i] = 0.f;
#pragma unroll
  for (int j = 0; j < KNN; ++j) {
    if (j < KNN - 1 || full) {
      int s = nrow[j] & (NPTS - 1);
      int dgs = deg[b12 + s];
      float ds = (dgs > 0) ? (1.0f / sqrtf((float)dgs)) : 0.0f;
      float w = -(ds * dn);
      const float4* pr = (const float4*)(xraw + (size_t)(b12 + s) * CH + p * 12);
#pragma unroll
      for (int q3 = 0; q3 < 3; ++q3) {
        float4 v = pr[q3];
        tx[q3*4]   += w * v.x; tx[q3*4+1] += w * v.y;
        tx[q3*4+2] += w * v.z; tx[q3*4+3] += w * v.w;
      }
    }
  }
#pragma unroll
  for (int q3 = 0; q3 < 3; ++q3)
    *(float4*)(txS + ln * LPAD + p * 12 + q3 * 4) =
        make_float4(tx[q3*4], tx[q3*4+1], tx[q3*4+2], tx[q3*4+3]);
  __syncthreads();

  float acc[12];
#pragma unroll
  for (int i = 0; i < 12; ++i) acc[i] = bs[p * 12 + i];
  const float* fr = fS + ln * LPAD;
  const float* tr = txS + ln * LPAD;
#pragma unroll
  for (int c = 0; c < CH; ++c) {
    float fc = fr[c];
    const float* wr = w0 + c * CH + p * 12;
#pragma unroll
    for (int i = 0; i < 12; ++i) acc[i] += fc * wr[i];
  }
#pragma unroll
  for (int c = 0; c < CH; ++c) {
    float tc = tr[c];
    const float* wr = w1 + c * CH + p * 12;
#pragma unroll
    for (int i = 0; i < 12; ++i) acc[i] += tc * wr[i];
  }
  float* op = out + (size_t)node * CH + p * 12;
#pragma unroll
  for (int q3 = 0; q3 < 3; ++q3)
    *(float4*)(op + q3 * 4) =
        make_float4(acc[q3*4], acc[q3*4+1], acc[q3*4+2], acc[q3*4+3]);
}

// ======================= FALLBACK (round-4, proven) =======================
__global__ __launch_bounds__(256)
void k_zero(int* __restrict__ deg) { deg[blockIdx.x * 256 + threadIdx.x] = 0; }

__global__ __launch_bounds__(256)
void k_hist(const u16* __restrict__ nn, int* __restrict__ deg) {
  int node = blockIdx.x * 256 + threadIdx.x;
  int b12 = node & ~(NPTS - 1);
  int jmax = (node == NBN - 1) ? (KNN - 1) : KNN;
  for (int j = 0; j < jmax; ++j)
    atomicAdd(&deg[b12 + (nn[(size_t)node * KNN + j] & (NPTS - 1))], 1);
}

__global__ __launch_bounds__(256)
void k_dinv(const int* __restrict__ deg, float* __restrict__ dinv) {
  int i = blockIdx.x * 256 + threadIdx.x;
  int dg = deg[i];
  dinv[i] = (dg > 0) ? (1.0f / sqrtf((float)dg)) : 0.0f;
}

#define NQ    4
#define QCOLS (NPTS/NQ)
#define TCOLS 32
#define NTILES (QCOLS/TCOLS)
#define RPB   64

__global__ __launch_bounds__(256)
void k_knn_nb(const float* __restrict__ x, u16* __restrict__ nn) {
  __shared__ __align__(16) float tile[NQ * TCOLS * CH];
  __shared__ float nrmS[NQ * TCOLS];
  __shared__ float csq[NQ * TCOLS];
  int tid = threadIdx.x;
  int r0 = blockIdx.x * RPB;
  int b  = r0 >> 12;
  int q  = tid >> 6;
  int lr = tid & 63;
  int n  = (r0 + lr) & (NPTS - 1);
  const float* xb = x + (size_t)b * CH * NPTS;
  float rf[CH];
#pragma unroll
  for (int c = 0; c < CH; ++c) rf[c] = xb[(size_t)c * NPTS + n];
  float sqn;
  {
    float a0 = 0, a1 = 0, a2 = 0, a3 = 0;
#pragma unroll
    for (int k = 0; k < CH; k += 4) {
      a0 += rf[k] * rf[k]; a1 += rf[k+1] * rf[k+1];
      a2 += rf[k+2] * rf[k+2]; a3 += rf[k+3] * rf[k+3];
    }
    float nrm = fmaxf(sqrtf((a0 + a1) + (a2 + a3)), 1e-12f);
#pragma unroll
    for (int c = 0; c < CH; ++c) rf[c] = rf[c] / nrm;
    a0 = a1 = a2 = a3 = 0;
#pragma unroll
    for (int k = 0; k < CH; k += 4) {
      a0 += rf[k] * rf[k]; a1 += rf[k+1] * rf[k+1];
      a2 += rf[k+2] * rf[k+2]; a3 += rf[k+3] * rf[k+3];
    }
    sqn = (a0 + a1) + (a2 + a3);
  }
  float d[KNN]; int id[KNN];
#pragma unroll
  for (int j = 0; j < KNN; ++j) { d[j] = 3.4e38f; id[j] = 0x7fffffff; }
  for (int t = 0; t < NTILES; ++t) {
    __syncthreads();
#pragma unroll
    for (int qq = 0; qq < NQ; ++qq) {
      int colbase = qq * QCOLS + t * TCOLS;
      float* dst = tile + qq * TCOLS * CH;
#pragma unroll
      for (int it = 0; it < 6; ++it) {
        int i = it * 256 + tid;
        int c = i >> 5, p = i & 31;
        dst[p * CH + c] = xb[(size_t)c * NPTS + colbase + p];
      }
    }
    __syncthreads();
    if (tid < NQ * TCOLS) {
      const float* cp = tile + tid * CH;
      float a0 = 0, a1 = 0, a2 = 0, a3 = 0;
#pragma unroll
      for (int k = 0; k < CH; k += 4) {
        float4 v = *(const float4*)(cp + k);
        a0 += v.x * v.x; a1 += v.y * v.y; a2 += v.z * v.z; a3 += v.w * v.w;
      }
      nrmS[tid] = fmaxf(sqrtf((a0 + a1) + (a2 + a3)), 1e-12f);
    }
    __syncthreads();
    for (int i = tid; i < NQ * TCOLS * CH; i += 256)
      tile[i] = tile[i] / nrmS[i / CH];
    __syncthreads();
    if (tid < NQ * TCOLS) {
      const float* cp = tile + tid * CH;
      float a0 = 0, a1 = 0, a2 = 0, a3 = 0;
#pragma unroll
      for (int k = 0; k < CH; k += 4) {
        float4 v = *(const float4*)(cp + k);
        a0 += v.x * v.x; a1 += v.y * v.y; a2 += v.z * v.z; a3 += v.w * v.w;
      }
      csq[tid] = (a0 + a1) + (a2 + a3);
    }
    __syncthreads();
    int cbase = q * QCOLS + t * TCOLS;
    const float* tq = tile + q * TCOLS * CH;
    for (int cc = 0; cc < TCOLS; ++cc) {
      const float* cp = tq + cc * CH;
      float a0 = 0, a1 = 0, a2 = 0, a3 = 0;
#pragma unroll
      for (int k = 0; k < CH; k += 4) {
        float4 v = *(const float4*)(cp + k);
        a0 += rf[k] * v.x; a1 += rf[k+1] * v.y;
        a2 += rf[k+2] * v.z; a3 += rf[k+3] * v.w;
      }
      float dist = (sqn + csq[q * TCOLS + cc]) - 2.0f * ((a0 + a1) + (a2 + a3));
      if (dist < d[KNN - 1]) {
        d[KNN - 1] = dist; id[KNN - 1] = cbase + cc;
#pragma unroll
        for (int k2 = KNN - 1; k2 > 0; --k2) {
          if (d[k2] < d[k2 - 1]) {
            float td = d[k2]; d[k2] = d[k2 - 1]; d[k2 - 1] = td;
            int ti = id[k2]; id[k2] = id[k2 - 1]; id[k2 - 1] = ti;
          }
        }
      }
    }
  }
  __syncthreads();
  float* md = tile;
  int*   mi = (int*)(tile + 256 * KNN);
#pragma unroll
  for (int j = 0; j < KNN; ++j) { md[tid * KNN + j] = d[j]; mi[tid * KNN + j] = id[j]; }
  __syncthreads();
  if (tid < RPB) {
    float fd[KNN]; int fi[KNN];
#pragma unroll
    for (int j = 0; j < KNN; ++j) { fd[j] = 3.4e38f; fi[j] = 0x7fffffff; }
    for (int qq = 0; qq < NQ; ++qq) {
      int s = qq * RPB + tid;
      for (int j = 0; j < KNN; ++j) {
        float dc = md[s * KNN + j]; int ic = mi[s * KNN + j];
        if (dc < fd[KNN - 1]) {
          fd[KNN - 1] = dc; fi[KNN - 1] = ic;
#pragma unroll
          for (int k2 = KNN - 1; k2 > 0; --k2) {
            if (fd[k2] < fd[k2 - 1]) {
              float td = fd[k2]; fd[k2] = fd[k2 - 1]; fd[k2 - 1] = td;
              int ti = fi[k2]; fi[k2] = fi[k2 - 1]; fi[k2 - 1] = ti;
            }
          }
        }
      }
    }
    u16* o = nn + (size_t)(r0 + tid) * KNN;
#pragma unroll
    for (int j = 0; j < KNN; ++j) o[j] = (u16)(fi[j] & (NPTS - 1));
  }
}

__global__ __launch_bounds__(256)
void k_out_nb(const float* __restrict__ x, const u16* __restrict__ nn,
              const float* __restrict__ dinv,
              const float* __restrict__ W0, const float* __restrict__ W1,
              const float* __restrict__ bias, float* __restrict__ out) {
  __shared__ float w0[CH * CH], w1[CH * CH], bs[CH];
  for (int i = threadIdx.x; i < CH * CH; i += 256) { w0[i] = W0[i]; w1[i] = W1[i]; }
  if (threadIdx.x < CH) bs[threadIdx.x] = bias[threadIdx.x];
  __syncthreads();
  int node = blockIdx.x * 256 + threadIdx.x;
  int b = node >> 12, n = node & (NPTS - 1);
  const float* xb = x + (size_t)b * CH * NPTS;
  float f[CH], acc[CH], tx[CH];
#pragma unroll
  for (int c = 0; c < CH; ++c) f[c] = xb[(size_t)c * NPTS + n];
#pragma unroll
  for (int o = 0; o < CH; ++o) acc[o] = bs[o];
#pragma unroll
  for (int c = 0; c < CH; ++c) {
    float fc = f[c];
    const float* wr = w0 + c * CH;
#pragma unroll
    for (int o = 0; o < CH; ++o) acc[o] += fc * wr[o];
  }
#pragma unroll
  for (int c = 0; c < CH; ++c) tx[c] = 0.f;
  float dn = dinv[node];
  int jmax = (node == NBN - 1) ? (KNN - 1) : KNN;
  for (int j = 0; j < jmax; ++j) {
    int s = nn[(size_t)node * KNN + j] & (NPTS - 1);
    float w = -(dinv[(b << 12) + s] * dn);
#pragma unroll
    for (int c = 0; c < CH; ++c) tx[c] += w * xb[(size_t)c * NPTS + s];
  }
#pragma unroll
  for (int c = 0; c < CH; ++c) {
    float tc = tx[c];
    const float* wr = w1 + c * CH;
#pragma unroll
    for (int o = 0; o < CH; ++o) acc[o] += tc * wr[o];
  }
  float4* op = (float4*)(out + (size_t)node * CH);
#pragma unroll
  for (int i = 0; i < CH / 4; ++i)
    op[i] = make_float4(acc[4*i], acc[4*i+1], acc[4*i+2], acc[4*i+3]);
}

extern "C" void kernel_launch(void* const* d_in, const int* in_sizes, int n_in,
                              void* d_out, int out_size, void* d_ws, size_t ws_size,
                              hipStream_t stream) {
  const float* x    = (const float*)d_in[0];
  const float* W0   = (const float*)d_in[1];
  const float* W1   = (const float*)d_in[2];
  const float* bias = (const float*)d_in[3];
  float* out = (float*)d_out;
  char* w = (char*)d_ws;

  const size_t SZ_XN   = (size_t)NBN * CH * 4;            //  6,291,456
  const size_t SZ_XRAW = (size_t)NBN * CH * 4;            //  6,291,456
  const size_t SZ_CSQ  = (size_t)NBN * 4;                 //    131,072
  const size_t SZ_NN   = (size_t)NBN * KNN * 2;           //    589,824
  const size_t SZ_DEG  = (size_t)NBN * 4;                 //    131,072
  const size_t SZ_AB   = (size_t)NBN * 128 * 2;           //  8,388,608
  const size_t SZ_CU   = (size_t)NBN * 16 * NCAND * 4;    // 25,165,824 (u32)
  const size_t SZ_C12  = (size_t)NBN * NCAND * 4;         //  1,572,864
  const size_t needF = SZ_XN + SZ_XRAW + SZ_CSQ + SZ_NN + SZ_DEG
                     + 2 * SZ_AB + SZ_CU + SZ_C12;        // ~56.9 MB

  if (ws_size >= needF) {          // FAST path: MFMA filter + reduce + rescore
    size_t off = 0;
    float* xn   = (float*)(w + off); off += SZ_XN;
    float* xraw = (float*)(w + off); off += SZ_XRAW;
    float* csq  = (float*)(w + off); off += SZ_CSQ;
    u16*   nn   = (u16*)  (w + off); off += SZ_NN;
    int*   deg  = (int*)  (w + off); off += SZ_DEG;
    u16*   Abuf = (u16*)  (w + off); off += SZ_AB;
    u16*   Bbuf = (u16*)  (w + off); off += SZ_AB;
    u32*   candu= (u32*)  (w + off); off += SZ_CU;
    u32*   cand12=(u32*)  (w + off);
    k_prep    <<<NBN / 256, 256, 0, stream>>>(x, xraw, xn, csq, Abuf, Bbuf, deg);
    k_knn_m   <<<dim3(NBN / 64, 4), 256, 0, stream>>>(Abuf, Bbuf, candu);
    k_reduce  <<<NBN / 64, 256, 0, stream>>>(candu, cand12);
    k_rescore <<<NBN / RR, 256, 0, stream>>>(xn, csq, cand12, nn, deg);
    k_out_f   <<<NBN / ONB, 256, 0, stream>>>(xraw, nn, deg, W0, W1, bias, out);
  } else {                         // FALLBACK: proven round-4 path (852 KB)
    u16*   nn   = (u16*)w;
    int*   deg  = (int*)(w + SZ_NN);
    float* dinv = (float*)(w + SZ_NN + SZ_DEG);
    k_knn_nb <<<NBN / RPB, 256, 0, stream>>>(x, nn);
    k_zero   <<<NBN / 256, 256, 0, stream>>>(deg);
    k_hist   <<<NBN / 256, 256, 0, stream>>>(nn, deg);
    k_dinv   <<<NBN / 256, 256, 0, stream>>>(deg, dinv);
    k_out_nb <<<NBN / 256, 256, 0, stream>>>(x, nn, dinv, W0, W1, bias, out);
  }
}

// Round 5
// 213.942 us; speedup vs baseline: 1.3225x; 1.0540x over previous
//
#include <hip/hip_runtime.h>

#define BATCH 8
#define CH    48
#define NPTS  4096
#define NBN   (BATCH*NPTS)
#define KNN   9
#define NCAND 12             // per-lane filter depth

typedef unsigned short u16;
typedef unsigned int   u32;
typedef unsigned long long u64;
typedef __bf16 bf16x8 __attribute__((ext_vector_type(8)));
typedef float  f32x4  __attribute__((ext_vector_type(4)));

__device__ __forceinline__ float bf2f(u16 v) { return __uint_as_float(((u32)v) << 16); }
__device__ __forceinline__ u16 f2bf(float f) {
  u32 u = __float_as_uint(f);
  u = (u + 0x7fffu + ((u >> 16) & 1u)) >> 16;
  return (u16)u;
}

// Shared med3 insert: insert x into sorted p0<=...<=p11 keeping smallest 12.
//   p_i' = med3(p_{i-1}, p_i, x) (i=11..1, old values), p0' = min(p0, x).
#define MED3U(d, a, b, c) \
  asm("v_med3_u32 %0, %1, %2, %3" : "=v"(d) : "v"(a), "v"(b), "v"(c))
#define INS12(p0,p1,p2,p3,p4,p5,p6,p7,p8,p9,p10,p11,x) do { \
  MED3U(p11,p10,p11,x); MED3U(p10,p9,p10,x); MED3U(p9,p8,p9,x);  \
  MED3U(p8, p7, p8, x); MED3U(p7, p6,p7, x); MED3U(p6,p5,p6,x);  \
  MED3U(p5, p4, p5, x); MED3U(p4, p3,p4, x); MED3U(p3,p2,p3,x);  \
  MED3U(p2, p1, p2, x); MED3U(p1, p0,p1, x); p0 = min(p0, x);    \
} while (0)

// async global->LDS staging: per-lane global src, wave-uniform LDS base
// (HW adds lane*16B). 16B/lane x 64 lanes = 1 KB per call.
__device__ __forceinline__ void stage_q(const u16* g, u16* l) {
  __builtin_amdgcn_global_load_lds(
      (const __attribute__((address_space(1))) void*)g,
      (__attribute__((address_space(3))) void*)l, 16, 0, 0);
}

// ======================= FAST PATH (ws >= ~57 MB) =======================
// k_prep: normalize per reference; write xraw/xn fp32 node-major, csq;
// build hi/lo-split bf16 operands. A layout MFMA-coalesced:
// [tile16][variant(4)][lane(64)][8 bf16]; B [node][128]. Zero deg.
__global__ __launch_bounds__(256)
void k_prep(const float* __restrict__ x, float* __restrict__ xraw,
            float* __restrict__ xn, float* __restrict__ csq,
            u16* __restrict__ Abuf, u16* __restrict__ Bbuf,
            int* __restrict__ deg) {
  int node = blockIdx.x * 256 + threadIdx.x;
  deg[node] = 0;
  int b = node >> 12, n = node & (NPTS - 1);
  const float* xb = x + (size_t)b * CH * NPTS;
  float f[CH];
#pragma unroll
  for (int c = 0; c < CH; ++c) f[c] = xb[(size_t)c * NPTS + n];
  float a0 = 0, a1 = 0, a2 = 0, a3 = 0;
#pragma unroll
  for (int k = 0; k < CH; k += 4) {
    a0 += f[k] * f[k]; a1 += f[k+1] * f[k+1];
    a2 += f[k+2] * f[k+2]; a3 += f[k+3] * f[k+3];
  }
  float nrm = fmaxf(sqrtf((a0 + a1) + (a2 + a3)), 1e-12f);
  float xv[CH];
#pragma unroll
  for (int c = 0; c < CH; ++c) xv[c] = f[c] / nrm;     // true division (ref)
  a0 = a1 = a2 = a3 = 0;
#pragma unroll
  for (int k = 0; k < CH; k += 4) {
    a0 += xv[k] * xv[k]; a1 += xv[k+1] * xv[k+1];
    a2 += xv[k+2] * xv[k+2]; a3 += xv[k+3] * xv[k+3];
  }
  float csqv = (a0 + a1) + (a2 + a3);
  csq[node] = csqv;
  float4* ro = (float4*)(xraw + (size_t)node * CH);
  float4* no = (float4*)(xn   + (size_t)node * CH);
#pragma unroll
  for (int i = 0; i < CH / 4; ++i) {
    ro[i] = make_float4(f[4*i], f[4*i+1], f[4*i+2], f[4*i+3]);
    no[i] = make_float4(xv[4*i], xv[4*i+1], xv[4*i+2], xv[4*i+3]);
  }
  u16 ah[64], al[64];
#pragma unroll
  for (int k = 0; k < CH; ++k) {
    float av = -2.0f * xv[k];
    u16 h = f2bf(av); ah[k] = h; al[k] = f2bf(av - bf2f(h));
  }
  { u16 h = f2bf(csqv); ah[48] = h; al[48] = f2bf(csqv - bf2f(h)); }
#pragma unroll
  for (int k = 49; k < 64; ++k) { ah[k] = 0; al[k] = 0; }
  u16* Bh = Bbuf + (size_t)node * 128;
#pragma unroll
  for (int k = 0; k < CH; ++k) {
    float bv = xv[k];
    u16 h = f2bf(bv); Bh[k] = h; Bh[64 + k] = f2bf(bv - bf2f(h));
  }
  Bh[48] = 0x3F80; Bh[64 + 48] = 0;            // 1.0 bf16 exact
#pragma unroll
  for (int k = 49; k < 64; ++k) { Bh[k] = 0; Bh[64 + k] = 0; }
  u16* Ag = Abuf + (size_t)(node >> 4) * 2048 + (size_t)(node & 15) * 8;
#pragma unroll
  for (int v = 0; v < 4; ++v) {
    const u16* src = (v < 2) ? ah : al;
    int koff = (v & 1) * 32;
#pragma unroll
    for (int q = 0; q < 4; ++q) {
      uint4 pk;
      const u16* s = src + koff + q * 8;
      pk.x = (u32)s[0] | ((u32)s[1] << 16);
      pk.y = (u32)s[2] | ((u32)s[3] << 16);
      pk.z = (u32)s[4] | ((u32)s[5] << 16);
      pk.w = (u32)s[6] | ((u32)s[7] << 16);
      *(uint4*)(Ag + v * 512 + q * 128) = pk;
    }
  }
}

// k_knn_m: wave = 16-row panel; blockIdx.y = column quarter (64 tiles of 16).
// All 4 waves of a block share one A-tile stream (A depends on batch+tile
// only) -> stage each 4 KB tile ONCE into LDS via global_load_lds (1 instr
// per wave = its 1 KB quarter), double-buffered. Software pipeline per tile:
//   ds_read(t) ; stage(t+1, other buf) ; FILTER(acc of t-1)  [~124 cyc VALU
//   covers ds_read latency + stage issue] ; 6 MFMA(t) ; __syncthreads()
// One barrier/tile; its vmcnt-drain is exactly the staging guarantee.
// Acc ping-pong (accA/accB) via unroll-2: no register copies.
// KEY: MFMA computes csq_col - 2<x_col,x_row> in [-1-eps,3+eps]; +2.5 bias
// -> strictly positive keys, raw-bits monotone. Key u32 = (bits &
// 0xFFFFF000) | global_col(12b); exact-rescore absorbs ~1e-3 quantization.
__global__ __launch_bounds__(256, 6)
void k_knn_m(const u16* __restrict__ Abuf, const u16* __restrict__ Bbuf,
             u32* __restrict__ candu) {
  __shared__ __align__(16) u16 As[2][2048];   // 2 x 4 KB tiles
  int tid = threadIdx.x;
  int lane = tid & 63;
  int wv = tid >> 6;
  int quad = lane >> 4, m16 = lane & 15;
  int panel = blockIdx.x * 4 + wv;
  int row = panel * 16 + m16;
  int b4096 = row & ~(NPTS - 1);
  int quarter = blockIdx.y;
  int ct0 = quarter * 64;

  const __bf16* Bb = (const __bf16*)Bbuf + (size_t)row * 128;
  bf16x8 bh0 = *(const bf16x8*)(Bb + quad * 8);
  bf16x8 bh1 = *(const bf16x8*)(Bb + 32 + quad * 8);
  bf16x8 bl0 = *(const bf16x8*)(Bb + 64 + quad * 8);
  bf16x8 bl1 = *(const bf16x8*)(Bb + 96 + quad * 8);

  // tiles ct0..ct0+63 for this batch; per-wave staging src (quarter wv)
  const u16* gs = Abuf + ((size_t)(b4096 >> 4) + ct0) * 2048
                  + wv * 512 + lane * 8;

  u32 s0=~0u,s1=~0u,s2=~0u,s3=~0u,s4=~0u,s5=~0u,
      s6=~0u,s7=~0u,s8=~0u,s9=~0u,s10=~0u,s11=~0u;

#define LDA(BUF, A0,A1,A2,A3) do {                                          \
    const u16* _p = &As[BUF][lane * 8];                                     \
    A0 = *(const bf16x8*)(_p);                                              \
    A1 = *(const bf16x8*)(_p + 512);                                        \
    A2 = *(const bf16x8*)(_p + 1024);                                       \
    A3 = *(const bf16x8*)(_p + 1536);                                       \
  } while (0)
#define MFMA6(ACC, A0,A1,A2,A3) do {                                        \
    ACC = (f32x4){2.5f, 2.5f, 2.5f, 2.5f};                                  \
    ACC = __builtin_amdgcn_mfma_f32_16x16x32_bf16(A0, bh0, ACC, 0, 0, 0);   \
    ACC = __builtin_amdgcn_mfma_f32_16x16x32_bf16(A1, bh1, ACC, 0, 0, 0);   \
    ACC = __builtin_amdgcn_mfma_f32_16x16x32_bf16(A0, bl0, ACC, 0, 0, 0);   \
    ACC = __builtin_amdgcn_mfma_f32_16x16x32_bf16(A1, bl1, ACC, 0, 0, 0);   \
    ACC = __builtin_amdgcn_mfma_f32_16x16x32_bf16(A2, bh0, ACC, 0, 0, 0);   \
    ACC = __builtin_amdgcn_mfma_f32_16x16x32_bf16(A3, bh1, ACC, 0, 0, 0);   \
  } while (0)
#define FILTER(ACC, CT) do {                                                \
    u32 _colb = ((u32)(CT) << 4) | ((u32)quad << 2);                        \
    _Pragma("unroll")                                                       \
    for (int _r = 0; _r < 4; ++_r) {                                        \
      u32 _u = __float_as_uint((ACC)[_r]);                                  \
      u32 _x = (_u & 0xFFFFF000u) | (_colb | (u32)_r);                      \
      INS12(s0,s1,s2,s3,s4,s5,s6,s7,s8,s9,s10,s11, _x);                     \
    }                                                                       \
  } while (0)

  f32x4 accA, accB;
  bf16x8 a0, a1, a2, a3;

  // prologue: stage tile 0 -> buf0
  stage_q(gs, &As[0][wv * 512]);
  __syncthreads();

  // iter 0: tile 0 from buf0; stage tile 1 -> buf1
  LDA(0, a0, a1, a2, a3);
  stage_q(gs + (size_t)1 * 2048, &As[1][wv * 512]);
  MFMA6(accA, a0, a1, a2, a3);
  __syncthreads();

  for (int i = 0; i < 31; ++i) {
    int t = 2 * i + 1;
    // iterA: tile t (odd) from buf1; stage t+1 -> buf0; filter tile t-1
    LDA(1, a0, a1, a2, a3);
    stage_q(gs + (size_t)(t + 1) * 2048, &As[0][wv * 512]);
    FILTER(accA, ct0 + t - 1);
    MFMA6(accB, a0, a1, a2, a3);
    __syncthreads();
    // iterB: tile t+1 (even) from buf0; stage t+2 -> buf1; filter tile t
    LDA(0, a0, a1, a2, a3);
    stage_q(gs + (size_t)(t + 2) * 2048, &As[1][wv * 512]);
    FILTER(accB, ct0 + t);
    MFMA6(accA, a0, a1, a2, a3);
    __syncthreads();
  }
  // leftover: tile 63 from buf1 (staged by last iterB)
  LDA(1, a0, a1, a2, a3);
  FILTER(accA, ct0 + 62);
  MFMA6(accB, a0, a1, a2, a3);
  FILTER(accB, ct0 + 63);
#undef LDA
#undef MFMA6
#undef FILTER

  u32* o = candu + (((size_t)row * 4 + quarter) * 4 + quad) * NCAND;
  o[0]=s0; o[1]=s1; o[2]=s2; o[3]=s3; o[4]=s4; o[5]=s5;
  o[6]=s6; o[7]=s7; o[8]=s8; o[9]=s9; o[10]=s10; o[11]=s11;
}

// k_reduce: per row, top-12 of the 192 u32 candidates (coalesced reads, no
// feature gathers). 64 rows/block x 4 threads/row; med3 insert network;
// 2-stage (48 each -> 48 merged by thread 0). Keys embed col in low 12b.
__global__ __launch_bounds__(256, 4)
void k_reduce(const u32* __restrict__ candu, u32* __restrict__ cand12) {
  __shared__ u32 ls[64 * 4 * NCAND];   // 12,288 B
  int tid = threadIdx.x;
  int lr = tid >> 2, q = tid & 3;
  int row = blockIdx.x * 64 + lr;
  const u32* src = candu + (size_t)row * 192 + q * 48;
  u32 t0=~0u,t1=~0u,t2=~0u,t3=~0u,t4=~0u,t5=~0u,
      t6=~0u,t7=~0u,t8=~0u,t9=~0u,t10=~0u,t11=~0u;
  for (int s = 0; s < 48; ++s) {
    u32 x = src[s];
    INS12(t0,t1,t2,t3,t4,t5,t6,t7,t8,t9,t10,t11, x);
  }
  u32* lw = ls + (size_t)(lr * 4 + q) * NCAND;
  lw[0]=t0; lw[1]=t1; lw[2]=t2; lw[3]=t3; lw[4]=t4; lw[5]=t5;
  lw[6]=t6; lw[7]=t7; lw[8]=t8; lw[9]=t9; lw[10]=t10; lw[11]=t11;
  __syncthreads();
  if (q == 0) {
    u32 g0=~0u,g1=~0u,g2=~0u,g3=~0u,g4=~0u,g5=~0u,
        g6=~0u,g7=~0u,g8=~0u,g9=~0u,g10=~0u,g11=~0u;
    const u32* lsrc = ls + (size_t)lr * 48;
    for (int s = 0; s < 48; ++s) {
      u32 x = lsrc[s];
      INS12(g0,g1,g2,g3,g4,g5,g6,g7,g8,g9,g10,g11, x);
    }
    u32* o = cand12 + (size_t)row * NCAND;
    o[0]=(g0&0xFFFu); o[1]=(g1&0xFFFu); o[2]=(g2&0xFFFu);
    o[3]=(g3&0xFFFu); o[4]=(g4&0xFFFu); o[5]=(g5&0xFFFu);
    o[6]=(g6&0xFFFu); o[7]=(g7&0xFFFu); o[8]=(g8&0xFFFu);
    o[9]=(g9&0xFFFu); o[10]=(g10&0xFFFu); o[11]=(g11&0xFFFu);
  }
}

// k_rescore: 16 rows/block x 16 threads/row; threads 0..11 each gather ONE
// candidate row and compute the exact fp32 dist (proven formula); thread 0
// merges 12 with the exact (dist, idx) comparator -> top-9. Fused nn write
// + degree histogram (tail edge drop). Only 12 gathers/row.
#define RR 16
__global__ __launch_bounds__(256, 4)
void k_rescore(const float* __restrict__ xn, const float* __restrict__ csq,
               const u32* __restrict__ cand12,
               u16* __restrict__ nn, int* __restrict__ deg) {
  __shared__ float dS[RR * NCAND];
  __shared__ int   iS[RR * NCAND];
  int tid = threadIdx.x;
  int lr = tid >> 4, q = tid & 15;
  int bi = blockIdx.x;
  int row = (bi & 7) * NPTS + (bi >> 3) * RR + lr;   // XCD swizzle (perf-only)
  int b4096 = row & ~(NPTS - 1);
  const float* xnb = xn + (size_t)b4096 * CH;
  if (q < NCAND) {
    float rf[CH];
    const float4* p = (const float4*)(xn + (size_t)row * CH);
#pragma unroll
    for (int i = 0; i < CH / 4; ++i) {
      float4 v = p[i];
      rf[4*i] = v.x; rf[4*i+1] = v.y; rf[4*i+2] = v.z; rf[4*i+3] = v.w;
    }
    float sqn = csq[row];
    int c = (int)(cand12[(size_t)row * NCAND + q] & (NPTS - 1));
    const float4* cp = (const float4*)(xnb + (size_t)c * CH);
    float a0 = 0, a1 = 0, a2 = 0, a3 = 0;
#pragma unroll
    for (int i = 0; i < CH / 4; ++i) {
      float4 v = cp[i];
      a0 += rf[4*i]   * v.x; a1 += rf[4*i+1] * v.y;
      a2 += rf[4*i+2] * v.z; a3 += rf[4*i+3] * v.w;
    }
    float dist = (sqn + csq[b4096 + c]) - 2.0f * ((a0 + a1) + (a2 + a3));
    dS[lr * NCAND + q] = dist;
    iS[lr * NCAND + q] = c;
  }
  __syncthreads();
  if (q == 0) {
    float gd[KNN]; int gi[KNN];
#pragma unroll
    for (int j = 0; j < KNN; ++j) { gd[j] = 3.4e38f; gi[j] = 0x7fffffff; }
    for (int s = 0; s < NCAND; ++s) {
      float dc = dS[lr * NCAND + s]; int ic = iS[lr * NCAND + s];
      if (dc < gd[KNN - 1] || (dc == gd[KNN - 1] && ic < gi[KNN - 1])) {
        gd[KNN - 1] = dc; gi[KNN - 1] = ic;
#pragma unroll
        for (int k2 = KNN - 1; k2 > 0; --k2) {
          bool sw = (gd[k2] < gd[k2 - 1]) ||
                    (gd[k2] == gd[k2 - 1] && gi[k2] < gi[k2 - 1]);
          if (sw) {
            float td = gd[k2]; gd[k2] = gd[k2 - 1]; gd[k2 - 1] = td;
            int ti = gi[k2]; gi[k2] = gi[k2 - 1]; gi[k2 - 1] = ti;
          }
        }
      }
    }
    u16* o = nn + (size_t)row * KNN;
    int jmax = (row == NBN - 1) ? (KNN - 1) : KNN;   // linspace tail drop
#pragma unroll
    for (int j = 0; j < KNN; ++j) o[j] = (u16)(gi[j] & (NPTS - 1));
    for (int j = 0; j < jmax; ++j)
      atomicAdd(&deg[b4096 + (gi[j] & (NPTS - 1))], 1);
  }
}

// k_out: 64 nodes/block x 4 threads/node (12 out-channels each), XCD swizzle.
#define ONB 64
#define LPAD 52
__global__ __launch_bounds__(256)
void k_out_f(const float* __restrict__ xraw, const u16* __restrict__ nn,
             const int* __restrict__ deg,
             const float* __restrict__ W0, const float* __restrict__ W1,
             const float* __restrict__ bias, float* __restrict__ out) {
  __shared__ float w0[CH * CH], w1[CH * CH], bs[CH];
  __shared__ __align__(16) float fS[ONB * LPAD];
  __shared__ __align__(16) float txS[ONB * LPAD];
  __shared__ float dinvS[ONB];
  int tid = threadIdx.x;
  int bi = blockIdx.x;
  int n0 = (bi & 7) * NPTS + (bi >> 3) * ONB;   // XCD swizzle (perf-only)
  int b12 = n0 & ~(NPTS - 1);
  for (int i = tid; i < CH * CH; i += 256) { w0[i] = W0[i]; w1[i] = W1[i]; }
  if (tid < CH) bs[tid] = bias[tid];
  for (int i = tid; i < ONB * 12; i += 256) {
    int ln = i / 12, f4 = i % 12;
    *(float4*)(fS + ln * LPAD + f4 * 4) =
        *(const float4*)(xraw + (size_t)(n0 + ln) * CH + f4 * 4);
  }
  if (tid < ONB) {
    int dg = deg[n0 + tid];
    dinvS[tid] = (dg > 0) ? (1.0f / sqrtf((float)dg)) : 0.0f;
  }
  __syncthreads();

  int ln = tid >> 2, p = tid & 3;
  int node = n0 + ln;
  float dn = dinvS[ln];
  const u16* nrow = nn + (size_t)node * KNN;
  bool full = (node != NBN - 1);
  float tx[12];
#pragma unroll
  for (int i = 0; i < 12; ++i) tx[i] = 0.f;
#pragma unroll
  for (int j = 0; j < KNN; ++j) {
    if (j < KNN - 1 || full) {
      int s = nrow[j] & (NPTS - 1);
      int dgs = deg[b12 + s];
      float ds = (dgs > 0) ? (1.0f / sqrtf((float)dgs)) : 0.0f;
      float w = -(ds * dn);
      const float4* pr = (const float4*)(xraw + (size_t)(b12 + s) * CH + p * 12);
#pragma unroll
      for (int q3 = 0; q3 < 3; ++q3) {
        float4 v = pr[q3];
        tx[q3*4]   += w * v.x; tx[q3*4+1] += w * v.y;
        tx[q3*4+2] += w * v.z; tx[q3*4+3] += w * v.w;
      }
    }
  }
#pragma unroll
  for (int q3 = 0; q3 < 3; ++q3)
    *(float4*)(txS + ln * LPAD + p * 12 + q3 * 4) =
        make_float4(tx[q3*4], tx[q3*4+1], tx[q3*4+2], tx[q3*4+3]);
  __syncthreads();

  float acc[12];
#pragma unroll
  for (int i = 0; i < 12; ++i) acc[i] = bs[p * 12 + i];
  const float* fr = fS + ln * LPAD;
  const float* tr = txS + ln * LPAD;
#pragma unroll
  for (int c = 0; c < CH; ++c) {
    float fc = fr[c];
    const float* wr = w0 + c * CH + p * 12;
#pragma unroll
    for (int i = 0; i < 12; ++i) acc[i] += fc * wr[i];
  }
#pragma unroll
  for (int c = 0; c < CH; ++c) {
    float tc = tr[c];
    const float* wr = w1 + c * CH + p * 12;
#pragma unroll
    for (int i = 0; i < 12; ++i) acc[i] += tc * wr[i];
  }
  float* op = out + (size_t)node * CH + p * 12;
#pragma unroll
  for (int q3 = 0; q3 < 3; ++q3)
    *(float4*)(op + q3 * 4) =
        make_float4(acc[q3*4], acc[q3*4+1], acc[q3*4+2], acc[q3*4+3]);
}

// ======================= FALLBACK (round-4, proven) =======================
__global__ __launch_bounds__(256)
void k_zero(int* __restrict__ deg) { deg[blockIdx.x * 256 + threadIdx.x] = 0; }

__global__ __launch_bounds__(256)
void k_hist(const u16* __restrict__ nn, int* __restrict__ deg) {
  int node = blockIdx.x * 256 + threadIdx.x;
  int b12 = node & ~(NPTS - 1);
  int jmax = (node == NBN - 1) ? (KNN - 1) : KNN;
  for (int j = 0; j < jmax; ++j)
    atomicAdd(&deg[b12 + (nn[(size_t)node * KNN + j] & (NPTS - 1))], 1);
}

__global__ __launch_bounds__(256)
void k_dinv(const int* __restrict__ deg, float* __restrict__ dinv) {
  int i = blockIdx.x * 256 + threadIdx.x;
  int dg = deg[i];
  dinv[i] = (dg > 0) ? (1.0f / sqrtf((float)dg)) : 0.0f;
}

#define NQ    4
#define QCOLS (NPTS/NQ)
#define TCOLS 32
#define NTILES (QCOLS/TCOLS)
#define RPB   64

__global__ __launch_bounds__(256)
void k_knn_nb(const float* __restrict__ x, u16* __restrict__ nn) {
  __shared__ __align__(16) float tile[NQ * TCOLS * CH];
  __shared__ float nrmS[NQ * TCOLS];
  __shared__ float csq[NQ * TCOLS];
  int tid = threadIdx.x;
  int r0 = blockIdx.x * RPB;
  int b  = r0 >> 12;
  int q  = tid >> 6;
  int lr = tid & 63;
  int n  = (r0 + lr) & (NPTS - 1);
  const float* xb = x + (size_t)b * CH * NPTS;
  float rf[CH];
#pragma unroll
  for (int c = 0; c < CH; ++c) rf[c] = xb[(size_t)c * NPTS + n];
  float sqn;
  {
    float a0 = 0, a1 = 0, a2 = 0, a3 = 0;
#pragma unroll
    for (int k = 0; k < CH; k += 4) {
      a0 += rf[k] * rf[k]; a1 += rf[k+1] * rf[k+1];
      a2 += rf[k+2] * rf[k+2]; a3 += rf[k+3] * rf[k+3];
    }
    float nrm = fmaxf(sqrtf((a0 + a1) + (a2 + a3)), 1e-12f);
#pragma unroll
    for (int c = 0; c < CH; ++c) rf[c] = rf[c] / nrm;
    a0 = a1 = a2 = a3 = 0;
#pragma unroll
    for (int k = 0; k < CH; k += 4) {
      a0 += rf[k] * rf[k]; a1 += rf[k+1] * rf[k+1];
      a2 += rf[k+2] * rf[k+2]; a3 += rf[k+3] * rf[k+3];
    }
    sqn = (a0 + a1) + (a2 + a3);
  }
  float d[KNN]; int id[KNN];
#pragma unroll
  for (int j = 0; j < KNN; ++j) { d[j] = 3.4e38f; id[j] = 0x7fffffff; }
  for (int t = 0; t < NTILES; ++t) {
    __syncthreads();
#pragma unroll
    for (int qq = 0; qq < NQ; ++qq) {
      int colbase = qq * QCOLS + t * TCOLS;
      float* dst = tile + qq * TCOLS * CH;
#pragma unroll
      for (int it = 0; it < 6; ++it) {
        int i = it * 256 + tid;
        int c = i >> 5, p = i & 31;
        dst[p * CH + c] = xb[(size_t)c * NPTS + colbase + p];
      }
    }
    __syncthreads();
    if (tid < NQ * TCOLS) {
      const float* cp = tile + tid * CH;
      float a0 = 0, a1 = 0, a2 = 0, a3 = 0;
#pragma unroll
      for (int k = 0; k < CH; k += 4) {
        float4 v = *(const float4*)(cp + k);
        a0 += v.x * v.x; a1 += v.y * v.y; a2 += v.z * v.z; a3 += v.w * v.w;
      }
      nrmS[tid] = fmaxf(sqrtf((a0 + a1) + (a2 + a3)), 1e-12f);
    }
    __syncthreads();
    for (int i = tid; i < NQ * TCOLS * CH; i += 256)
      tile[i] = tile[i] / nrmS[i / CH];
    __syncthreads();
    if (tid < NQ * TCOLS) {
      const float* cp = tile + tid * CH;
      float a0 = 0, a1 = 0, a2 = 0, a3 = 0;
#pragma unroll
      for (int k = 0; k < CH; k += 4) {
        float4 v = *(const float4*)(cp + k);
        a0 += v.x * v.x; a1 += v.y * v.y; a2 += v.z * v.z; a3 += v.w * v.w;
      }
      csq[tid] = (a0 + a1) + (a2 + a3);
    }
    __syncthreads();
    int cbase = q * QCOLS + t * TCOLS;
    const float* tq = tile + q * TCOLS * CH;
    for (int cc = 0; cc < TCOLS; ++cc) {
      const float* cp = tq + cc * CH;
      float a0 = 0, a1 = 0, a2 = 0, a3 = 0;
#pragma unroll
      for (int k = 0; k < CH; k += 4) {
        float4 v = *(const float4*)(cp + k);
        a0 += rf[k] * v.x; a1 += rf[k+1] * v.y;
        a2 += rf[k+2] * v.z; a3 += rf[k+3] * v.w;
      }
      float dist = (sqn + csq[q * TCOLS + cc]) - 2.0f * ((a0 + a1) + (a2 + a3));
      if (dist < d[KNN - 1]) {
        d[KNN - 1] = dist; id[KNN - 1] = cbase + cc;
#pragma unroll
        for (int k2 = KNN - 1; k2 > 0; --k2) {
          if (d[k2] < d[k2 - 1]) {
            float td = d[k2]; d[k2] = d[k2 - 1]; d[k2 - 1] = td;
            int ti = id[k2]; id[k2] = id[k2 - 1]; id[k2 - 1] = ti;
          }
        }
      }
    }
  }
  __syncthreads();
  float* md = tile;
  int*   mi = (int*)(tile + 256 * KNN);
#pragma unroll
  for (int j = 0; j < KNN; ++j) { md[tid * KNN + j] = d[j]; mi[tid * KNN + j] = id[j]; }
  __syncthreads();
  if (tid < RPB) {
    float fd[KNN]; int fi[KNN];
#pragma unroll
    for (int j = 0; j < KNN; ++j) { fd[j] = 3.4e38f; fi[j] = 0x7fffffff; }
    for (int qq = 0; qq < NQ; ++qq) {
      int s = qq * RPB + tid;
      for (int j = 0; j < KNN; ++j) {
        float dc = md[s * KNN + j]; int ic = mi[s * KNN + j];
        if (dc < fd[KNN - 1]) {
          fd[KNN - 1] = dc; fi[KNN - 1] = ic;
#pragma unroll
          for (int k2 = KNN - 1; k2 > 0; --k2) {
            if (fd[k2] < fd[k2 - 1]) {
              float td = fd[k2]; fd[k2] = fd[k2 - 1]; fd[k2 - 1] = td;
              int ti = fi[k2]; fi[k2] = fi[k2 - 1]; fi[k2 - 1] = ti;
            }
          }
        }
      }
    }
    u16* o = nn + (size_t)(r0 + tid) * KNN;
#pragma unroll
    for (int j = 0; j < KNN; ++j) o[j] = (u16)(fi[j] & (NPTS - 1));
  }
}

__global__ __launch_bounds__(256)
void k_out_nb(const float* __restrict__ x, const u16* __restrict__ nn,
              const float* __restrict__ dinv,
              const float* __restrict__ W0, const float* __restrict__ W1,
              const float* __restrict__ bias, float* __restrict__ out) {
  __shared__ float w0[CH * CH], w1[CH * CH], bs[CH];
  for (int i = threadIdx.x; i < CH * CH; i += 256) { w0[i] = W0[i]; w1[i] = W1[i]; }
  if (threadIdx.x < CH) bs[threadIdx.x] = bias[threadIdx.x];
  __syncthreads();
  int node = blockIdx.x * 256 + threadIdx.x;
  int b = node >> 12, n = node & (NPTS - 1);
  const float* xb = x + (size_t)b * CH * NPTS;
  float f[CH], acc[CH], tx[CH];
#pragma unroll
  for (int c = 0; c < CH; ++c) f[c] = xb[(size_t)c * NPTS + n];
#pragma unroll
  for (int o = 0; o < CH; ++o) acc[o] = bs[o];
#pragma unroll
  for (int c = 0; c < CH; ++c) {
    float fc = f[c];
    const float* wr = w0 + c * CH;
#pragma unroll
    for (int o = 0; o < CH; ++o) acc[o] += fc * wr[o];
  }
#pragma unroll
  for (int c = 0; c < CH; ++c) tx[c] = 0.f;
  float dn = dinv[node];
  int jmax = (node == NBN - 1) ? (KNN - 1) : KNN;
  for (int j = 0; j < jmax; ++j) {
    int s = nn[(size_t)node * KNN + j] & (NPTS - 1);
    float w = -(dinv[(b << 12) + s] * dn);
#pragma unroll
    for (int c = 0; c < CH; ++c) tx[c] += w * xb[(size_t)c * NPTS + s];
  }
#pragma unroll
  for (int c = 0; c < CH; ++c) {
    float tc = tx[c];
    const float* wr = w1 + c * CH;
#pragma unroll
    for (int o = 0; o < CH; ++o) acc[o] += tc * wr[o];
  }
  float4* op = (float4*)(out + (size_t)node * CH);
#pragma unroll
  for (int i = 0; i < CH / 4; ++i)
    op[i] = make_float4(acc[4*i], acc[4*i+1], acc[4*i+2], acc[4*i+3]);
}

extern "C" void kernel_launch(void* const* d_in, const int* in_sizes, int n_in,
                              void* d_out, int out_size, void* d_ws, size_t ws_size,
                              hipStream_t stream) {
  const float* x    = (const float*)d_in[0];
  const float* W0   = (const float*)d_in[1];
  const float* W1   = (const float*)d_in[2];
  const float* bias = (const float*)d_in[3];
  float* out = (float*)d_out;
  char* w = (char*)d_ws;

  const size_t SZ_XN   = (size_t)NBN * CH * 4;            //  6,291,456
  const size_t SZ_XRAW = (size_t)NBN * CH * 4;            //  6,291,456
  const size_t SZ_CSQ  = (size_t)NBN * 4;                 //    131,072
  const size_t SZ_NN   = (size_t)NBN * KNN * 2;           //    589,824
  const size_t SZ_DEG  = (size_t)NBN * 4;                 //    131,072
  const size_t SZ_AB   = (size_t)NBN * 128 * 2;           //  8,388,608
  const size_t SZ_CU   = (size_t)NBN * 16 * NCAND * 4;    // 25,165,824 (u32)
  const size_t SZ_C12  = (size_t)NBN * NCAND * 4;         //  1,572,864
  const size_t needF = SZ_XN + SZ_XRAW + SZ_CSQ + SZ_NN + SZ_DEG
                     + 2 * SZ_AB + SZ_CU + SZ_C12;        // ~56.9 MB

  if (ws_size >= needF) {          // FAST path: MFMA filter + reduce + rescore
    size_t off = 0;
    float* xn   = (float*)(w + off); off += SZ_XN;
    float* xraw = (float*)(w + off); off += SZ_XRAW;
    float* csq  = (float*)(w + off); off += SZ_CSQ;
    u16*   nn   = (u16*)  (w + off); off += SZ_NN;
    int*   deg  = (int*)  (w + off); off += SZ_DEG;
    u16*   Abuf = (u16*)  (w + off); off += SZ_AB;
    u16*   Bbuf = (u16*)  (w + off); off += SZ_AB;
    u32*   candu= (u32*)  (w + off); off += SZ_CU;
    u32*   cand12=(u32*)  (w + off);
    k_prep    <<<NBN / 256, 256, 0, stream>>>(x, xraw, xn, csq, Abuf, Bbuf, deg);
    k_knn_m   <<<dim3(NBN / 64, 4), 256, 0, stream>>>(Abuf, Bbuf, candu);
    k_reduce  <<<NBN / 64, 256, 0, stream>>>(candu, cand12);
    k_rescore <<<NBN / RR, 256, 0, stream>>>(xn, csq, cand12, nn, deg);
    k_out_f   <<<NBN / ONB, 256, 0, stream>>>(xraw, nn, deg, W0, W1, bias, out);
  } else {                         // FALLBACK: proven round-4 path (852 KB)
    u16*   nn   = (u16*)w;
    int*   deg  = (int*)(w + SZ_NN);
    float* dinv = (float*)(w + SZ_NN + SZ_DEG);
    k_knn_nb <<<NBN / RPB, 256, 0, stream>>>(x, nn);
    k_zero   <<<NBN / 256, 256, 0, stream>>>(deg);
    k_hist   <<<NBN / 256, 256, 0, stream>>>(nn, deg);
    k_dinv   <<<NBN / 256, 256, 0, stream>>>(deg, dinv);
    k_out_nb <<<NBN / 256, 256, 0, stream>>>(x, nn, dinv, W0, W1, bias, out);
  }
}

// Round 6
// 208.179 us; speedup vs baseline: 1.3591x; 1.0277x over previous
//
#include <hip/hip_runtime.h>

#define BATCH 8
#define CH    48
#define NPTS  4096
#define NBN   (BATCH*NPTS)
#define KNN   9
#define NCAND 12             // per-lane filter depth

typedef unsigned short u16;
typedef unsigned int   u32;
typedef unsigned long long u64;
typedef __bf16 bf16x8 __attribute__((ext_vector_type(8)));
typedef float  f32x4  __attribute__((ext_vector_type(4)));

__device__ __forceinline__ float bf2f(u16 v) { return __uint_as_float(((u32)v) << 16); }
__device__ __forceinline__ u16 f2bf(float f) {
  u32 u = __float_as_uint(f);
  u = (u + 0x7fffu + ((u >> 16) & 1u)) >> 16;
  return (u16)u;
}

// Shared med3 insert: insert x into sorted p0<=...<=p11 keeping smallest 12.
//   p_i' = med3(p_{i-1}, p_i, x) (i=11..1, old values), p0' = min(p0, x).
#define MED3U(d, a, b, c) \
  asm("v_med3_u32 %0, %1, %2, %3" : "=v"(d) : "v"(a), "v"(b), "v"(c))
#define INS12(p0,p1,p2,p3,p4,p5,p6,p7,p8,p9,p10,p11,x) do { \
  MED3U(p11,p10,p11,x); MED3U(p10,p9,p10,x); MED3U(p9,p8,p9,x);  \
  MED3U(p8, p7, p8, x); MED3U(p7, p6,p7, x); MED3U(p6,p5,p6,x);  \
  MED3U(p5, p4, p5, x); MED3U(p4, p3,p4, x); MED3U(p3,p2,p3,x);  \
  MED3U(p2, p1, p2, x); MED3U(p1, p0,p1, x); p0 = min(p0, x);    \
} while (0)

// async global->LDS staging: per-lane global src, wave-uniform LDS base
// (HW adds lane*16B). 16B/lane x 64 lanes = 1 KB per call.
__device__ __forceinline__ void stage_q(const u16* g, u16* l) {
  __builtin_amdgcn_global_load_lds(
      (const __attribute__((address_space(1))) void*)g,
      (__attribute__((address_space(3))) void*)l, 16, 0, 0);
}

// ======================= FAST PATH (ws >= ~57 MB) =======================
// k_prep: normalize per reference; write xraw/xn fp32 node-major, csq;
// build hi/lo-split bf16 operands. A layout MFMA-coalesced:
// [tile16][variant(4)][lane(64)][8 bf16]; B [node][128]. Zero deg.
__global__ __launch_bounds__(256)
void k_prep(const float* __restrict__ x, float* __restrict__ xraw,
            float* __restrict__ xn, float* __restrict__ csq,
            u16* __restrict__ Abuf, u16* __restrict__ Bbuf,
            int* __restrict__ deg) {
  int node = blockIdx.x * 256 + threadIdx.x;
  deg[node] = 0;
  int b = node >> 12, n = node & (NPTS - 1);
  const float* xb = x + (size_t)b * CH * NPTS;
  float f[CH];
#pragma unroll
  for (int c = 0; c < CH; ++c) f[c] = xb[(size_t)c * NPTS + n];
  float a0 = 0, a1 = 0, a2 = 0, a3 = 0;
#pragma unroll
  for (int k = 0; k < CH; k += 4) {
    a0 += f[k] * f[k]; a1 += f[k+1] * f[k+1];
    a2 += f[k+2] * f[k+2]; a3 += f[k+3] * f[k+3];
  }
  float nrm = fmaxf(sqrtf((a0 + a1) + (a2 + a3)), 1e-12f);
  float xv[CH];
#pragma unroll
  for (int c = 0; c < CH; ++c) xv[c] = f[c] / nrm;     // true division (ref)
  a0 = a1 = a2 = a3 = 0;
#pragma unroll
  for (int k = 0; k < CH; k += 4) {
    a0 += xv[k] * xv[k]; a1 += xv[k+1] * xv[k+1];
    a2 += xv[k+2] * xv[k+2]; a3 += xv[k+3] * xv[k+3];
  }
  float csqv = (a0 + a1) + (a2 + a3);
  csq[node] = csqv;
  float4* ro = (float4*)(xraw + (size_t)node * CH);
  float4* no = (float4*)(xn   + (size_t)node * CH);
#pragma unroll
  for (int i = 0; i < CH / 4; ++i) {
    ro[i] = make_float4(f[4*i], f[4*i+1], f[4*i+2], f[4*i+3]);
    no[i] = make_float4(xv[4*i], xv[4*i+1], xv[4*i+2], xv[4*i+3]);
  }
  u16 ah[64], al[64];
#pragma unroll
  for (int k = 0; k < CH; ++k) {
    float av = -2.0f * xv[k];
    u16 h = f2bf(av); ah[k] = h; al[k] = f2bf(av - bf2f(h));
  }
  { u16 h = f2bf(csqv); ah[48] = h; al[48] = f2bf(csqv - bf2f(h)); }
#pragma unroll
  for (int k = 49; k < 64; ++k) { ah[k] = 0; al[k] = 0; }
  u16* Bh = Bbuf + (size_t)node * 128;
#pragma unroll
  for (int k = 0; k < CH; ++k) {
    float bv = xv[k];
    u16 h = f2bf(bv); Bh[k] = h; Bh[64 + k] = f2bf(bv - bf2f(h));
  }
  Bh[48] = 0x3F80; Bh[64 + 48] = 0;            // 1.0 bf16 exact
#pragma unroll
  for (int k = 49; k < 64; ++k) { Bh[k] = 0; Bh[64 + k] = 0; }
  u16* Ag = Abuf + (size_t)(node >> 4) * 2048 + (size_t)(node & 15) * 8;
#pragma unroll
  for (int v = 0; v < 4; ++v) {
    const u16* src = (v < 2) ? ah : al;
    int koff = (v & 1) * 32;
#pragma unroll
    for (int q = 0; q < 4; ++q) {
      uint4 pk;
      const u16* s = src + koff + q * 8;
      pk.x = (u32)s[0] | ((u32)s[1] << 16);
      pk.y = (u32)s[2] | ((u32)s[3] << 16);
      pk.z = (u32)s[4] | ((u32)s[5] << 16);
      pk.w = (u32)s[6] | ((u32)s[7] << 16);
      *(uint4*)(Ag + v * 512 + q * 128) = pk;
    }
  }
}

// k_knn_m: wave = 16-row panel; blockIdx.y = column quarter (64 tiles of 16).
// A-tiles staged block-cooperatively into LDS via global_load_lds.
// 2-TILE BARRIER PERIODS: __syncthreads drains vmcnt(0), so a 1-tile period
// puts each staged load's L2 round-trip (~200-400cy) on the critical path
// against ~160cy of compute (round-5 residual). Processing 2 tiles per
// barrier gives the stage ~250-300cy of MFMA+filter cover and halves the
// barrier count. Schedule/period: LDA(t0); stage(t0+2,t0+3); MFMA(acc0);
// FILTER(prev acc1); LDA(t1); MFMA(acc1); FILTER(acc0); barrier.
// KEY: MFMA computes csq_col - 2<x_col,x_row> in [-1-eps,3+eps]; +2.5 bias
// -> strictly positive keys, raw-bits monotone. Key u32 = (bits &
// 0xFFFFF000) | global_col(12b); exact-rescore absorbs ~1e-3 quantization.
__global__ __launch_bounds__(256, 6)
void k_knn_m(const u16* __restrict__ Abuf, const u16* __restrict__ Bbuf,
             u32* __restrict__ candu) {
  __shared__ __align__(16) u16 As[2][2][2048];   // [period parity][slot] 16 KB
  int tid = threadIdx.x;
  int lane = tid & 63;
  int wv = tid >> 6;
  int quad = lane >> 4, m16 = lane & 15;
  int panel = blockIdx.x * 4 + wv;
  int row = panel * 16 + m16;
  int b4096 = row & ~(NPTS - 1);
  int quarter = blockIdx.y;
  int ct0 = quarter * 64;

  const __bf16* Bb = (const __bf16*)Bbuf + (size_t)row * 128;
  bf16x8 bh0 = *(const bf16x8*)(Bb + quad * 8);
  bf16x8 bh1 = *(const bf16x8*)(Bb + 32 + quad * 8);
  bf16x8 bl0 = *(const bf16x8*)(Bb + 64 + quad * 8);
  bf16x8 bl1 = *(const bf16x8*)(Bb + 96 + quad * 8);

  // tiles ct0..ct0+63 for this batch; per-wave staging src (quarter wv)
  const u16* gs = Abuf + ((size_t)(b4096 >> 4) + ct0) * 2048
                  + wv * 512 + lane * 8;

  u32 s0=~0u,s1=~0u,s2=~0u,s3=~0u,s4=~0u,s5=~0u,
      s6=~0u,s7=~0u,s8=~0u,s9=~0u,s10=~0u,s11=~0u;

  const f32x4 C25 = {2.5f, 2.5f, 2.5f, 2.5f};

#define LDA(P, S, A0,A1,A2,A3) do {                                         \
    const u16* _p = &As[P][S][lane * 8];                                    \
    A0 = *(const bf16x8*)(_p);                                              \
    A1 = *(const bf16x8*)(_p + 512);                                        \
    A2 = *(const bf16x8*)(_p + 1024);                                       \
    A3 = *(const bf16x8*)(_p + 1536);                                       \
  } while (0)
#define MFMA6(ACC, A0,A1,A2,A3) do {                                        \
    ACC = __builtin_amdgcn_mfma_f32_16x16x32_bf16(A0, bh0, C25, 0, 0, 0);   \
    ACC = __builtin_amdgcn_mfma_f32_16x16x32_bf16(A1, bh1, ACC, 0, 0, 0);   \
    ACC = __builtin_amdgcn_mfma_f32_16x16x32_bf16(A0, bl0, ACC, 0, 0, 0);   \
    ACC = __builtin_amdgcn_mfma_f32_16x16x32_bf16(A1, bl1, ACC, 0, 0, 0);   \
    ACC = __builtin_amdgcn_mfma_f32_16x16x32_bf16(A2, bh0, ACC, 0, 0, 0);   \
    ACC = __builtin_amdgcn_mfma_f32_16x16x32_bf16(A3, bh1, ACC, 0, 0, 0);   \
  } while (0)
#define FILTER(ACC, CT) do {                                                \
    u32 _colb = ((u32)(CT) << 4) | ((u32)quad << 2);                        \
    _Pragma("unroll")                                                       \
    for (int _r = 0; _r < 4; ++_r) {                                        \
      u32 _u = __float_as_uint((ACC)[_r]);                                  \
      u32 _x = (_u & 0xFFFFF000u) | (_colb | (u32)_r);                      \
      INS12(s0,s1,s2,s3,s4,s5,s6,s7,s8,s9,s10,s11, _x);                     \
    }                                                                       \
  } while (0)

  f32x4 accA, accB;
  bf16x8 a0, a1, a2, a3;

  // prologue: stage tiles 0,1 -> parity 0
  stage_q(gs,        &As[0][0][wv * 512]);
  stage_q(gs + 2048, &As[0][1][wv * 512]);
  __syncthreads();

  // period 0: tiles 0,1 from parity 0; stage tiles 2,3 -> parity 1
  LDA(0, 0, a0, a1, a2, a3);
  stage_q(gs + (size_t)2 * 2048, &As[1][0][wv * 512]);
  stage_q(gs + (size_t)3 * 2048, &As[1][1][wv * 512]);
  MFMA6(accA, a0, a1, a2, a3);
  LDA(0, 1, a0, a1, a2, a3);
  MFMA6(accB, a0, a1, a2, a3);
  FILTER(accA, ct0 + 0);
  __syncthreads();

  for (int p = 1; p < 31; ++p) {
    int par = p & 1;
    LDA(par, 0, a0, a1, a2, a3);
    stage_q(gs + (size_t)(2 * p + 2) * 2048, &As[par ^ 1][0][wv * 512]);
    stage_q(gs + (size_t)(2 * p + 3) * 2048, &As[par ^ 1][1][wv * 512]);
    MFMA6(accA, a0, a1, a2, a3);          // tile 2p
    FILTER(accB, ct0 + 2 * p - 1);        // finish tile 2p-1 (covers latency)
    LDA(par, 1, a0, a1, a2, a3);
    MFMA6(accB, a0, a1, a2, a3);          // tile 2p+1
    FILTER(accA, ct0 + 2 * p);
    __syncthreads();
  }
  // period 31 (parity 1): tiles 62,63; no stage
  LDA(1, 0, a0, a1, a2, a3);
  MFMA6(accA, a0, a1, a2, a3);
  FILTER(accB, ct0 + 61);
  LDA(1, 1, a0, a1, a2, a3);
  MFMA6(accB, a0, a1, a2, a3);
  FILTER(accA, ct0 + 62);
  FILTER(accB, ct0 + 63);
#undef LDA
#undef MFMA6
#undef FILTER

  u32* o = candu + (((size_t)row * 4 + quarter) * 4 + quad) * NCAND;
  o[0]=s0; o[1]=s1; o[2]=s2; o[3]=s3; o[4]=s4; o[5]=s5;
  o[6]=s6; o[7]=s7; o[8]=s8; o[9]=s9; o[10]=s10; o[11]=s11;
}

// k_reduce: per row, top-12 of the 192 u32 candidates. 64 rows/block x 4
// threads/row; med3 insert network; 2-stage (48 each -> 48 merged by thread
// 0). Loads vectorized to uint4 (12 x 16B/lane instead of 48 x 4B).
__global__ __launch_bounds__(256, 4)
void k_reduce(const u32* __restrict__ candu, u32* __restrict__ cand12) {
  __shared__ __align__(16) u32 ls[64 * 4 * NCAND];   // 12,288 B
  int tid = threadIdx.x;
  int lr = tid >> 2, q = tid & 3;
  int row = blockIdx.x * 64 + lr;
  const uint4* src = (const uint4*)(candu + (size_t)row * 192 + q * 48);
  u32 t0=~0u,t1=~0u,t2=~0u,t3=~0u,t4=~0u,t5=~0u,
      t6=~0u,t7=~0u,t8=~0u,t9=~0u,t10=~0u,t11=~0u;
  for (int s = 0; s < 12; ++s) {
    uint4 v = src[s];
    INS12(t0,t1,t2,t3,t4,t5,t6,t7,t8,t9,t10,t11, v.x);
    INS12(t0,t1,t2,t3,t4,t5,t6,t7,t8,t9,t10,t11, v.y);
    INS12(t0,t1,t2,t3,t4,t5,t6,t7,t8,t9,t10,t11, v.z);
    INS12(t0,t1,t2,t3,t4,t5,t6,t7,t8,t9,t10,t11, v.w);
  }
  u32* lw = ls + (size_t)(lr * 4 + q) * NCAND;
  lw[0]=t0; lw[1]=t1; lw[2]=t2; lw[3]=t3; lw[4]=t4; lw[5]=t5;
  lw[6]=t6; lw[7]=t7; lw[8]=t8; lw[9]=t9; lw[10]=t10; lw[11]=t11;
  __syncthreads();
  if (q == 0) {
    u32 g0=~0u,g1=~0u,g2=~0u,g3=~0u,g4=~0u,g5=~0u,
        g6=~0u,g7=~0u,g8=~0u,g9=~0u,g10=~0u,g11=~0u;
    const uint4* lsrc = (const uint4*)(ls + (size_t)lr * 48);
    for (int s = 0; s < 12; ++s) {
      uint4 v = lsrc[s];
      INS12(g0,g1,g2,g3,g4,g5,g6,g7,g8,g9,g10,g11, v.x);
      INS12(g0,g1,g2,g3,g4,g5,g6,g7,g8,g9,g10,g11, v.y);
      INS12(g0,g1,g2,g3,g4,g5,g6,g7,g8,g9,g10,g11, v.z);
      INS12(g0,g1,g2,g3,g4,g5,g6,g7,g8,g9,g10,g11, v.w);
    }
    u32* o = cand12 + (size_t)row * NCAND;
    o[0]=(g0&0xFFFu); o[1]=(g1&0xFFFu); o[2]=(g2&0xFFFu);
    o[3]=(g3&0xFFFu); o[4]=(g4&0xFFFu); o[5]=(g5&0xFFFu);
    o[6]=(g6&0xFFFu); o[7]=(g7&0xFFFu); o[8]=(g8&0xFFFu);
    o[9]=(g9&0xFFFu); o[10]=(g10&0xFFFu); o[11]=(g11&0xFFFu);
  }
}

// k_rescore: 16 rows/block x 16 threads/row; threads 0..11 each gather ONE
// candidate row and compute the exact fp32 dist (proven formula); thread 0
// merges 12 with the exact (dist, idx) comparator -> top-9. Fused nn write
// + degree histogram (tail edge drop). Only 12 gathers/row.
#define RR 16
__global__ __launch_bounds__(256, 4)
void k_rescore(const float* __restrict__ xn, const float* __restrict__ csq,
               const u32* __restrict__ cand12,
               u16* __restrict__ nn, int* __restrict__ deg) {
  __shared__ float dS[RR * NCAND];
  __shared__ int   iS[RR * NCAND];
  int tid = threadIdx.x;
  int lr = tid >> 4, q = tid & 15;
  int bi = blockIdx.x;
  int row = (bi & 7) * NPTS + (bi >> 3) * RR + lr;   // XCD swizzle (perf-only)
  int b4096 = row & ~(NPTS - 1);
  const float* xnb = xn + (size_t)b4096 * CH;
  if (q < NCAND) {
    float rf[CH];
    const float4* p = (const float4*)(xn + (size_t)row * CH);
#pragma unroll
    for (int i = 0; i < CH / 4; ++i) {
      float4 v = p[i];
      rf[4*i] = v.x; rf[4*i+1] = v.y; rf[4*i+2] = v.z; rf[4*i+3] = v.w;
    }
    float sqn = csq[row];
    int c = (int)(cand12[(size_t)row * NCAND + q] & (NPTS - 1));
    const float4* cp = (const float4*)(xnb + (size_t)c * CH);
    float a0 = 0, a1 = 0, a2 = 0, a3 = 0;
#pragma unroll
    for (int i = 0; i < CH / 4; ++i) {
      float4 v = cp[i];
      a0 += rf[4*i]   * v.x; a1 += rf[4*i+1] * v.y;
      a2 += rf[4*i+2] * v.z; a3 += rf[4*i+3] * v.w;
    }
    float dist = (sqn + csq[b4096 + c]) - 2.0f * ((a0 + a1) + (a2 + a3));
    dS[lr * NCAND + q] = dist;
    iS[lr * NCAND + q] = c;
  }
  __syncthreads();
  if (q == 0) {
    float gd[KNN]; int gi[KNN];
#pragma unroll
    for (int j = 0; j < KNN; ++j) { gd[j] = 3.4e38f; gi[j] = 0x7fffffff; }
    for (int s = 0; s < NCAND; ++s) {
      float dc = dS[lr * NCAND + s]; int ic = iS[lr * NCAND + s];
      if (dc < gd[KNN - 1] || (dc == gd[KNN - 1] && ic < gi[KNN - 1])) {
        gd[KNN - 1] = dc; gi[KNN - 1] = ic;
#pragma unroll
        for (int k2 = KNN - 1; k2 > 0; --k2) {
          bool sw = (gd[k2] < gd[k2 - 1]) ||
                    (gd[k2] == gd[k2 - 1] && gi[k2] < gi[k2 - 1]);
          if (sw) {
            float td = gd[k2]; gd[k2] = gd[k2 - 1]; gd[k2 - 1] = td;
            int ti = gi[k2]; gi[k2] = gi[k2 - 1]; gi[k2 - 1] = ti;
          }
        }
      }
    }
    u16* o = nn + (size_t)row * KNN;
    int jmax = (row == NBN - 1) ? (KNN - 1) : KNN;   // linspace tail drop
#pragma unroll
    for (int j = 0; j < KNN; ++j) o[j] = (u16)(gi[j] & (NPTS - 1));
    for (int j = 0; j < jmax; ++j)
      atomicAdd(&deg[b4096 + (gi[j] & (NPTS - 1))], 1);
  }
}

// k_out: 64 nodes/block x 4 threads/node (12 out-channels each), XCD swizzle.
#define ONB 64
#define LPAD 52
__global__ __launch_bounds__(256)
void k_out_f(const float* __restrict__ xraw, const u16* __restrict__ nn,
             const int* __restrict__ deg,
             const float* __restrict__ W0, const float* __restrict__ W1,
             const float* __restrict__ bias, float* __restrict__ out) {
  __shared__ float w0[CH * CH], w1[CH * CH], bs[CH];
  __shared__ __align__(16) float fS[ONB * LPAD];
  __shared__ __align__(16) float txS[ONB * LPAD];
  __shared__ float dinvS[ONB];
  int tid = threadIdx.x;
  int bi = blockIdx.x;
  int n0 = (bi & 7) * NPTS + (bi >> 3) * ONB;   // XCD swizzle (perf-only)
  int b12 = n0 & ~(NPTS - 1);
  for (int i = tid; i < CH * CH; i += 256) { w0[i] = W0[i]; w1[i] = W1[i]; }
  if (tid < CH) bs[tid] = bias[tid];
  for (int i = tid; i < ONB * 12; i += 256) {
    int ln = i / 12, f4 = i % 12;
    *(float4*)(fS + ln * LPAD + f4 * 4) =
        *(const float4*)(xraw + (size_t)(n0 + ln) * CH + f4 * 4);
  }
  if (tid < ONB) {
    int dg = deg[n0 + tid];
    dinvS[tid] = (dg > 0) ? (1.0f / sqrtf((float)dg)) : 0.0f;
  }
  __syncthreads();

  int ln = tid >> 2, p = tid & 3;
  int node = n0 + ln;
  float dn = dinvS[ln];
  const u16* nrow = nn + (size_t)node * KNN;
  bool full = (node != NBN - 1);
  float tx[12];
#pragma unroll
  for (int i = 0; i < 12; ++i) tx[i] = 0.f;
#pragma unroll
  for (int j = 0; j < KNN; ++j) {
    if (j < KNN - 1 || full) {
      int s = nrow[j] & (NPTS - 1);
      int dgs = deg[b12 + s];
      float ds = (dgs > 0) ? (1.0f / sqrtf((float)dgs)) : 0.0f;
      float w = -(ds * dn);
      const float4* pr = (const float4*)(xraw + (size_t)(b12 + s) * CH + p * 12);
#pragma unroll
      for (int q3 = 0; q3 < 3; ++q3) {
        float4 v = pr[q3];
        tx[q3*4]   += w * v.x; tx[q3*4+1] += w * v.y;
        tx[q3*4+2] += w * v.z; tx[q3*4+3] += w * v.w;
      }
    }
  }
#pragma unroll
  for (int q3 = 0; q3 < 3; ++q3)
    *(float4*)(txS + ln * LPAD + p * 12 + q3 * 4) =
        make_float4(tx[q3*4], tx[q3*4+1], tx[q3*4+2], tx[q3*4+3]);
  __syncthreads();

  float acc[12];
#pragma unroll
  for (int i = 0; i < 12; ++i) acc[i] = bs[p * 12 + i];
  const float* fr = fS + ln * LPAD;
  const float* tr = txS + ln * LPAD;
#pragma unroll
  for (int c = 0; c < CH; ++c) {
    float fc = fr[c];
    const float* wr = w0 + c * CH + p * 12;
#pragma unroll
    for (int i = 0; i < 12; ++i) acc[i] += fc * wr[i];
  }
#pragma unroll
  for (int c = 0; c < CH; ++c) {
    float tc = tr[c];
    const float* wr = w1 + c * CH + p * 12;
#pragma unroll
    for (int i = 0; i < 12; ++i) acc[i] += tc * wr[i];
  }
  float* op = out + (size_t)node * CH + p * 12;
#pragma unroll
  for (int q3 = 0; q3 < 3; ++q3)
    *(float4*)(op + q3 * 4) =
        make_float4(acc[q3*4], acc[q3*4+1], acc[q3*4+2], acc[q3*4+3]);
}

// ======================= FALLBACK (round-4, proven) =======================
__global__ __launch_bounds__(256)
void k_zero(int* __restrict__ deg) { deg[blockIdx.x * 256 + threadIdx.x] = 0; }

__global__ __launch_bounds__(256)
void k_hist(const u16* __restrict__ nn, int* __restrict__ deg) {
  int node = blockIdx.x * 256 + threadIdx.x;
  int b12 = node & ~(NPTS - 1);
  int jmax = (node == NBN - 1) ? (KNN - 1) : KNN;
  for (int j = 0; j < jmax; ++j)
    atomicAdd(&deg[b12 + (nn[(size_t)node * KNN + j] & (NPTS - 1))], 1);
}

__global__ __launch_bounds__(256)
void k_dinv(const int* __restrict__ deg, float* __restrict__ dinv) {
  int i = blockIdx.x * 256 + threadIdx.x;
  int dg = deg[i];
  dinv[i] = (dg > 0) ? (1.0f / sqrtf((float)dg)) : 0.0f;
}

#define NQ    4
#define QCOLS (NPTS/NQ)
#define TCOLS 32
#define NTILES (QCOLS/TCOLS)
#define RPB   64

__global__ __launch_bounds__(256)
void k_knn_nb(const float* __restrict__ x, u16* __restrict__ nn) {
  __shared__ __align__(16) float tile[NQ * TCOLS * CH];
  __shared__ float nrmS[NQ * TCOLS];
  __shared__ float csq[NQ * TCOLS];
  int tid = threadIdx.x;
  int r0 = blockIdx.x * RPB;
  int b  = r0 >> 12;
  int q  = tid >> 6;
  int lr = tid & 63;
  int n  = (r0 + lr) & (NPTS - 1);
  const float* xb = x + (size_t)b * CH * NPTS;
  float rf[CH];
#pragma unroll
  for (int c = 0; c < CH; ++c) rf[c] = xb[(size_t)c * NPTS + n];
  float sqn;
  {
    float a0 = 0, a1 = 0, a2 = 0, a3 = 0;
#pragma unroll
    for (int k = 0; k < CH; k += 4) {
      a0 += rf[k] * rf[k]; a1 += rf[k+1] * rf[k+1];
      a2 += rf[k+2] * rf[k+2]; a3 += rf[k+3] * rf[k+3];
    }
    float nrm = fmaxf(sqrtf((a0 + a1) + (a2 + a3)), 1e-12f);
#pragma unroll
    for (int c = 0; c < CH; ++c) rf[c] = rf[c] / nrm;
    a0 = a1 = a2 = a3 = 0;
#pragma unroll
    for (int k = 0; k < CH; k += 4) {
      a0 += rf[k] * rf[k]; a1 += rf[k+1] * rf[k+1];
      a2 += rf[k+2] * rf[k+2]; a3 += rf[k+3] * rf[k+3];
    }
    sqn = (a0 + a1) + (a2 + a3);
  }
  float d[KNN]; int id[KNN];
#pragma unroll
  for (int j = 0; j < KNN; ++j) { d[j] = 3.4e38f; id[j] = 0x7fffffff; }
  for (int t = 0; t < NTILES; ++t) {
    __syncthreads();
#pragma unroll
    for (int qq = 0; qq < NQ; ++qq) {
      int colbase = qq * QCOLS + t * TCOLS;
      float* dst = tile + qq * TCOLS * CH;
#pragma unroll
      for (int it = 0; it < 6; ++it) {
        int i = it * 256 + tid;
        int c = i >> 5, p = i & 31;
        dst[p * CH + c] = xb[(size_t)c * NPTS + colbase + p];
      }
    }
    __syncthreads();
    if (tid < NQ * TCOLS) {
      const float* cp = tile + tid * CH;
      float a0 = 0, a1 = 0, a2 = 0, a3 = 0;
#pragma unroll
      for (int k = 0; k < CH; k += 4) {
        float4 v = *(const float4*)(cp + k);
        a0 += v.x * v.x; a1 += v.y * v.y; a2 += v.z * v.z; a3 += v.w * v.w;
      }
      nrmS[tid] = fmaxf(sqrtf((a0 + a1) + (a2 + a3)), 1e-12f);
    }
    __syncthreads();
    for (int i = tid; i < NQ * TCOLS * CH; i += 256)
      tile[i] = tile[i] / nrmS[i / CH];
    __syncthreads();
    if (tid < NQ * TCOLS) {
      const float* cp = tile + tid * CH;
      float a0 = 0, a1 = 0, a2 = 0, a3 = 0;
#pragma unroll
      for (int k = 0; k < CH; k += 4) {
        float4 v = *(const float4*)(cp + k);
        a0 += v.x * v.x; a1 += v.y * v.y; a2 += v.z * v.z; a3 += v.w * v.w;
      }
      csq[tid] = (a0 + a1) + (a2 + a3);
    }
    __syncthreads();
    int cbase = q * QCOLS + t * TCOLS;
    const float* tq = tile + q * TCOLS * CH;
    for (int cc = 0; cc < TCOLS; ++cc) {
      const float* cp = tq + cc * CH;
      float a0 = 0, a1 = 0, a2 = 0, a3 = 0;
#pragma unroll
      for (int k = 0; k < CH; k += 4) {
        float4 v = *(const float4*)(cp + k);
        a0 += rf[k] * v.x; a1 += rf[k+1] * v.y;
        a2 += rf[k+2] * v.z; a3 += rf[k+3] * v.w;
      }
      float dist = (sqn + csq[q * TCOLS + cc]) - 2.0f * ((a0 + a1) + (a2 + a3));
      if (dist < d[KNN - 1]) {
        d[KNN - 1] = dist; id[KNN - 1] = cbase + cc;
#pragma unroll
        for (int k2 = KNN - 1; k2 > 0; --k2) {
          if (d[k2] < d[k2 - 1]) {
            float td = d[k2]; d[k2] = d[k2 - 1]; d[k2 - 1] = td;
            int ti = id[k2]; id[k2] = id[k2 - 1]; id[k2 - 1] = ti;
          }
        }
      }
    }
  }
  __syncthreads();
  float* md = tile;
  int*   mi = (int*)(tile + 256 * KNN);
#pragma unroll
  for (int j = 0; j < KNN; ++j) { md[tid * KNN + j] = d[j]; mi[tid * KNN + j] = id[j]; }
  __syncthreads();
  if (tid < RPB) {
    float fd[KNN]; int fi[KNN];
#pragma unroll
    for (int j = 0; j < KNN; ++j) { fd[j] = 3.4e38f; fi[j] = 0x7fffffff; }
    for (int qq = 0; qq < NQ; ++qq) {
      int s = qq * RPB + tid;
      for (int j = 0; j < KNN; ++j) {
        float dc = md[s * KNN + j]; int ic = mi[s * KNN + j];
        if (dc < fd[KNN - 1]) {
          fd[KNN - 1] = dc; fi[KNN - 1] = ic;
#pragma unroll
          for (int k2 = KNN - 1; k2 > 0; --k2) {
            if (fd[k2] < fd[k2 - 1]) {
              float td = fd[k2]; fd[k2] = fd[k2 - 1]; fd[k2 - 1] = td;
              int ti = fi[k2]; fi[k2] = fi[k2 - 1]; fi[k2 - 1] = ti;
            }
          }
        }
      }
    }
    u16* o = nn + (size_t)(r0 + tid) * KNN;
#pragma unroll
    for (int j = 0; j < KNN; ++j) o[j] = (u16)(fi[j] & (NPTS - 1));
  }
}

__global__ __launch_bounds__(256)
void k_out_nb(const float* __restrict__ x, const u16* __restrict__ nn,
              const float* __restrict__ dinv,
              const float* __restrict__ W0, const float* __restrict__ W1,
              const float* __restrict__ bias, float* __restrict__ out) {
  __shared__ float w0[CH * CH], w1[CH * CH], bs[CH];
  for (int i = threadIdx.x; i < CH * CH; i += 256) { w0[i] = W0[i]; w1[i] = W1[i]; }
  if (threadIdx.x < CH) bs[threadIdx.x] = bias[threadIdx.x];
  __syncthreads();
  int node = blockIdx.x * 256 + threadIdx.x;
  int b = node >> 12, n = node & (NPTS - 1);
  const float* xb = x + (size_t)b * CH * NPTS;
  float f[CH], acc[CH], tx[CH];
#pragma unroll
  for (int c = 0; c < CH; ++c) f[c] = xb[(size_t)c * NPTS + n];
#pragma unroll
  for (int o = 0; o < CH; ++o) acc[o] = bs[o];
#pragma unroll
  for (int c = 0; c < CH; ++c) {
    float fc = f[c];
    const float* wr = w0 + c * CH;
#pragma unroll
    for (int o = 0; o < CH; ++o) acc[o] += fc * wr[o];
  }
#pragma unroll
  for (int c = 0; c < CH; ++c) tx[c] = 0.f;
  float dn = dinv[node];
  int jmax = (node == NBN - 1) ? (KNN - 1) : KNN;
  for (int j = 0; j < jmax; ++j) {
    int s = nn[(size_t)node * KNN + j] & (NPTS - 1);
    float w = -(dinv[(b << 12) + s] * dn);
#pragma unroll
    for (int c = 0; c < CH; ++c) tx[c] += w * xb[(size_t)c * NPTS + s];
  }
#pragma unroll
  for (int c = 0; c < CH; ++c) {
    float tc = tx[c];
    const float* wr = w1 + c * CH;
#pragma unroll
    for (int o = 0; o < CH; ++o) acc[o] += tc * wr[o];
  }
  float4* op = (float4*)(out + (size_t)node * CH);
#pragma unroll
  for (int i = 0; i < CH / 4; ++i)
    op[i] = make_float4(acc[4*i], acc[4*i+1], acc[4*i+2], acc[4*i+3]);
}

extern "C" void kernel_launch(void* const* d_in, const int* in_sizes, int n_in,
                              void* d_out, int out_size, void* d_ws, size_t ws_size,
                              hipStream_t stream) {
  const float* x    = (const float*)d_in[0];
  const float* W0   = (const float*)d_in[1];
  const float* W1   = (const float*)d_in[2];
  const float* bias = (const float*)d_in[3];
  float* out = (float*)d_out;
  char* w = (char*)d_ws;

  const size_t SZ_XN   = (size_t)NBN * CH * 4;            //  6,291,456
  const size_t SZ_XRAW = (size_t)NBN * CH * 4;            //  6,291,456
  const size_t SZ_CSQ  = (size_t)NBN * 4;                 //    131,072
  const size_t SZ_NN   = (size_t)NBN * KNN * 2;           //    589,824
  const size_t SZ_DEG  = (size_t)NBN * 4;                 //    131,072
  const size_t SZ_AB   = (size_t)NBN * 128 * 2;           //  8,388,608
  const size_t SZ_CU   = (size_t)NBN * 16 * NCAND * 4;    // 25,165,824 (u32)
  const size_t SZ_C12  = (size_t)NBN * NCAND * 4;         //  1,572,864
  const size_t needF = SZ_XN + SZ_XRAW + SZ_CSQ + SZ_NN + SZ_DEG
                     + 2 * SZ_AB + SZ_CU + SZ_C12;        // ~56.9 MB

  if (ws_size >= needF) {          // FAST path: MFMA filter + reduce + rescore
    size_t off = 0;
    float* xn   = (float*)(w + off); off += SZ_XN;
    float* xraw = (float*)(w + off); off += SZ_XRAW;
    float* csq  = (float*)(w + off); off += SZ_CSQ;
    u16*   nn   = (u16*)  (w + off); off += SZ_NN;
    int*   deg  = (int*)  (w + off); off += SZ_DEG;
    u16*   Abuf = (u16*)  (w + off); off += SZ_AB;
    u16*   Bbuf = (u16*)  (w + off); off += SZ_AB;
    u32*   candu= (u32*)  (w + off); off += SZ_CU;
    u32*   cand12=(u32*)  (w + off);
    k_prep    <<<NBN / 256, 256, 0, stream>>>(x, xraw, xn, csq, Abuf, Bbuf, deg);
    k_knn_m   <<<dim3(NBN / 64, 4), 256, 0, stream>>>(Abuf, Bbuf, candu);
    k_reduce  <<<NBN / 64, 256, 0, stream>>>(candu, cand12);
    k_rescore <<<NBN / RR, 256, 0, stream>>>(xn, csq, cand12, nn, deg);
    k_out_f   <<<NBN / ONB, 256, 0, stream>>>(xraw, nn, deg, W0, W1, bias, out);
  } else {                         // FALLBACK: proven round-4 path (852 KB)
    u16*   nn   = (u16*)w;
    int*   deg  = (int*)(w + SZ_NN);
    float* dinv = (float*)(w + SZ_NN + SZ_DEG);
    k_knn_nb <<<NBN / RPB, 256, 0, stream>>>(x, nn);
    k_zero   <<<NBN / 256, 256, 0, stream>>>(deg);
    k_hist   <<<NBN / 256, 256, 0, stream>>>(nn, deg);
    k_dinv   <<<NBN / 256, 256, 0, stream>>>(deg, dinv);
    k_out_nb <<<NBN / 256, 256, 0, stream>>>(x, nn, dinv, W0, W1, bias, out);
  }
}

// Round 7
// 206.672 us; speedup vs baseline: 1.3690x; 1.0073x over previous
//
#include <hip/hip_runtime.h>

#define BATCH 8
#define CH    48
#define NPTS  4096
#define NBN   (BATCH*NPTS)
#define KNN   9
#define NCAND 12             // per-lane filter depth

typedef unsigned short u16;
typedef unsigned int   u32;
typedef unsigned long long u64;
typedef __bf16 bf16x8 __attribute__((ext_vector_type(8)));
typedef float  f32x4  __attribute__((ext_vector_type(4)));

__device__ __forceinline__ float bf2f(u16 v) { return __uint_as_float(((u32)v) << 16); }
__device__ __forceinline__ u16 f2bf(float f) {
  u32 u = __float_as_uint(f);
  u = (u + 0x7fffu + ((u >> 16) & 1u)) >> 16;
  return (u16)u;
}

// Shared med3 insert: insert x into sorted p0<=...<=p11 keeping smallest 12.
//   p_i' = med3(p_{i-1}, p_i, x) (i=11..1, old values), p0' = min(p0, x).
#define MED3U(d, a, b, c) \
  asm("v_med3_u32 %0, %1, %2, %3" : "=v"(d) : "v"(a), "v"(b), "v"(c))
#define INS12(p0,p1,p2,p3,p4,p5,p6,p7,p8,p9,p10,p11,x) do { \
  MED3U(p11,p10,p11,x); MED3U(p10,p9,p10,x); MED3U(p9,p8,p9,x);  \
  MED3U(p8, p7, p8, x); MED3U(p7, p6,p7, x); MED3U(p6,p5,p6,x);  \
  MED3U(p5, p4, p5, x); MED3U(p4, p3,p4, x); MED3U(p3,p2,p3,x);  \
  MED3U(p2, p1, p2, x); MED3U(p1, p0,p1, x); p0 = min(p0, x);    \
} while (0)

// async global->LDS staging: per-lane global src, wave-uniform LDS base
// (HW adds lane*16B). 16B/lane x 64 lanes = 1 KB per call.
__device__ __forceinline__ void stage_q(const u16* g, u16* l) {
  __builtin_amdgcn_global_load_lds(
      (const __attribute__((address_space(1))) void*)g,
      (__attribute__((address_space(3))) void*)l, 16, 0, 0);
}

// ======================= FAST PATH (ws >= ~45 MB) =======================
// k_prep (LEAN REWRITE): the old version kept f[48]+xv[48]+ah[64]+al[64]
// live -> ~170+ VGPRs -> scratch spills (rule: runtime arrays -> localMem),
// and launched only 128 blocks (half the CUs idle). New version: ONE
// division (rn=1/nrm) + multiplies; A/B packed words built and stored in
// 8-channel groups with no persistent arrays (peak live ~70 VGPR); 64-thr
// blocks x 512 spread over all CUs. Layouts unchanged:
// A [tile16][variant(4)][lane(64)][8 bf16]; B [node][hi 64 u16][lo 64 u16].
__global__ __launch_bounds__(64)
void k_prep(const float* __restrict__ x, float* __restrict__ xraw,
            float* __restrict__ xn, float* __restrict__ csq,
            u16* __restrict__ Abuf, u16* __restrict__ Bbuf,
            int* __restrict__ deg) {
  int node = blockIdx.x * 64 + threadIdx.x;
  deg[node] = 0;
  int b = node >> 12, n = node & (NPTS - 1);
  const float* xb = x + (size_t)b * CH * NPTS;
  float f[CH];
#pragma unroll
  for (int c = 0; c < CH; ++c) f[c] = xb[(size_t)c * NPTS + n];
  float a0 = 0, a1 = 0, a2 = 0, a3 = 0;
#pragma unroll
  for (int k = 0; k < CH; k += 4) {
    a0 += f[k] * f[k]; a1 += f[k+1] * f[k+1];
    a2 += f[k+2] * f[k+2]; a3 += f[k+3] * f[k+3];
  }
  float nrm = fmaxf(sqrtf((a0 + a1) + (a2 + a3)), 1e-12f);
  float rn = 1.0f / nrm;            // one exact division; xv = f*rn
  a0 = a1 = a2 = a3 = 0;
#pragma unroll
  for (int k = 0; k < CH; k += 4) {
    float v0 = f[k]*rn, v1 = f[k+1]*rn, v2 = f[k+2]*rn, v3 = f[k+3]*rn;
    a0 += v0*v0; a1 += v1*v1; a2 += v2*v2; a3 += v3*v3;
  }
  float csqv = (a0 + a1) + (a2 + a3);
  csq[node] = csqv;
  float4* ro = (float4*)(xraw + (size_t)node * CH);
  float4* no = (float4*)(xn   + (size_t)node * CH);
#pragma unroll
  for (int i = 0; i < CH / 4; ++i) {
    ro[i] = make_float4(f[4*i], f[4*i+1], f[4*i+2], f[4*i+3]);
    no[i] = make_float4(f[4*i]*rn, f[4*i+1]*rn, f[4*i+2]*rn, f[4*i+3]*rn);
  }
  uint4* Bo = (uint4*)(Bbuf + (size_t)node * 128);
  u16* Ag = Abuf + (size_t)(node >> 4) * 2048 + (size_t)(node & 15) * 8;
  // groups g=0..5: channels 8g..8g+7; build 4 uint4 (Bhi,Blo,Ahi,Alo), store.
#pragma unroll
  for (int g = 0; g < 6; ++g) {
    u32 bhw[4], blw[4], ahw[4], alw[4];
#pragma unroll
    for (int j = 0; j < 4; ++j) {
      int k = g * 8 + j * 2;
      float v0 = f[k] * rn, v1 = f[k+1] * rn;
      u16 h0 = f2bf(v0), h1 = f2bf(v1);
      u16 l0 = f2bf(v0 - bf2f(h0)), l1 = f2bf(v1 - bf2f(h1));
      bhw[j] = (u32)h0 | ((u32)h1 << 16);
      blw[j] = (u32)l0 | ((u32)l1 << 16);
      float w0 = -2.0f * v0, w1 = -2.0f * v1;
      u16 g0 = f2bf(w0), g1 = f2bf(w1);
      u16 m0 = f2bf(w0 - bf2f(g0)), m1 = f2bf(w1 - bf2f(g1));
      ahw[j] = (u32)g0 | ((u32)g1 << 16);
      alw[j] = (u32)m0 | ((u32)m1 << 16);
    }
    Bo[g]     = make_uint4(bhw[0], bhw[1], bhw[2], bhw[3]);
    Bo[8 + g] = make_uint4(blw[0], blw[1], blw[2], blw[3]);
    int v = g >> 2, q = g & 3;          // hi variant: v<2; lo at +1024
    *(uint4*)(Ag + v * 512 + q * 128)        = make_uint4(ahw[0], ahw[1], ahw[2], ahw[3]);
    *(uint4*)(Ag + 1024 + v * 512 + q * 128) = make_uint4(alw[0], alw[1], alw[2], alw[3]);
  }
  // g=6: ch48 = csq (A) / 1.0 (B); ch49-55 zero
  {
    u16 h = f2bf(csqv); u16 l = f2bf(csqv - bf2f(h));
    Bo[6]  = make_uint4(0x3F80u, 0, 0, 0);
    Bo[14] = make_uint4(0, 0, 0, 0);
    *(uint4*)(Ag + 512 + 2 * 128)        = make_uint4((u32)h, 0, 0, 0);
    *(uint4*)(Ag + 1024 + 512 + 2 * 128) = make_uint4((u32)l, 0, 0, 0);
  }
  // g=7: ch56-63 zero
  {
    uint4 z = make_uint4(0, 0, 0, 0);
    Bo[7] = z; Bo[15] = z;
    *(uint4*)(Ag + 512 + 3 * 128)        = z;
    *(uint4*)(Ag + 1024 + 512 + 3 * 128) = z;
  }
}

// k_knn_m: wave = 16-row panel; blockIdx.y = column HALF (128 tiles of 16).
// Halves (was quarters): per-lane candidates 256->512 (total filter ops
// unchanged) but candu traffic HALVES (25->12.6 MB) and k_reduce input
// halves (192->96/row). A-tiles staged block-cooperatively into LDS via
// global_load_lds, 2-tile barrier periods (round-6 structure).
// KEY: MFMA computes csq_col - 2<x_col,x_row> in [-1-eps,3+eps]; +2.5 bias
// -> strictly positive keys, raw-bits monotone. Key u32 = (bits &
// 0xFFFFF000) | global_col(12b); exact-rescore absorbs ~1e-3 quantization.
__global__ __launch_bounds__(256, 6)
void k_knn_m(const u16* __restrict__ Abuf, const u16* __restrict__ Bbuf,
             u32* __restrict__ candu) {
  __shared__ __align__(16) u16 As[2][2][2048];   // [period parity][slot] 16 KB
  int tid = threadIdx.x;
  int lane = tid & 63;
  int wv = tid >> 6;
  int quad = lane >> 4, m16 = lane & 15;
  int panel = blockIdx.x * 4 + wv;
  int row = panel * 16 + m16;
  int b4096 = row & ~(NPTS - 1);
  int half = blockIdx.y;
  int ct0 = half * 128;

  const __bf16* Bb = (const __bf16*)Bbuf + (size_t)row * 128;
  bf16x8 bh0 = *(const bf16x8*)(Bb + quad * 8);
  bf16x8 bh1 = *(const bf16x8*)(Bb + 32 + quad * 8);
  bf16x8 bl0 = *(const bf16x8*)(Bb + 64 + quad * 8);
  bf16x8 bl1 = *(const bf16x8*)(Bb + 96 + quad * 8);

  // tiles ct0..ct0+127 for this batch; per-wave staging src (quarter wv)
  const u16* gs = Abuf + ((size_t)(b4096 >> 4) + ct0) * 2048
                  + wv * 512 + lane * 8;

  u32 s0=~0u,s1=~0u,s2=~0u,s3=~0u,s4=~0u,s5=~0u,
      s6=~0u,s7=~0u,s8=~0u,s9=~0u,s10=~0u,s11=~0u;

  const f32x4 C25 = {2.5f, 2.5f, 2.5f, 2.5f};

#define LDA(P, S, A0,A1,A2,A3) do {                                         \
    const u16* _p = &As[P][S][lane * 8];                                    \
    A0 = *(const bf16x8*)(_p);                                              \
    A1 = *(const bf16x8*)(_p + 512);                                        \
    A2 = *(const bf16x8*)(_p + 1024);                                       \
    A3 = *(const bf16x8*)(_p + 1536);                                       \
  } while (0)
#define MFMA6(ACC, A0,A1,A2,A3) do {                                        \
    ACC = __builtin_amdgcn_mfma_f32_16x16x32_bf16(A0, bh0, C25, 0, 0, 0);   \
    ACC = __builtin_amdgcn_mfma_f32_16x16x32_bf16(A1, bh1, ACC, 0, 0, 0);   \
    ACC = __builtin_amdgcn_mfma_f32_16x16x32_bf16(A0, bl0, ACC, 0, 0, 0);   \
    ACC = __builtin_amdgcn_mfma_f32_16x16x32_bf16(A1, bl1, ACC, 0, 0, 0);   \
    ACC = __builtin_amdgcn_mfma_f32_16x16x32_bf16(A2, bh0, ACC, 0, 0, 0);   \
    ACC = __builtin_amdgcn_mfma_f32_16x16x32_bf16(A3, bh1, ACC, 0, 0, 0);   \
  } while (0)
#define FILTER(ACC, CT) do {                                                \
    u32 _colb = ((u32)(CT) << 4) | ((u32)quad << 2);                        \
    _Pragma("unroll")                                                       \
    for (int _r = 0; _r < 4; ++_r) {                                        \
      u32 _u = __float_as_uint((ACC)[_r]);                                  \
      u32 _x = (_u & 0xFFFFF000u) | (_colb | (u32)_r);                      \
      INS12(s0,s1,s2,s3,s4,s5,s6,s7,s8,s9,s10,s11, _x);                     \
    }                                                                       \
  } while (0)

  f32x4 accA, accB;
  bf16x8 a0, a1, a2, a3;

  // prologue: stage tiles 0,1 -> parity 0
  stage_q(gs,        &As[0][0][wv * 512]);
  stage_q(gs + 2048, &As[0][1][wv * 512]);
  __syncthreads();

  // period 0: tiles 0,1 from parity 0; stage tiles 2,3 -> parity 1
  LDA(0, 0, a0, a1, a2, a3);
  stage_q(gs + (size_t)2 * 2048, &As[1][0][wv * 512]);
  stage_q(gs + (size_t)3 * 2048, &As[1][1][wv * 512]);
  MFMA6(accA, a0, a1, a2, a3);
  LDA(0, 1, a0, a1, a2, a3);
  MFMA6(accB, a0, a1, a2, a3);
  FILTER(accA, ct0 + 0);
  __syncthreads();

  for (int p = 1; p < 63; ++p) {
    int par = p & 1;
    LDA(par, 0, a0, a1, a2, a3);
    stage_q(gs + (size_t)(2 * p + 2) * 2048, &As[par ^ 1][0][wv * 512]);
    stage_q(gs + (size_t)(2 * p + 3) * 2048, &As[par ^ 1][1][wv * 512]);
    MFMA6(accA, a0, a1, a2, a3);          // tile 2p
    FILTER(accB, ct0 + 2 * p - 1);        // finish tile 2p-1 (covers latency)
    LDA(par, 1, a0, a1, a2, a3);
    MFMA6(accB, a0, a1, a2, a3);          // tile 2p+1
    FILTER(accA, ct0 + 2 * p);
    __syncthreads();
  }
  // period 63 (parity 1): tiles 126,127; no stage
  LDA(1, 0, a0, a1, a2, a3);
  MFMA6(accA, a0, a1, a2, a3);
  FILTER(accB, ct0 + 125);
  LDA(1, 1, a0, a1, a2, a3);
  MFMA6(accB, a0, a1, a2, a3);
  FILTER(accA, ct0 + 126);
  FILTER(accB, ct0 + 127);
#undef LDA
#undef MFMA6
#undef FILTER

  u32* o = candu + (((size_t)row * 2 + half) * 4 + quad) * NCAND;
  o[0]=s0; o[1]=s1; o[2]=s2; o[3]=s3; o[4]=s4; o[5]=s5;
  o[6]=s6; o[7]=s7; o[8]=s8; o[9]=s9; o[10]=s10; o[11]=s11;
}

// k_reduce: per row, top-12 of the 96 u32 candidates (2 halves x 4 quads x
// 12). 64 rows/block x 4 threads/row; med3 insert network; 2-stage
// (24 each -> 48 merged by thread 0). uint4-vectorized loads.
__global__ __launch_bounds__(256, 4)
void k_reduce(const u32* __restrict__ candu, u32* __restrict__ cand12) {
  __shared__ __align__(16) u32 ls[64 * 4 * NCAND];   // 12,288 B
  int tid = threadIdx.x;
  int lr = tid >> 2, q = tid & 3;
  int row = blockIdx.x * 64 + lr;
  const uint4* src = (const uint4*)(candu + (size_t)row * 96 + q * 24);
  u32 t0=~0u,t1=~0u,t2=~0u,t3=~0u,t4=~0u,t5=~0u,
      t6=~0u,t7=~0u,t8=~0u,t9=~0u,t10=~0u,t11=~0u;
  for (int s = 0; s < 6; ++s) {
    uint4 v = src[s];
    INS12(t0,t1,t2,t3,t4,t5,t6,t7,t8,t9,t10,t11, v.x);
    INS12(t0,t1,t2,t3,t4,t5,t6,t7,t8,t9,t10,t11, v.y);
    INS12(t0,t1,t2,t3,t4,t5,t6,t7,t8,t9,t10,t11, v.z);
    INS12(t0,t1,t2,t3,t4,t5,t6,t7,t8,t9,t10,t11, v.w);
  }
  u32* lw = ls + (size_t)(lr * 4 + q) * NCAND;
  lw[0]=t0; lw[1]=t1; lw[2]=t2; lw[3]=t3; lw[4]=t4; lw[5]=t5;
  lw[6]=t6; lw[7]=t7; lw[8]=t8; lw[9]=t9; lw[10]=t10; lw[11]=t11;
  __syncthreads();
  if (q == 0) {
    u32 g0=~0u,g1=~0u,g2=~0u,g3=~0u,g4=~0u,g5=~0u,
        g6=~0u,g7=~0u,g8=~0u,g9=~0u,g10=~0u,g11=~0u;
    const uint4* lsrc = (const uint4*)(ls + (size_t)lr * 48);
    for (int s = 0; s < 12; ++s) {
      uint4 v = lsrc[s];
      INS12(g0,g1,g2,g3,g4,g5,g6,g7,g8,g9,g10,g11, v.x);
      INS12(g0,g1,g2,g3,g4,g5,g6,g7,g8,g9,g10,g11, v.y);
      INS12(g0,g1,g2,g3,g4,g5,g6,g7,g8,g9,g10,g11, v.z);
      INS12(g0,g1,g2,g3,g4,g5,g6,g7,g8,g9,g10,g11, v.w);
    }
    u32* o = cand12 + (size_t)row * NCAND;
    o[0]=(g0&0xFFFu); o[1]=(g1&0xFFFu); o[2]=(g2&0xFFFu);
    o[3]=(g3&0xFFFu); o[4]=(g4&0xFFFu); o[5]=(g5&0xFFFu);
    o[6]=(g6&0xFFFu); o[7]=(g7&0xFFFu); o[8]=(g8&0xFFFu);
    o[9]=(g9&0xFFFu); o[10]=(g10&0xFFFu); o[11]=(g11&0xFFFu);
  }
}

// k_rescore: 16 rows/block x 16 threads/row; threads 0..11 each gather ONE
// candidate row and compute the exact fp32 dist (proven formula); thread 0
// merges 12 with the exact (dist, idx) comparator -> top-9. Fused nn write
// + degree histogram (tail edge drop). Only 12 gathers/row.
#define RR 16
__global__ __launch_bounds__(256, 4)
void k_rescore(const float* __restrict__ xn, const float* __restrict__ csq,
               const u32* __restrict__ cand12,
               u16* __restrict__ nn, int* __restrict__ deg) {
  __shared__ float dS[RR * NCAND];
  __shared__ int   iS[RR * NCAND];
  int tid = threadIdx.x;
  int lr = tid >> 4, q = tid & 15;
  int bi = blockIdx.x;
  int row = (bi & 7) * NPTS + (bi >> 3) * RR + lr;   // XCD swizzle (perf-only)
  int b4096 = row & ~(NPTS - 1);
  const float* xnb = xn + (size_t)b4096 * CH;
  if (q < NCAND) {
    float rf[CH];
    const float4* p = (const float4*)(xn + (size_t)row * CH);
#pragma unroll
    for (int i = 0; i < CH / 4; ++i) {
      float4 v = p[i];
      rf[4*i] = v.x; rf[4*i+1] = v.y; rf[4*i+2] = v.z; rf[4*i+3] = v.w;
    }
    float sqn = csq[row];
    int c = (int)(cand12[(size_t)row * NCAND + q] & (NPTS - 1));
    const float4* cp = (const float4*)(xnb + (size_t)c * CH);
    float a0 = 0, a1 = 0, a2 = 0, a3 = 0;
#pragma unroll
    for (int i = 0; i < CH / 4; ++i) {
      float4 v = cp[i];
      a0 += rf[4*i]   * v.x; a1 += rf[4*i+1] * v.y;
      a2 += rf[4*i+2] * v.z; a3 += rf[4*i+3] * v.w;
    }
    float dist = (sqn + csq[b4096 + c]) - 2.0f * ((a0 + a1) + (a2 + a3));
    dS[lr * NCAND + q] = dist;
    iS[lr * NCAND + q] = c;
  }
  __syncthreads();
  if (q == 0) {
    float gd[KNN]; int gi[KNN];
#pragma unroll
    for (int j = 0; j < KNN; ++j) { gd[j] = 3.4e38f; gi[j] = 0x7fffffff; }
    for (int s = 0; s < NCAND; ++s) {
      float dc = dS[lr * NCAND + s]; int ic = iS[lr * NCAND + s];
      if (dc < gd[KNN - 1] || (dc == gd[KNN - 1] && ic < gi[KNN - 1])) {
        gd[KNN - 1] = dc; gi[KNN - 1] = ic;
#pragma unroll
        for (int k2 = KNN - 1; k2 > 0; --k2) {
          bool sw = (gd[k2] < gd[k2 - 1]) ||
                    (gd[k2] == gd[k2 - 1] && gi[k2] < gi[k2 - 1]);
          if (sw) {
            float td = gd[k2]; gd[k2] = gd[k2 - 1]; gd[k2 - 1] = td;
            int ti = gi[k2]; gi[k2] = gi[k2 - 1]; gi[k2 - 1] = ti;
          }
        }
      }
    }
    u16* o = nn + (size_t)row * KNN;
    int jmax = (row == NBN - 1) ? (KNN - 1) : KNN;   // linspace tail drop
#pragma unroll
    for (int j = 0; j < KNN; ++j) o[j] = (u16)(gi[j] & (NPTS - 1));
    for (int j = 0; j < jmax; ++j)
      atomicAdd(&deg[b4096 + (gi[j] & (NPTS - 1))], 1);
  }
}

// k_out: 64 nodes/block x 4 threads/node (12 out-channels each), XCD swizzle.
#define ONB 64
#define LPAD 52
__global__ __launch_bounds__(256)
void k_out_f(const float* __restrict__ xraw, const u16* __restrict__ nn,
             const int* __restrict__ deg,
             const float* __restrict__ W0, const float* __restrict__ W1,
             const float* __restrict__ bias, float* __restrict__ out) {
  __shared__ float w0[CH * CH], w1[CH * CH], bs[CH];
  __shared__ __align__(16) float fS[ONB * LPAD];
  __shared__ __align__(16) float txS[ONB * LPAD];
  __shared__ float dinvS[ONB];
  int tid = threadIdx.x;
  int bi = blockIdx.x;
  int n0 = (bi & 7) * NPTS + (bi >> 3) * ONB;   // XCD swizzle (perf-only)
  int b12 = n0 & ~(NPTS - 1);
  for (int i = tid; i < CH * CH; i += 256) { w0[i] = W0[i]; w1[i] = W1[i]; }
  if (tid < CH) bs[tid] = bias[tid];
  for (int i = tid; i < ONB * 12; i += 256) {
    int ln = i / 12, f4 = i % 12;
    *(float4*)(fS + ln * LPAD + f4 * 4) =
        *(const float4*)(xraw + (size_t)(n0 + ln) * CH + f4 * 4);
  }
  if (tid < ONB) {
    int dg = deg[n0 + tid];
    dinvS[tid] = (dg > 0) ? (1.0f / sqrtf((float)dg)) : 0.0f;
  }
  __syncthreads();

  int ln = tid >> 2, p = tid & 3;
  int node = n0 + ln;
  float dn = dinvS[ln];
  const u16* nrow = nn + (size_t)node * KNN;
  bool full = (node != NBN - 1);
  float tx[12];
#pragma unroll
  for (int i = 0; i < 12; ++i) tx[i] = 0.f;
#pragma unroll
  for (int j = 0; j < KNN; ++j) {
    if (j < KNN - 1 || full) {
      int s = nrow[j] & (NPTS - 1);
      int dgs = deg[b12 + s];
      float ds = (dgs > 0) ? (1.0f / sqrtf((float)dgs)) : 0.0f;
      float w = -(ds * dn);
      const float4* pr = (const float4*)(xraw + (size_t)(b12 + s) * CH + p * 12);
#pragma unroll
      for (int q3 = 0; q3 < 3; ++q3) {
        float4 v = pr[q3];
        tx[q3*4]   += w * v.x; tx[q3*4+1] += w * v.y;
        tx[q3*4+2] += w * v.z; tx[q3*4+3] += w * v.w;
      }
    }
  }
#pragma unroll
  for (int q3 = 0; q3 < 3; ++q3)
    *(float4*)(txS + ln * LPAD + p * 12 + q3 * 4) =
        make_float4(tx[q3*4], tx[q3*4+1], tx[q3*4+2], tx[q3*4+3]);
  __syncthreads();

  float acc[12];
#pragma unroll
  for (int i = 0; i < 12; ++i) acc[i] = bs[p * 12 + i];
  const float* fr = fS + ln * LPAD;
  const float* tr = txS + ln * LPAD;
#pragma unroll
  for (int c = 0; c < CH; ++c) {
    float fc = fr[c];
    const float* wr = w0 + c * CH + p * 12;
#pragma unroll
    for (int i = 0; i < 12; ++i) acc[i] += fc * wr[i];
  }
#pragma unroll
  for (int c = 0; c < CH; ++c) {
    float tc = tr[c];
    const float* wr = w1 + c * CH + p * 12;
#pragma unroll
    for (int i = 0; i < 12; ++i) acc[i] += tc * wr[i];
  }
  float* op = out + (size_t)node * CH + p * 12;
#pragma unroll
  for (int q3 = 0; q3 < 3; ++q3)
    *(float4*)(op + q3 * 4) =
        make_float4(acc[q3*4], acc[q3*4+1], acc[q3*4+2], acc[q3*4+3]);
}

// ======================= FALLBACK (round-4, proven) =======================
__global__ __launch_bounds__(256)
void k_zero(int* __restrict__ deg) { deg[blockIdx.x * 256 + threadIdx.x] = 0; }

__global__ __launch_bounds__(256)
void k_hist(const u16* __restrict__ nn, int* __restrict__ deg) {
  int node = blockIdx.x * 256 + threadIdx.x;
  int b12 = node & ~(NPTS - 1);
  int jmax = (node == NBN - 1) ? (KNN - 1) : KNN;
  for (int j = 0; j < jmax; ++j)
    atomicAdd(&deg[b12 + (nn[(size_t)node * KNN + j] & (NPTS - 1))], 1);
}

__global__ __launch_bounds__(256)
void k_dinv(const int* __restrict__ deg, float* __restrict__ dinv) {
  int i = blockIdx.x * 256 + threadIdx.x;
  int dg = deg[i];
  dinv[i] = (dg > 0) ? (1.0f / sqrtf((float)dg)) : 0.0f;
}

#define NQ    4
#define QCOLS (NPTS/NQ)
#define TCOLS 32
#define NTILES (QCOLS/TCOLS)
#define RPB   64

__global__ __launch_bounds__(256)
void k_knn_nb(const float* __restrict__ x, u16* __restrict__ nn) {
  __shared__ __align__(16) float tile[NQ * TCOLS * CH];
  __shared__ float nrmS[NQ * TCOLS];
  __shared__ float csq[NQ * TCOLS];
  int tid = threadIdx.x;
  int r0 = blockIdx.x * RPB;
  int b  = r0 >> 12;
  int q  = tid >> 6;
  int lr = tid & 63;
  int n  = (r0 + lr) & (NPTS - 1);
  const float* xb = x + (size_t)b * CH * NPTS;
  float rf[CH];
#pragma unroll
  for (int c = 0; c < CH; ++c) rf[c] = xb[(size_t)c * NPTS + n];
  float sqn;
  {
    float a0 = 0, a1 = 0, a2 = 0, a3 = 0;
#pragma unroll
    for (int k = 0; k < CH; k += 4) {
      a0 += rf[k] * rf[k]; a1 += rf[k+1] * rf[k+1];
      a2 += rf[k+2] * rf[k+2]; a3 += rf[k+3] * rf[k+3];
    }
    float nrm = fmaxf(sqrtf((a0 + a1) + (a2 + a3)), 1e-12f);
#pragma unroll
    for (int c = 0; c < CH; ++c) rf[c] = rf[c] / nrm;
    a0 = a1 = a2 = a3 = 0;
#pragma unroll
    for (int k = 0; k < CH; k += 4) {
      a0 += rf[k] * rf[k]; a1 += rf[k+1] * rf[k+1];
      a2 += rf[k+2] * rf[k+2]; a3 += rf[k+3] * rf[k+3];
    }
    sqn = (a0 + a1) + (a2 + a3);
  }
  float d[KNN]; int id[KNN];
#pragma unroll
  for (int j = 0; j < KNN; ++j) { d[j] = 3.4e38f; id[j] = 0x7fffffff; }
  for (int t = 0; t < NTILES; ++t) {
    __syncthreads();
#pragma unroll
    for (int qq = 0; qq < NQ; ++qq) {
      int colbase = qq * QCOLS + t * TCOLS;
      float* dst = tile + qq * TCOLS * CH;
#pragma unroll
      for (int it = 0; it < 6; ++it) {
        int i = it * 256 + tid;
        int c = i >> 5, p = i & 31;
        dst[p * CH + c] = xb[(size_t)c * NPTS + colbase + p];
      }
    }
    __syncthreads();
    if (tid < NQ * TCOLS) {
      const float* cp = tile + tid * CH;
      float a0 = 0, a1 = 0, a2 = 0, a3 = 0;
#pragma unroll
      for (int k = 0; k < CH; k += 4) {
        float4 v = *(const float4*)(cp + k);
        a0 += v.x * v.x; a1 += v.y * v.y; a2 += v.z * v.z; a3 += v.w * v.w;
      }
      nrmS[tid] = fmaxf(sqrtf((a0 + a1) + (a2 + a3)), 1e-12f);
    }
    __syncthreads();
    for (int i = tid; i < NQ * TCOLS * CH; i += 256)
      tile[i] = tile[i] / nrmS[i / CH];
    __syncthreads();
    if (tid < NQ * TCOLS) {
      const float* cp = tile + tid * CH;
      float a0 = 0, a1 = 0, a2 = 0, a3 = 0;
#pragma unroll
      for (int k = 0; k < CH; k += 4) {
        float4 v = *(const float4*)(cp + k);
        a0 += v.x * v.x; a1 += v.y * v.y; a2 += v.z * v.z; a3 += v.w * v.w;
      }
      csq[tid] = (a0 + a1) + (a2 + a3);
    }
    __syncthreads();
    int cbase = q * QCOLS + t * TCOLS;
    const float* tq = tile + q * TCOLS * CH;
    for (int cc = 0; cc < TCOLS; ++cc) {
      const float* cp = tq + cc * CH;
      float a0 = 0, a1 = 0, a2 = 0, a3 = 0;
#pragma unroll
      for (int k = 0; k < CH; k += 4) {
        float4 v = *(const float4*)(cp + k);
        a0 += rf[k] * v.x; a1 += rf[k+1] * v.y;
        a2 += rf[k+2] * v.z; a3 += rf[k+3] * v.w;
      }
      float dist = (sqn + csq[q * TCOLS + cc]) - 2.0f * ((a0 + a1) + (a2 + a3));
      if (dist < d[KNN - 1]) {
        d[KNN - 1] = dist; id[KNN - 1] = cbase + cc;
#pragma unroll
        for (int k2 = KNN - 1; k2 > 0; --k2) {
          if (d[k2] < d[k2 - 1]) {
            float td = d[k2]; d[k2] = d[k2 - 1]; d[k2 - 1] = td;
            int ti = id[k2]; id[k2] = id[k2 - 1]; id[k2 - 1] = ti;
          }
        }
      }
    }
  }
  __syncthreads();
  float* md = tile;
  int*   mi = (int*)(tile + 256 * KNN);
#pragma unroll
  for (int j = 0; j < KNN; ++j) { md[tid * KNN + j] = d[j]; mi[tid * KNN + j] = id[j]; }
  __syncthreads();
  if (tid < RPB) {
    float fd[KNN]; int fi[KNN];
#pragma unroll
    for (int j = 0; j < KNN; ++j) { fd[j] = 3.4e38f; fi[j] = 0x7fffffff; }
    for (int qq = 0; qq < NQ; ++qq) {
      int s = qq * RPB + tid;
      for (int j = 0; j < KNN; ++j) {
        float dc = md[s * KNN + j]; int ic = mi[s * KNN + j];
        if (dc < fd[KNN - 1]) {
          fd[KNN - 1] = dc; fi[KNN - 1] = ic;
#pragma unroll
          for (int k2 = KNN - 1; k2 > 0; --k2) {
            if (fd[k2] < fd[k2 - 1]) {
              float td = fd[k2]; fd[k2] = fd[k2 - 1]; fd[k2 - 1] = td;
              int ti = fi[k2]; fi[k2] = fi[k2 - 1]; fi[k2 - 1] = ti;
            }
          }
        }
      }
    }
    u16* o = nn + (size_t)(r0 + tid) * KNN;
#pragma unroll
    for (int j = 0; j < KNN; ++j) o[j] = (u16)(fi[j] & (NPTS - 1));
  }
}

__global__ __launch_bounds__(256)
void k_out_nb(const float* __restrict__ x, const u16* __restrict__ nn,
              const float* __restrict__ dinv,
              const float* __restrict__ W0, const float* __restrict__ W1,
              const float* __restrict__ bias, float* __restrict__ out) {
  __shared__ float w0[CH * CH], w1[CH * CH], bs[CH];
  for (int i = threadIdx.x; i < CH * CH; i += 256) { w0[i] = W0[i]; w1[i] = W1[i]; }
  if (threadIdx.x < CH) bs[threadIdx.x] = bias[threadIdx.x];
  __syncthreads();
  int node = blockIdx.x * 256 + threadIdx.x;
  int b = node >> 12, n = node & (NPTS - 1);
  const float* xb = x + (size_t)b * CH * NPTS;
  float f[CH], acc[CH], tx[CH];
#pragma unroll
  for (int c = 0; c < CH; ++c) f[c] = xb[(size_t)c * NPTS + n];
#pragma unroll
  for (int o = 0; o < CH; ++o) acc[o] = bs[o];
#pragma unroll
  for (int c = 0; c < CH; ++c) {
    float fc = f[c];
    const float* wr = w0 + c * CH;
#pragma unroll
    for (int o = 0; o < CH; ++o) acc[o] += fc * wr[o];
  }
#pragma unroll
  for (int c = 0; c < CH; ++c) tx[c] = 0.f;
  float dn = dinv[node];
  int jmax = (node == NBN - 1) ? (KNN - 1) : KNN;
  for (int j = 0; j < jmax; ++j) {
    int s = nn[(size_t)node * KNN + j] & (NPTS - 1);
    float w = -(dinv[(b << 12) + s] * dn);
#pragma unroll
    for (int c = 0; c < CH; ++c) tx[c] += w * xb[(size_t)c * NPTS + s];
  }
#pragma unroll
  for (int c = 0; c < CH; ++c) {
    float tc = tx[c];
    const float* wr = w1 + c * CH;
#pragma unroll
    for (int o = 0; o < CH; ++o) acc[o] += tc * wr[o];
  }
  float4* op = (float4*)(out + (size_t)node * CH);
#pragma unroll
  for (int i = 0; i < CH / 4; ++i)
    op[i] = make_float4(acc[4*i], acc[4*i+1], acc[4*i+2], acc[4*i+3]);
}

extern "C" void kernel_launch(void* const* d_in, const int* in_sizes, int n_in,
                              void* d_out, int out_size, void* d_ws, size_t ws_size,
                              hipStream_t stream) {
  const float* x    = (const float*)d_in[0];
  const float* W0   = (const float*)d_in[1];
  const float* W1   = (const float*)d_in[2];
  const float* bias = (const float*)d_in[3];
  float* out = (float*)d_out;
  char* w = (char*)d_ws;

  const size_t SZ_XN   = (size_t)NBN * CH * 4;            //  6,291,456
  const size_t SZ_XRAW = (size_t)NBN * CH * 4;            //  6,291,456
  const size_t SZ_CSQ  = (size_t)NBN * 4;                 //    131,072
  const size_t SZ_NN   = (size_t)NBN * KNN * 2;           //    589,824
  const size_t SZ_DEG  = (size_t)NBN * 4;                 //    131,072
  const size_t SZ_AB   = (size_t)NBN * 128 * 2;           //  8,388,608
  const size_t SZ_CU   = (size_t)NBN * 8 * NCAND * 4;     // 12,582,912 (u32, 2 halves)
  const size_t SZ_C12  = (size_t)NBN * NCAND * 4;         //  1,572,864
  const size_t needF = SZ_XN + SZ_XRAW + SZ_CSQ + SZ_NN + SZ_DEG
                     + 2 * SZ_AB + SZ_CU + SZ_C12;        // ~44.3 MB

  if (ws_size >= needF) {          // FAST path: MFMA filter + reduce + rescore
    size_t off = 0;
    float* xn   = (float*)(w + off); off += SZ_XN;
    float* xraw = (float*)(w + off); off += SZ_XRAW;
    float* csq  = (float*)(w + off); off += SZ_CSQ;
    u16*   nn   = (u16*)  (w + off); off += SZ_NN;
    int*   deg  = (int*)  (w + off); off += SZ_DEG;
    u16*   Abuf = (u16*)  (w + off); off += SZ_AB;
    u16*   Bbuf = (u16*)  (w + off); off += SZ_AB;
    u32*   candu= (u32*)  (w + off); off += SZ_CU;
    u32*   cand12=(u32*)  (w + off);
    k_prep    <<<NBN / 64, 64, 0, stream>>>(x, xraw, xn, csq, Abuf, Bbuf, deg);
    k_knn_m   <<<dim3(NBN / 64, 2), 256, 0, stream>>>(Abuf, Bbuf, candu);
    k_reduce  <<<NBN / 64, 256, 0, stream>>>(candu, cand12);
    k_rescore <<<NBN / RR, 256, 0, stream>>>(xn, csq, cand12, nn, deg);
    k_out_f   <<<NBN / ONB, 256, 0, stream>>>(xraw, nn, deg, W0, W1, bias, out);
  } else {                         // FALLBACK: proven round-4 path (852 KB)
    u16*   nn   = (u16*)w;
    int*   deg  = (int*)(w + SZ_NN);
    float* dinv = (float*)(w + SZ_NN + SZ_DEG);
    k_knn_nb <<<NBN / RPB, 256, 0, stream>>>(x, nn);
    k_zero   <<<NBN / 256, 256, 0, stream>>>(deg);
    k_hist   <<<NBN / 256, 256, 0, stream>>>(nn, deg);
    k_dinv   <<<NBN / 256, 256, 0, stream>>>(deg, dinv);
    k_out_nb <<<NBN / 256, 256, 0, stream>>>(x, nn, dinv, W0, W1, bias, out);
  }
}

// Round 8
// 200.871 us; speedup vs baseline: 1.4085x; 1.0289x over previous
//
#include <hip/hip_runtime.h>

#define BATCH 8
#define CH    48
#define NPTS  4096
#define NBN   (BATCH*NPTS)
#define KNN   9
#define NCAND 12             // per-lane filter depth

typedef unsigned short u16;
typedef unsigned int   u32;
typedef unsigned long long u64;
typedef __bf16 bf16x8 __attribute__((ext_vector_type(8)));
typedef float  f32x4  __attribute__((ext_vector_type(4)));

__device__ __forceinline__ float bf2f(u16 v) { return __uint_as_float(((u32)v) << 16); }
__device__ __forceinline__ u16 f2bf(float f) {
  u32 u = __float_as_uint(f);
  u = (u + 0x7fffu + ((u >> 16) & 1u)) >> 16;
  return (u16)u;
}

// Shared med3 insert: insert x into sorted p0<=...<=p11 keeping smallest 12.
//   p_i' = med3(p_{i-1}, p_i, x) (i=11..1, old values), p0' = min(p0, x).
#define MED3U(d, a, b, c) \
  asm("v_med3_u32 %0, %1, %2, %3" : "=v"(d) : "v"(a), "v"(b), "v"(c))
#define INS12(p0,p1,p2,p3,p4,p5,p6,p7,p8,p9,p10,p11,x) do { \
  MED3U(p11,p10,p11,x); MED3U(p10,p9,p10,x); MED3U(p9,p8,p9,x);  \
  MED3U(p8, p7, p8, x); MED3U(p7, p6,p7, x); MED3U(p6,p5,p6,x);  \
  MED3U(p5, p4, p5, x); MED3U(p4, p3,p4, x); MED3U(p3,p2,p3,x);  \
  MED3U(p2, p1, p2, x); MED3U(p1, p0,p1, x); p0 = min(p0, x);    \
} while (0)

// async global->LDS staging: per-lane global src, wave-uniform LDS base
// (HW adds lane*16B). 16B/lane x 64 lanes = 1 KB per call.
__device__ __forceinline__ void stage_q(const u16* g, u16* l) {
  __builtin_amdgcn_global_load_lds(
      (const __attribute__((address_space(1))) void*)g,
      (__attribute__((address_space(3))) void*)l, 16, 0, 0);
}

// ======================= FAST PATH (ws >= ~43 MB) =======================
// k_prep: lean (one division, no persistent u16 arrays -> no spills).
// A layout [tile16][variant(4)][lane(64)][8 bf16]; B [node][hi 64][lo 64].
__global__ __launch_bounds__(64)
void k_prep(const float* __restrict__ x, float* __restrict__ xraw,
            float* __restrict__ xn, float* __restrict__ csq,
            u16* __restrict__ Abuf, u16* __restrict__ Bbuf,
            int* __restrict__ deg) {
  int node = blockIdx.x * 64 + threadIdx.x;
  deg[node] = 0;
  int b = node >> 12, n = node & (NPTS - 1);
  const float* xb = x + (size_t)b * CH * NPTS;
  float f[CH];
#pragma unroll
  for (int c = 0; c < CH; ++c) f[c] = xb[(size_t)c * NPTS + n];
  float a0 = 0, a1 = 0, a2 = 0, a3 = 0;
#pragma unroll
  for (int k = 0; k < CH; k += 4) {
    a0 += f[k] * f[k]; a1 += f[k+1] * f[k+1];
    a2 += f[k+2] * f[k+2]; a3 += f[k+3] * f[k+3];
  }
  float nrm = fmaxf(sqrtf((a0 + a1) + (a2 + a3)), 1e-12f);
  float rn = 1.0f / nrm;            // one exact division; xv = f*rn
  a0 = a1 = a2 = a3 = 0;
#pragma unroll
  for (int k = 0; k < CH; k += 4) {
    float v0 = f[k]*rn, v1 = f[k+1]*rn, v2 = f[k+2]*rn, v3 = f[k+3]*rn;
    a0 += v0*v0; a1 += v1*v1; a2 += v2*v2; a3 += v3*v3;
  }
  float csqv = (a0 + a1) + (a2 + a3);
  csq[node] = csqv;
  float4* ro = (float4*)(xraw + (size_t)node * CH);
  float4* no = (float4*)(xn   + (size_t)node * CH);
#pragma unroll
  for (int i = 0; i < CH / 4; ++i) {
    ro[i] = make_float4(f[4*i], f[4*i+1], f[4*i+2], f[4*i+3]);
    no[i] = make_float4(f[4*i]*rn, f[4*i+1]*rn, f[4*i+2]*rn, f[4*i+3]*rn);
  }
  uint4* Bo = (uint4*)(Bbuf + (size_t)node * 128);
  u16* Ag = Abuf + (size_t)(node >> 4) * 2048 + (size_t)(node & 15) * 8;
#pragma unroll
  for (int g = 0; g < 6; ++g) {
    u32 bhw[4], blw[4], ahw[4], alw[4];
#pragma unroll
    for (int j = 0; j < 4; ++j) {
      int k = g * 8 + j * 2;
      float v0 = f[k] * rn, v1 = f[k+1] * rn;
      u16 h0 = f2bf(v0), h1 = f2bf(v1);
      u16 l0 = f2bf(v0 - bf2f(h0)), l1 = f2bf(v1 - bf2f(h1));
      bhw[j] = (u32)h0 | ((u32)h1 << 16);
      blw[j] = (u32)l0 | ((u32)l1 << 16);
      float w0 = -2.0f * v0, w1 = -2.0f * v1;
      u16 g0 = f2bf(w0), g1 = f2bf(w1);
      u16 m0 = f2bf(w0 - bf2f(g0)), m1 = f2bf(w1 - bf2f(g1));
      ahw[j] = (u32)g0 | ((u32)g1 << 16);
      alw[j] = (u32)m0 | ((u32)m1 << 16);
    }
    Bo[g]     = make_uint4(bhw[0], bhw[1], bhw[2], bhw[3]);
    Bo[8 + g] = make_uint4(blw[0], blw[1], blw[2], blw[3]);
    int v = g >> 2, q = g & 3;          // hi variant: v<2; lo at +1024
    *(uint4*)(Ag + v * 512 + q * 128)        = make_uint4(ahw[0], ahw[1], ahw[2], ahw[3]);
    *(uint4*)(Ag + 1024 + v * 512 + q * 128) = make_uint4(alw[0], alw[1], alw[2], alw[3]);
  }
  { // g=6: ch48 = csq (A) / 1.0 (B); ch49-55 zero
    u16 h = f2bf(csqv); u16 l = f2bf(csqv - bf2f(h));
    Bo[6]  = make_uint4(0x3F80u, 0, 0, 0);
    Bo[14] = make_uint4(0, 0, 0, 0);
    *(uint4*)(Ag + 512 + 2 * 128)        = make_uint4((u32)h, 0, 0, 0);
    *(uint4*)(Ag + 1024 + 512 + 2 * 128) = make_uint4((u32)l, 0, 0, 0);
  }
  { // g=7: ch56-63 zero
    uint4 z = make_uint4(0, 0, 0, 0);
    Bo[7] = z; Bo[15] = z;
    *(uint4*)(Ag + 512 + 3 * 128)        = z;
    *(uint4*)(Ag + 1024 + 512 + 3 * 128) = z;
  }
}

// k_knn_m: unchanged round-7 structure (halves, LDS staging, 2-tile periods).
__global__ __launch_bounds__(256, 6)
void k_knn_m(const u16* __restrict__ Abuf, const u16* __restrict__ Bbuf,
             u32* __restrict__ candu) {
  __shared__ __align__(16) u16 As[2][2][2048];   // 16 KB
  int tid = threadIdx.x;
  int lane = tid & 63;
  int wv = tid >> 6;
  int quad = lane >> 4, m16 = lane & 15;
  int panel = blockIdx.x * 4 + wv;
  int row = panel * 16 + m16;
  int b4096 = row & ~(NPTS - 1);
  int half = blockIdx.y;
  int ct0 = half * 128;

  const __bf16* Bb = (const __bf16*)Bbuf + (size_t)row * 128;
  bf16x8 bh0 = *(const bf16x8*)(Bb + quad * 8);
  bf16x8 bh1 = *(const bf16x8*)(Bb + 32 + quad * 8);
  bf16x8 bl0 = *(const bf16x8*)(Bb + 64 + quad * 8);
  bf16x8 bl1 = *(const bf16x8*)(Bb + 96 + quad * 8);

  const u16* gs = Abuf + ((size_t)(b4096 >> 4) + ct0) * 2048
                  + wv * 512 + lane * 8;

  u32 s0=~0u,s1=~0u,s2=~0u,s3=~0u,s4=~0u,s5=~0u,
      s6=~0u,s7=~0u,s8=~0u,s9=~0u,s10=~0u,s11=~0u;

  const f32x4 C25 = {2.5f, 2.5f, 2.5f, 2.5f};

#define LDA(P, S, A0,A1,A2,A3) do {                                         \
    const u16* _p = &As[P][S][lane * 8];                                    \
    A0 = *(const bf16x8*)(_p);                                              \
    A1 = *(const bf16x8*)(_p + 512);                                        \
    A2 = *(const bf16x8*)(_p + 1024);                                       \
    A3 = *(const bf16x8*)(_p + 1536);                                       \
  } while (0)
#define MFMA6(ACC, A0,A1,A2,A3) do {                                        \
    ACC = __builtin_amdgcn_mfma_f32_16x16x32_bf16(A0, bh0, C25, 0, 0, 0);   \
    ACC = __builtin_amdgcn_mfma_f32_16x16x32_bf16(A1, bh1, ACC, 0, 0, 0);   \
    ACC = __builtin_amdgcn_mfma_f32_16x16x32_bf16(A0, bl0, ACC, 0, 0, 0);   \
    ACC = __builtin_amdgcn_mfma_f32_16x16x32_bf16(A1, bl1, ACC, 0, 0, 0);   \
    ACC = __builtin_amdgcn_mfma_f32_16x16x32_bf16(A2, bh0, ACC, 0, 0, 0);   \
    ACC = __builtin_amdgcn_mfma_f32_16x16x32_bf16(A3, bh1, ACC, 0, 0, 0);   \
  } while (0)
#define FILTER(ACC, CT) do {                                                \
    u32 _colb = ((u32)(CT) << 4) | ((u32)quad << 2);                        \
    _Pragma("unroll")                                                       \
    for (int _r = 0; _r < 4; ++_r) {                                        \
      u32 _u = __float_as_uint((ACC)[_r]);                                  \
      u32 _x = (_u & 0xFFFFF000u) | (_colb | (u32)_r);                      \
      INS12(s0,s1,s2,s3,s4,s5,s6,s7,s8,s9,s10,s11, _x);                     \
    }                                                                       \
  } while (0)

  f32x4 accA, accB;
  bf16x8 a0, a1, a2, a3;

  stage_q(gs,        &As[0][0][wv * 512]);
  stage_q(gs + 2048, &As[0][1][wv * 512]);
  __syncthreads();

  LDA(0, 0, a0, a1, a2, a3);
  stage_q(gs + (size_t)2 * 2048, &As[1][0][wv * 512]);
  stage_q(gs + (size_t)3 * 2048, &As[1][1][wv * 512]);
  MFMA6(accA, a0, a1, a2, a3);
  LDA(0, 1, a0, a1, a2, a3);
  MFMA6(accB, a0, a1, a2, a3);
  FILTER(accA, ct0 + 0);
  __syncthreads();

  for (int p = 1; p < 63; ++p) {
    int par = p & 1;
    LDA(par, 0, a0, a1, a2, a3);
    stage_q(gs + (size_t)(2 * p + 2) * 2048, &As[par ^ 1][0][wv * 512]);
    stage_q(gs + (size_t)(2 * p + 3) * 2048, &As[par ^ 1][1][wv * 512]);
    MFMA6(accA, a0, a1, a2, a3);          // tile 2p
    FILTER(accB, ct0 + 2 * p - 1);        // finish tile 2p-1 (covers latency)
    LDA(par, 1, a0, a1, a2, a3);
    MFMA6(accB, a0, a1, a2, a3);          // tile 2p+1
    FILTER(accA, ct0 + 2 * p);
    __syncthreads();
  }
  LDA(1, 0, a0, a1, a2, a3);
  MFMA6(accA, a0, a1, a2, a3);
  FILTER(accB, ct0 + 125);
  LDA(1, 1, a0, a1, a2, a3);
  MFMA6(accB, a0, a1, a2, a3);
  FILTER(accA, ct0 + 126);
  FILTER(accB, ct0 + 127);
#undef LDA
#undef MFMA6
#undef FILTER

  u32* o = candu + (((size_t)row * 2 + half) * 4 + quad) * NCAND;
  o[0]=s0; o[1]=s1; o[2]=s2; o[3]=s3; o[4]=s4; o[5]=s5;
  o[6]=s6; o[7]=s7; o[8]=s8; o[9]=s9; o[10]=s10; o[11]=s11;
}

// k_rr: FUSED reduce+rescore. 32 rows/block (1024 blocks, XCD swizzle).
// Stage 0: block's 32 xn rows + csq staged coalesced into LDS (once, not
//          12x per row as the old k_rescore did).
// Stage 1: 4 thr/row, top-12 of 24 candidates (med3 network, uint4 loads).
// Stage 2: 1 thr/row merges 48 -> top-12 keys (written back in-place).
// Stage 3: 384 rescore tasks flat over 256 threads: gather cand row,
//          exact fp32 dist vs LDS row features.
// Stage 4: 1 thr/row exact (dist,idx) top-9 -> nn write + deg histogram.
// Removes: cand12 buffer, one dispatch, 12x redundant rf loads.
#define RWS 32
__global__ __launch_bounds__(256)
void k_rr(const u32* __restrict__ candu, const float* __restrict__ xn,
          const float* __restrict__ csq, u16* __restrict__ nn,
          int* __restrict__ deg) {
  __shared__ __align__(16) u32 cs[RWS][48];
  __shared__ __align__(16) float xnS[RWS][52];
  __shared__ float csqS[RWS];
  __shared__ float dS[RWS][12];
  __shared__ int   iS[RWS][12];
  int tid = threadIdx.x, bi = blockIdx.x;
  int row0 = (bi & 7) * NPTS + (bi >> 3) * RWS;   // XCD swizzle (perf-only)
  int b4096 = row0 & ~(NPTS - 1);
  // stage 0: xn rows + csq
  for (int i = tid; i < RWS * 12; i += 256) {
    int ln = i / 12, f4 = i % 12;
    *(float4*)&xnS[ln][f4 * 4] =
        *(const float4*)(xn + (size_t)(row0 + ln) * CH + f4 * 4);
  }
  if (tid < RWS) csqS[tid] = csq[row0 + tid];
  // stage 1
  if (tid < RWS * 4) {
    int lr = tid >> 2, q = tid & 3;
    const uint4* src = (const uint4*)(candu + (size_t)(row0 + lr) * 96 + q * 24);
    u32 t0=~0u,t1=~0u,t2=~0u,t3=~0u,t4=~0u,t5=~0u,
        t6=~0u,t7=~0u,t8=~0u,t9=~0u,t10=~0u,t11=~0u;
#pragma unroll
    for (int s = 0; s < 6; ++s) {
      uint4 v = src[s];
      INS12(t0,t1,t2,t3,t4,t5,t6,t7,t8,t9,t10,t11, v.x);
      INS12(t0,t1,t2,t3,t4,t5,t6,t7,t8,t9,t10,t11, v.y);
      INS12(t0,t1,t2,t3,t4,t5,t6,t7,t8,t9,t10,t11, v.z);
      INS12(t0,t1,t2,t3,t4,t5,t6,t7,t8,t9,t10,t11, v.w);
    }
    u32* lw = &cs[lr][q * 12];
    lw[0]=t0; lw[1]=t1; lw[2]=t2; lw[3]=t3; lw[4]=t4; lw[5]=t5;
    lw[6]=t6; lw[7]=t7; lw[8]=t8; lw[9]=t9; lw[10]=t10; lw[11]=t11;
  }
  __syncthreads();
  // stage 2
  if (tid < RWS) {
    int lr = tid;
    u32 g0=~0u,g1=~0u,g2=~0u,g3=~0u,g4=~0u,g5=~0u,
        g6=~0u,g7=~0u,g8=~0u,g9=~0u,g10=~0u,g11=~0u;
    const uint4* ls4 = (const uint4*)&cs[lr][0];
#pragma unroll
    for (int s = 0; s < 12; ++s) {
      uint4 v = ls4[s];
      INS12(g0,g1,g2,g3,g4,g5,g6,g7,g8,g9,g10,g11, v.x);
      INS12(g0,g1,g2,g3,g4,g5,g6,g7,g8,g9,g10,g11, v.y);
      INS12(g0,g1,g2,g3,g4,g5,g6,g7,g8,g9,g10,g11, v.z);
      INS12(g0,g1,g2,g3,g4,g5,g6,g7,g8,g9,g10,g11, v.w);
    }
    u32* lw = &cs[lr][0];   // in-place: reads all done (serial in thread)
    lw[0]=g0; lw[1]=g1; lw[2]=g2; lw[3]=g3; lw[4]=g4; lw[5]=g5;
    lw[6]=g6; lw[7]=g7; lw[8]=g8; lw[9]=g9; lw[10]=g10; lw[11]=g11;
  }
  __syncthreads();
  // stage 3: rescore
  for (int task = tid; task < RWS * 12; task += 256) {
    int r = task / 12, j = task % 12;
    int c = (int)(cs[r][j] & 0xFFFu);
    const float4* cp = (const float4*)(xn + (size_t)(b4096 + c) * CH);
    const float* rf = &xnS[r][0];
    float a0 = 0, a1 = 0, a2 = 0, a3 = 0;
#pragma unroll
    for (int i = 0; i < CH / 4; ++i) {
      float4 v = cp[i];
      a0 += rf[4*i]   * v.x; a1 += rf[4*i+1] * v.y;
      a2 += rf[4*i+2] * v.z; a3 += rf[4*i+3] * v.w;
    }
    float dist = (csqS[r] + csq[b4096 + c]) - 2.0f * ((a0 + a1) + (a2 + a3));
    dS[r][j] = dist; iS[r][j] = c;
  }
  __syncthreads();
  // stage 4: exact top-9
  if (tid < RWS) {
    int lr = tid;
    int row = row0 + lr;
    float gd[KNN]; int gi[KNN];
#pragma unroll
    for (int j = 0; j < KNN; ++j) { gd[j] = 3.4e38f; gi[j] = 0x7fffffff; }
    for (int s = 0; s < NCAND; ++s) {
      float dc = dS[lr][s]; int ic = iS[lr][s];
      if (dc < gd[KNN - 1] || (dc == gd[KNN - 1] && ic < gi[KNN - 1])) {
        gd[KNN - 1] = dc; gi[KNN - 1] = ic;
#pragma unroll
        for (int k2 = KNN - 1; k2 > 0; --k2) {
          bool sw = (gd[k2] < gd[k2 - 1]) ||
                    (gd[k2] == gd[k2 - 1] && gi[k2] < gi[k2 - 1]);
          if (sw) {
            float td = gd[k2]; gd[k2] = gd[k2 - 1]; gd[k2 - 1] = td;
            int ti = gi[k2]; gi[k2] = gi[k2 - 1]; gi[k2 - 1] = ti;
          }
        }
      }
    }
    u16* o = nn + (size_t)row * KNN;
    int jmax = (row == NBN - 1) ? (KNN - 1) : KNN;   // linspace tail drop
#pragma unroll
    for (int j = 0; j < KNN; ++j) o[j] = (u16)(gi[j] & (NPTS - 1));
    for (int j = 0; j < jmax; ++j)
      atomicAdd(&deg[b4096 + (gi[j] & (NPTS - 1))], 1);
  }
}

// k_out: 32 nodes/block x 8 threads/node (6 out-channels each), 1024 blocks
// (2x the old TLP for the gather-latency phase), XCD swizzle.
#define ONB 32
#define LPAD 52
__global__ __launch_bounds__(256)
void k_out_f(const float* __restrict__ xraw, const u16* __restrict__ nn,
             const int* __restrict__ deg,
             const float* __restrict__ W0, const float* __restrict__ W1,
             const float* __restrict__ bias, float* __restrict__ out) {
  __shared__ float w0[CH * CH], w1[CH * CH], bs[CH];
  __shared__ __align__(16) float fS[ONB * LPAD];
  __shared__ __align__(16) float txS[ONB * LPAD];
  __shared__ float dinvS[ONB];
  int tid = threadIdx.x;
  int bi = blockIdx.x;
  int n0 = (bi & 7) * NPTS + (bi >> 3) * ONB;   // XCD swizzle (perf-only)
  int b12 = n0 & ~(NPTS - 1);
  for (int i = tid; i < CH * CH; i += 256) { w0[i] = W0[i]; w1[i] = W1[i]; }
  if (tid < CH) bs[tid] = bias[tid];
  for (int i = tid; i < ONB * 12; i += 256) {
    int ln = i / 12, f4 = i % 12;
    *(float4*)(fS + ln * LPAD + f4 * 4) =
        *(const float4*)(xraw + (size_t)(n0 + ln) * CH + f4 * 4);
  }
  if (tid < ONB) {
    int dg = deg[n0 + tid];
    dinvS[tid] = (dg > 0) ? (1.0f / sqrtf((float)dg)) : 0.0f;
  }
  __syncthreads();

  int ln = tid >> 3, p = tid & 7;   // 8 thr/node, 6 channels each
  int node = n0 + ln;
  float dn = dinvS[ln];
  const u16* nrow = nn + (size_t)node * KNN;
  bool full = (node != NBN - 1);
  float tx[6];
#pragma unroll
  for (int i = 0; i < 6; ++i) tx[i] = 0.f;
#pragma unroll
  for (int j = 0; j < KNN; ++j) {
    if (j < KNN - 1 || full) {
      int s = nrow[j] & (NPTS - 1);
      int dgs = deg[b12 + s];
      float ds = (dgs > 0) ? (1.0f / sqrtf((float)dgs)) : 0.0f;
      float w = -(ds * dn);
      const float2* pr = (const float2*)(xraw + (size_t)(b12 + s) * CH + p * 6);
#pragma unroll
      for (int q3 = 0; q3 < 3; ++q3) {
        float2 v = pr[q3];
        tx[q3*2]   += w * v.x; tx[q3*2+1] += w * v.y;
      }
    }
  }
#pragma unroll
  for (int q3 = 0; q3 < 3; ++q3)
    *(float2*)(txS + ln * LPAD + p * 6 + q3 * 2) =
        make_float2(tx[q3*2], tx[q3*2+1]);
  __syncthreads();

  float acc[6];
#pragma unroll
  for (int i = 0; i < 6; ++i) acc[i] = bs[p * 6 + i];
  const float* fr = fS + ln * LPAD;
  const float* tr = txS + ln * LPAD;
#pragma unroll
  for (int c = 0; c < CH; ++c) {
    float fc = fr[c];
    const float* wr = w0 + c * CH + p * 6;
#pragma unroll
    for (int i = 0; i < 6; ++i) acc[i] += fc * wr[i];
  }
#pragma unroll
  for (int c = 0; c < CH; ++c) {
    float tc = tr[c];
    const float* wr = w1 + c * CH + p * 6;
#pragma unroll
    for (int i = 0; i < 6; ++i) acc[i] += tc * wr[i];
  }
  float* op = out + (size_t)node * CH + p * 6;
#pragma unroll
  for (int q3 = 0; q3 < 3; ++q3)
    *(float2*)(op + q3 * 2) = make_float2(acc[q3*2], acc[q3*2+1]);
}

// ======================= FALLBACK (round-4, proven) =======================
__global__ __launch_bounds__(256)
void k_zero(int* __restrict__ deg) { deg[blockIdx.x * 256 + threadIdx.x] = 0; }

__global__ __launch_bounds__(256)
void k_hist(const u16* __restrict__ nn, int* __restrict__ deg) {
  int node = blockIdx.x * 256 + threadIdx.x;
  int b12 = node & ~(NPTS - 1);
  int jmax = (node == NBN - 1) ? (KNN - 1) : KNN;
  for (int j = 0; j < jmax; ++j)
    atomicAdd(&deg[b12 + (nn[(size_t)node * KNN + j] & (NPTS - 1))], 1);
}

__global__ __launch_bounds__(256)
void k_dinv(const int* __restrict__ deg, float* __restrict__ dinv) {
  int i = blockIdx.x * 256 + threadIdx.x;
  int dg = deg[i];
  dinv[i] = (dg > 0) ? (1.0f / sqrtf((float)dg)) : 0.0f;
}

#define NQ    4
#define QCOLS (NPTS/NQ)
#define TCOLS 32
#define NTILES (QCOLS/TCOLS)
#define RPB   64

__global__ __launch_bounds__(256)
void k_knn_nb(const float* __restrict__ x, u16* __restrict__ nn) {
  __shared__ __align__(16) float tile[NQ * TCOLS * CH];
  __shared__ float nrmS[NQ * TCOLS];
  __shared__ float csq[NQ * TCOLS];
  int tid = threadIdx.x;
  int r0 = blockIdx.x * RPB;
  int b  = r0 >> 12;
  int q  = tid >> 6;
  int lr = tid & 63;
  int n  = (r0 + lr) & (NPTS - 1);
  const float* xb = x + (size_t)b * CH * NPTS;
  float rf[CH];
#pragma unroll
  for (int c = 0; c < CH; ++c) rf[c] = xb[(size_t)c * NPTS + n];
  float sqn;
  {
    float a0 = 0, a1 = 0, a2 = 0, a3 = 0;
#pragma unroll
    for (int k = 0; k < CH; k += 4) {
      a0 += rf[k] * rf[k]; a1 += rf[k+1] * rf[k+1];
      a2 += rf[k+2] * rf[k+2]; a3 += rf[k+3] * rf[k+3];
    }
    float nrm = fmaxf(sqrtf((a0 + a1) + (a2 + a3)), 1e-12f);
#pragma unroll
    for (int c = 0; c < CH; ++c) rf[c] = rf[c] / nrm;
    a0 = a1 = a2 = a3 = 0;
#pragma unroll
    for (int k = 0; k < CH; k += 4) {
      a0 += rf[k] * rf[k]; a1 += rf[k+1] * rf[k+1];
      a2 += rf[k+2] * rf[k+2]; a3 += rf[k+3] * rf[k+3];
    }
    sqn = (a0 + a1) + (a2 + a3);
  }
  float d[KNN]; int id[KNN];
#pragma unroll
  for (int j = 0; j < KNN; ++j) { d[j] = 3.4e38f; id[j] = 0x7fffffff; }
  for (int t = 0; t < NTILES; ++t) {
    __syncthreads();
#pragma unroll
    for (int qq = 0; qq < NQ; ++qq) {
      int colbase = qq * QCOLS + t * TCOLS;
      float* dst = tile + qq * TCOLS * CH;
#pragma unroll
      for (int it = 0; it < 6; ++it) {
        int i = it * 256 + tid;
        int c = i >> 5, p = i & 31;
        dst[p * CH + c] = xb[(size_t)c * NPTS + colbase + p];
      }
    }
    __syncthreads();
    if (tid < NQ * TCOLS) {
      const float* cp = tile + tid * CH;
      float a0 = 0, a1 = 0, a2 = 0, a3 = 0;
#pragma unroll
      for (int k = 0; k < CH; k += 4) {
        float4 v = *(const float4*)(cp + k);
        a0 += v.x * v.x; a1 += v.y * v.y; a2 += v.z * v.z; a3 += v.w * v.w;
      }
      nrmS[tid] = fmaxf(sqrtf((a0 + a1) + (a2 + a3)), 1e-12f);
    }
    __syncthreads();
    for (int i = tid; i < NQ * TCOLS * CH; i += 256)
      tile[i] = tile[i] / nrmS[i / CH];
    __syncthreads();
    if (tid < NQ * TCOLS) {
      const float* cp = tile + tid * CH;
      float a0 = 0, a1 = 0, a2 = 0, a3 = 0;
#pragma unroll
      for (int k = 0; k < CH; k += 4) {
        float4 v = *(const float4*)(cp + k);
        a0 += v.x * v.x; a1 += v.y * v.y; a2 += v.z * v.z; a3 += v.w * v.w;
      }
      csq[tid] = (a0 + a1) + (a2 + a3);
    }
    __syncthreads();
    int cbase = q * QCOLS + t * TCOLS;
    const float* tq = tile + q * TCOLS * CH;
    for (int cc = 0; cc < TCOLS; ++cc) {
      const float* cp = tq + cc * CH;
      float a0 = 0, a1 = 0, a2 = 0, a3 = 0;
#pragma unroll
      for (int k = 0; k < CH; k += 4) {
        float4 v = *(const float4*)(cp + k);
        a0 += rf[k] * v.x; a1 += rf[k+1] * v.y;
        a2 += rf[k+2] * v.z; a3 += rf[k+3] * v.w;
      }
      float dist = (sqn + csq[q * TCOLS + cc]) - 2.0f * ((a0 + a1) + (a2 + a3));
      if (dist < d[KNN - 1]) {
        d[KNN - 1] = dist; id[KNN - 1] = cbase + cc;
#pragma unroll
        for (int k2 = KNN - 1; k2 > 0; --k2) {
          if (d[k2] < d[k2 - 1]) {
            float td = d[k2]; d[k2] = d[k2 - 1]; d[k2 - 1] = td;
            int ti = id[k2]; id[k2] = id[k2 - 1]; id[k2 - 1] = ti;
          }
        }
      }
    }
  }
  __syncthreads();
  float* md = tile;
  int*   mi = (int*)(tile + 256 * KNN);
#pragma unroll
  for (int j = 0; j < KNN; ++j) { md[tid * KNN + j] = d[j]; mi[tid * KNN + j] = id[j]; }
  __syncthreads();
  if (tid < RPB) {
    float fd[KNN]; int fi[KNN];
#pragma unroll
    for (int j = 0; j < KNN; ++j) { fd[j] = 3.4e38f; fi[j] = 0x7fffffff; }
    for (int qq = 0; qq < NQ; ++qq) {
      int s = qq * RPB + tid;
      for (int j = 0; j < KNN; ++j) {
        float dc = md[s * KNN + j]; int ic = mi[s * KNN + j];
        if (dc < fd[KNN - 1]) {
          fd[KNN - 1] = dc; fi[KNN - 1] = ic;
#pragma unroll
          for (int k2 = KNN - 1; k2 > 0; --k2) {
            if (fd[k2] < fd[k2 - 1]) {
              float td = fd[k2]; fd[k2] = fd[k2 - 1]; fd[k2 - 1] = td;
              int ti = fi[k2]; fi[k2] = fi[k2 - 1]; fi[k2 - 1] = ti;
            }
          }
        }
      }
    }
    u16* o = nn + (size_t)(r0 + tid) * KNN;
#pragma unroll
    for (int j = 0; j < KNN; ++j) o[j] = (u16)(fi[j] & (NPTS - 1));
  }
}

__global__ __launch_bounds__(256)
void k_out_nb(const float* __restrict__ x, const u16* __restrict__ nn,
              const float* __restrict__ dinv,
              const float* __restrict__ W0, const float* __restrict__ W1,
              const float* __restrict__ bias, float* __restrict__ out) {
  __shared__ float w0[CH * CH], w1[CH * CH], bs[CH];
  for (int i = threadIdx.x; i < CH * CH; i += 256) { w0[i] = W0[i]; w1[i] = W1[i]; }
  if (threadIdx.x < CH) bs[threadIdx.x] = bias[threadIdx.x];
  __syncthreads();
  int node = blockIdx.x * 256 + threadIdx.x;
  int b = node >> 12, n = node & (NPTS - 1);
  const float* xb = x + (size_t)b * CH * NPTS;
  float f[CH], acc[CH], tx[CH];
#pragma unroll
  for (int c = 0; c < CH; ++c) f[c] = xb[(size_t)c * NPTS + n];
#pragma unroll
  for (int o = 0; o < CH; ++o) acc[o] = bs[o];
#pragma unroll
  for (int c = 0; c < CH; ++c) {
    float fc = f[c];
    const float* wr = w0 + c * CH;
#pragma unroll
    for (int o = 0; o < CH; ++o) acc[o] += fc * wr[o];
  }
#pragma unroll
  for (int c = 0; c < CH; ++c) tx[c] = 0.f;
  float dn = dinv[node];
  int jmax = (node == NBN - 1) ? (KNN - 1) : KNN;
  for (int j = 0; j < jmax; ++j) {
    int s = nn[(size_t)node * KNN + j] & (NPTS - 1);
    float w = -(dinv[(b << 12) + s] * dn);
#pragma unroll
    for (int c = 0; c < CH; ++c) tx[c] += w * xb[(size_t)c * NPTS + s];
  }
#pragma unroll
  for (int c = 0; c < CH; ++c) {
    float tc = tx[c];
    const float* wr = w1 + c * CH;
#pragma unroll
    for (int o = 0; o < CH; ++o) acc[o] += tc * wr[o];
  }
  float4* op = (float4*)(out + (size_t)node * CH);
#pragma unroll
  for (int i = 0; i < CH / 4; ++i)
    op[i] = make_float4(acc[4*i], acc[4*i+1], acc[4*i+2], acc[4*i+3]);
}

extern "C" void kernel_launch(void* const* d_in, const int* in_sizes, int n_in,
                              void* d_out, int out_size, void* d_ws, size_t ws_size,
                              hipStream_t stream) {
  const float* x    = (const float*)d_in[0];
  const float* W0   = (const float*)d_in[1];
  const float* W1   = (const float*)d_in[2];
  const float* bias = (const float*)d_in[3];
  float* out = (float*)d_out;
  char* w = (char*)d_ws;

  const size_t SZ_XN   = (size_t)NBN * CH * 4;            //  6,291,456
  const size_t SZ_XRAW = (size_t)NBN * CH * 4;            //  6,291,456
  const size_t SZ_CSQ  = (size_t)NBN * 4;                 //    131,072
  const size_t SZ_NN   = (size_t)NBN * KNN * 2;           //    589,824
  const size_t SZ_DEG  = (size_t)NBN * 4;                 //    131,072
  const size_t SZ_AB   = (size_t)NBN * 128 * 2;           //  8,388,608
  const size_t SZ_CU   = (size_t)NBN * 8 * NCAND * 4;     // 12,582,912 (u32, 2 halves)
  const size_t needF = SZ_XN + SZ_XRAW + SZ_CSQ + SZ_NN + SZ_DEG
                     + 2 * SZ_AB + SZ_CU;                 // ~42.7 MB

  if (ws_size >= needF) {          // FAST path: MFMA filter + fused rr
    size_t off = 0;
    float* xn   = (float*)(w + off); off += SZ_XN;
    float* xraw = (float*)(w + off); off += SZ_XRAW;
    float* csq  = (float*)(w + off); off += SZ_CSQ;
    u16*   nn   = (u16*)  (w + off); off += SZ_NN;
    int*   deg  = (int*)  (w + off); off += SZ_DEG;
    u16*   Abuf = (u16*)  (w + off); off += SZ_AB;
    u16*   Bbuf = (u16*)  (w + off); off += SZ_AB;
    u32*   candu= (u32*)  (w + off);
    k_prep    <<<NBN / 64, 64, 0, stream>>>(x, xraw, xn, csq, Abuf, Bbuf, deg);
    k_knn_m   <<<dim3(NBN / 64, 2), 256, 0, stream>>>(Abuf, Bbuf, candu);
    k_rr      <<<NBN / RWS, 256, 0, stream>>>(candu, xn, csq, nn, deg);
    k_out_f   <<<NBN / ONB, 256, 0, stream>>>(xraw, nn, deg, W0, W1, bias, out);
  } else {                         // FALLBACK: proven round-4 path (852 KB)
    u16*   nn   = (u16*)w;
    int*   deg  = (int*)(w + SZ_NN);
    float* dinv = (float*)(w + SZ_NN + SZ_DEG);
    k_knn_nb <<<NBN / RPB, 256, 0, stream>>>(x, nn);
    k_zero   <<<NBN / 256, 256, 0, stream>>>(deg);
    k_hist   <<<NBN / 256, 256, 0, stream>>>(nn, deg);
    k_dinv   <<<NBN / 256, 256, 0, stream>>>(deg, dinv);
    k_out_nb <<<NBN / 256, 256, 0, stream>>>(x, nn, dinv, W0, W1, bias, out);
  }
}